// Round 2
// baseline (3187.825 us; speedup 1.0000x reference)
//
#include <hip/hip_runtime.h>
#include <hip/hip_bf16.h>
#include <math.h>

typedef __hip_bfloat16 bf16;

#define H_ 300
#define W_ 300
#define HW_ 90000
#define NBATCH 32

struct alignas(4) bpack { bf16 a, b; };

__device__ __forceinline__ float ldv(const float* p) { return *p; }
__device__ __forceinline__ float ldv(const bf16* p) { return __bfloat162float(*p); }
__device__ __forceinline__ bf16 f2b(float v) { return __float2bfloat16(v); }
__device__ __forceinline__ float sigm(float x) { return 1.f / (1.f + __expf(-x)); }

// ---------------------------------------------------------------------------
// Generic 3x3 SAME conv, tile 32x32, 256 threads (16x16 quads of 2x2 px).
// Input staged to LDS in CHUNK-channel slices; weights staged to LDS.
// acc fp32, in/out bf16 (TIN selects fp32 input for conv1).
// n_groups splits output channels across blockIdx.z (conv3: 32 = 2 x 16).
// blockIdx.z = (local batch) * n_groups + group; pointers are chunk-local.
// ---------------------------------------------------------------------------
template <typename TIN, int CIN, int CHUNK, int COUT>
__global__ __launch_bounds__(256) void conv_k(
    const TIN* __restrict__ in, const float* __restrict__ w,
    const float* __restrict__ bias, bf16* __restrict__ out,
    int co_total, int n_groups)
{
    __shared__ float s_in[CHUNK * 1156];      // (34x34) halo tile per channel
    __shared__ float s_w[CIN * 9 * COUT];     // [ci][tap][co]

    int bz = blockIdx.z;
    int b = bz / n_groups;
    int g = bz % n_groups;
    int co_off = g * COUT;
    const float* wg_ = w + (size_t)co_off * CIN * 9;

    int x0 = blockIdx.x * 32, y0 = blockIdx.y * 32;
    int tid = threadIdx.x;

    for (int i = tid; i < CIN * 9 * COUT; i += 256) {
        int ci = i / (9 * COUT);
        int r = i - ci * 9 * COUT;
        int t = r / COUT;
        int co = r - t * COUT;
        s_w[i] = wg_[(co * CIN + ci) * 9 + t];
    }

    float acc[4][COUT];
#pragma unroll
    for (int co = 0; co < COUT; ++co) {
        float bv = bias[co_off + co];
        acc[0][co] = bv; acc[1][co] = bv; acc[2][co] = bv; acc[3][co] = bv;
    }

    int qx = (tid & 15) * 2, qy = (tid >> 4) * 2;
    const TIN* inb = in + (size_t)b * CIN * HW_;

    for (int c0 = 0; c0 < CIN; c0 += CHUNK) {
        __syncthreads();
        for (int i = tid; i < CHUNK * 1156; i += 256) {
            int ci = i / 1156;
            int r2 = i - ci * 1156;
            int ry = r2 / 34;
            int rx = r2 - ry * 34;
            int gy = y0 + ry - 1, gx = x0 + rx - 1;
            float v = 0.f;
            if (gy >= 0 && gy < H_ && gx >= 0 && gx < W_)
                v = ldv(&inb[(size_t)(c0 + ci) * HW_ + gy * W_ + gx]);
            s_in[i] = v;
        }
        __syncthreads();
        for (int ci = 0; ci < CHUNK; ++ci) {
            float n[4][4];
#pragma unroll
            for (int r = 0; r < 4; ++r)
#pragma unroll
                for (int c = 0; c < 4; ++c)
                    n[r][c] = s_in[ci * 1156 + (qy + r) * 34 + qx + c];
#pragma unroll
            for (int t = 0; t < 9; ++t) {
                int dy = t / 3, dx = t % 3;
#pragma unroll
                for (int co4 = 0; co4 < COUT / 4; ++co4) {
                    const float4 wv =
                        *(const float4*)&s_w[((c0 + ci) * 9 + t) * COUT + co4 * 4];
#pragma unroll
                    for (int p = 0; p < 4; ++p) {
                        float iv = n[(p >> 1) + dy][(p & 1) + dx];
                        acc[p][co4 * 4 + 0] += iv * wv.x;
                        acc[p][co4 * 4 + 1] += iv * wv.y;
                        acc[p][co4 * 4 + 2] += iv * wv.z;
                        acc[p][co4 * 4 + 3] += iv * wv.w;
                    }
                }
            }
        }
    }

    int px = x0 + qx, py = y0 + qy;
    if (px < W_) {
        bf16* ob = out + ((size_t)b * co_total + co_off) * HW_;
#pragma unroll
        for (int co = 0; co < COUT; ++co) {
#pragma unroll
            for (int pr = 0; pr < 2; ++pr) {
                if (py + pr < H_) {
                    bpack v{f2b(acc[pr * 2 + 0][co]), f2b(acc[pr * 2 + 1][co])};
                    *reinterpret_cast<bpack*>(
                        ob + (size_t)co * HW_ + (size_t)(py + pr) * W_ + px) = v;
                }
            }
        }
    }
}

// ---------------------------------------------------------------------------
// Block-average pools. p5 from x; p10/p15 from p5 (10=2*5, 15=3*5, aligned).
// n = number of output elements this launch (chunk-local).
// ---------------------------------------------------------------------------
__global__ __launch_bounds__(256) void pool5_k(const bf16* __restrict__ x,
                                               bf16* __restrict__ p5, int n)
{
    int idx = blockIdx.x * 256 + threadIdx.x;
    if (idx >= n) return;
    int j = idx % 60;
    int i = (idx / 60) % 60;
    int bc = idx / 3600;
    const bf16* src = x + (size_t)bc * HW_ + (size_t)(i * 5) * W_ + j * 5;
    float s = 0.f;
#pragma unroll
    for (int r = 0; r < 5; ++r)
#pragma unroll
        for (int c = 0; c < 5; ++c) s += ldv(&src[r * W_ + c]);
    p5[idx] = f2b(s * (1.f / 25.f));
}

template <int R, int OD>
__global__ __launch_bounds__(256) void poolr_k(const bf16* __restrict__ p5,
                                               bf16* __restrict__ po, int n)
{
    int idx = blockIdx.x * 256 + threadIdx.x;
    if (idx >= n) return;
    int j = idx % OD;
    int i = (idx / OD) % OD;
    int bc = idx / (OD * OD);
    const bf16* src = p5 + (size_t)bc * 3600 + (size_t)(i * R) * 60 + j * R;
    float s = 0.f;
#pragma unroll
    for (int r = 0; r < R; ++r)
#pragma unroll
        for (int c = 0; c < R; ++c) s += ldv(&src[r * 60 + c]);
    po[idx] = f2b(s * (1.f / (R * R)));
}

// ---------------------------------------------------------------------------
// cK conv: 16 input channels = [x(8) , upsample(poolK)(8)], 8 outputs,
// written into g_in at channel offset ch_off. The pooled half is staged to
// LDS with on-the-fly nearest upsample (index division by K).
// ---------------------------------------------------------------------------
template <int K>
__global__ __launch_bounds__(256) void convc_k(
    const bf16* __restrict__ x, const bf16* __restrict__ pk,
    const float* __restrict__ w, const float* __restrict__ bias,
    bf16* __restrict__ gin, int ch_off)
{
    constexpr int PD = 300 / K;
    __shared__ float s_in[8 * 1156];
    __shared__ float s_w[16 * 9 * 8];

    int b = blockIdx.z;
    int x0 = blockIdx.x * 32, y0 = blockIdx.y * 32;
    int tid = threadIdx.x;

    for (int i = tid; i < 16 * 9 * 8; i += 256) {
        int ci = i / 72;
        int r = i - ci * 72;
        int t = r / 8;
        int co = r - t * 8;
        s_w[i] = w[(co * 16 + ci) * 9 + t];
    }

    float acc[4][8];
#pragma unroll
    for (int co = 0; co < 8; ++co) {
        float bv = bias[co];
        acc[0][co] = bv; acc[1][co] = bv; acc[2][co] = bv; acc[3][co] = bv;
    }

    int qx = (tid & 15) * 2, qy = (tid >> 4) * 2;

    auto compute = [&](int cb) {
        for (int ci = 0; ci < 8; ++ci) {
            float n[4][4];
#pragma unroll
            for (int r = 0; r < 4; ++r)
#pragma unroll
                for (int c = 0; c < 4; ++c)
                    n[r][c] = s_in[ci * 1156 + (qy + r) * 34 + qx + c];
#pragma unroll
            for (int t = 0; t < 9; ++t) {
                int dy = t / 3, dx = t % 3;
#pragma unroll
                for (int co4 = 0; co4 < 2; ++co4) {
                    const float4 wv =
                        *(const float4*)&s_w[((cb + ci) * 9 + t) * 8 + co4 * 4];
#pragma unroll
                    for (int p = 0; p < 4; ++p) {
                        float iv = n[(p >> 1) + dy][(p & 1) + dx];
                        acc[p][co4 * 4 + 0] += iv * wv.x;
                        acc[p][co4 * 4 + 1] += iv * wv.y;
                        acc[p][co4 * 4 + 2] += iv * wv.z;
                        acc[p][co4 * 4 + 3] += iv * wv.w;
                    }
                }
            }
        }
    };

    // chunk 0: x channels
    const bf16* xb = x + (size_t)b * 8 * HW_;
    for (int i = tid; i < 8 * 1156; i += 256) {
        int ci = i / 1156;
        int r2 = i - ci * 1156;
        int ry = r2 / 34;
        int rx = r2 - ry * 34;
        int gy = y0 + ry - 1, gx = x0 + rx - 1;
        float v = 0.f;
        if (gy >= 0 && gy < H_ && gx >= 0 && gx < W_)
            v = ldv(&xb[(size_t)ci * HW_ + gy * W_ + gx]);
        s_in[i] = v;
    }
    __syncthreads();
    compute(0);
    __syncthreads();

    // chunk 1: pooled channels, upsampled on the fly
    const bf16* pb = pk + (size_t)b * 8 * PD * PD;
    for (int i = tid; i < 8 * 1156; i += 256) {
        int ci = i / 1156;
        int r2 = i - ci * 1156;
        int ry = r2 / 34;
        int rx = r2 - ry * 34;
        int gy = y0 + ry - 1, gx = x0 + rx - 1;
        float v = 0.f;
        if (gy >= 0 && gy < H_ && gx >= 0 && gx < W_)
            v = ldv(&pb[(size_t)ci * PD * PD + (gy / K) * PD + gx / K]);
        s_in[i] = v;
    }
    __syncthreads();
    compute(8);

    int px = x0 + qx, py = y0 + qy;
    if (px < W_) {
        bf16* ob = gin + ((size_t)b * 24 + ch_off) * HW_;
#pragma unroll
        for (int co = 0; co < 8; ++co) {
#pragma unroll
            for (int pr = 0; pr < 2; ++pr) {
                if (py + pr < H_) {
                    bpack v{f2b(acc[pr * 2 + 0][co]), f2b(acc[pr * 2 + 1][co])};
                    *reinterpret_cast<bpack*>(
                        ob + (size_t)co * HW_ + (size_t)(py + pr) * W_ + px) = v;
                }
            }
        }
    }
}

// ---------------------------------------------------------------------------
// Gated conv: g_in(24ch) -> conv(wg) * sigmoid(conv(wm)), 8 output channels.
// Both convs fused as one 24->16 conv (co 0-7 = g, 8-15 = m).
// Output pointer is pre-offset by the host to the chunk's batch position.
// ---------------------------------------------------------------------------
__global__ __launch_bounds__(256) void gated_k(
    const bf16* __restrict__ gin, const float* __restrict__ wg,
    const float* __restrict__ bg, const float* __restrict__ wm,
    const float* __restrict__ bm, bf16* __restrict__ gated)
{
    __shared__ float s_in[8 * 1156];
    __shared__ float s_w[24 * 9 * 16];

    int b = blockIdx.z;
    int x0 = blockIdx.x * 32, y0 = blockIdx.y * 32;
    int tid = threadIdx.x;

    for (int i = tid; i < 24 * 9 * 16; i += 256) {
        int ci = i / 144;
        int r = i - ci * 144;
        int t = r / 16;
        int co = r - t * 16;
        s_w[i] = (co < 8) ? wg[(co * 24 + ci) * 9 + t]
                          : wm[((co - 8) * 24 + ci) * 9 + t];
    }

    float acc[4][16];
#pragma unroll
    for (int co = 0; co < 16; ++co) {
        float bv = (co < 8) ? bg[co] : bm[co - 8];
        acc[0][co] = bv; acc[1][co] = bv; acc[2][co] = bv; acc[3][co] = bv;
    }

    int qx = (tid & 15) * 2, qy = (tid >> 4) * 2;
    const bf16* inb = gin + (size_t)b * 24 * HW_;

    for (int c0 = 0; c0 < 24; c0 += 8) {
        __syncthreads();
        for (int i = tid; i < 8 * 1156; i += 256) {
            int ci = i / 1156;
            int r2 = i - ci * 1156;
            int ry = r2 / 34;
            int rx = r2 - ry * 34;
            int gy = y0 + ry - 1, gx = x0 + rx - 1;
            float v = 0.f;
            if (gy >= 0 && gy < H_ && gx >= 0 && gx < W_)
                v = ldv(&inb[(size_t)(c0 + ci) * HW_ + gy * W_ + gx]);
            s_in[i] = v;
        }
        __syncthreads();
        for (int ci = 0; ci < 8; ++ci) {
            float n[4][4];
#pragma unroll
            for (int r = 0; r < 4; ++r)
#pragma unroll
                for (int c = 0; c < 4; ++c)
                    n[r][c] = s_in[ci * 1156 + (qy + r) * 34 + qx + c];
#pragma unroll
            for (int t = 0; t < 9; ++t) {
                int dy = t / 3, dx = t % 3;
#pragma unroll
                for (int co4 = 0; co4 < 4; ++co4) {
                    const float4 wv =
                        *(const float4*)&s_w[((c0 + ci) * 9 + t) * 16 + co4 * 4];
#pragma unroll
                    for (int p = 0; p < 4; ++p) {
                        float iv = n[(p >> 1) + dy][(p & 1) + dx];
                        acc[p][co4 * 4 + 0] += iv * wv.x;
                        acc[p][co4 * 4 + 1] += iv * wv.y;
                        acc[p][co4 * 4 + 2] += iv * wv.z;
                        acc[p][co4 * 4 + 3] += iv * wv.w;
                    }
                }
            }
        }
    }

    int px = x0 + qx, py = y0 + qy;
    if (px < W_) {
        bf16* ob = gated + (size_t)b * 8 * HW_;
#pragma unroll
        for (int co = 0; co < 8; ++co) {
#pragma unroll
            for (int pr = 0; pr < 2; ++pr) {
                if (py + pr < H_) {
                    float g0 = acc[pr * 2 + 0][co], m0 = acc[pr * 2 + 0][co + 8];
                    float g1 = acc[pr * 2 + 1][co], m1 = acc[pr * 2 + 1][co + 8];
                    bpack v{f2b(g0 * sigm(m0)), f2b(g1 * sigm(m1))};
                    *reinterpret_cast<bpack*>(
                        ob + (size_t)co * HW_ + (size_t)(py + pr) * W_ + px) = v;
                }
            }
        }
    }
}

// ---------------------------------------------------------------------------
// BN batch stats: deterministic two-stage reduction (no atomics).
// Stage 1: 64 blocks per channel write (sum, sumsq) partials over ALL 32 imgs.
// ---------------------------------------------------------------------------
__global__ __launch_bounds__(256) void reduce_k(const bf16* __restrict__ gated,
                                                float2* __restrict__ partials)
{
    int c = blockIdx.y;
    int bx = blockIdx.x;
    float s = 0.f, s2 = 0.f;
    for (int b = 0; b < NBATCH; ++b) {
        const bf16* p = gated + ((size_t)b * 8 + c) * HW_;
        for (int i = bx * 256 + threadIdx.x; i < HW_; i += 64 * 256) {
            float v = ldv(&p[i]);
            s += v;
            s2 += v * v;
        }
    }
#pragma unroll
    for (int off = 32; off > 0; off >>= 1) {
        s += __shfl_down(s, off);
        s2 += __shfl_down(s2, off);
    }
    __shared__ float2 red[4];
    int lane = threadIdx.x & 63, wv = threadIdx.x >> 6;
    if (lane == 0) red[wv] = make_float2(s, s2);
    __syncthreads();
    if (threadIdx.x == 0) {
        float a = 0.f, b2 = 0.f;
        for (int i = 0; i < 4; ++i) { a += red[i].x; b2 += red[i].y; }
        partials[c * 64 + bx] = make_float2(a, b2);
    }
}

// Stage 2: finalize mean/rstd, fold BN affine into conv11 weights:
// conv11(BN(g)) = conv(g, w11*s_c) + (b11 + sum(w11*t_c)).
__global__ void stats_fold_k(const float2* __restrict__ partials,
                             const float* __restrict__ bn_w,
                             const float* __restrict__ bn_b,
                             const float* __restrict__ w11,
                             const float* __restrict__ b11,
                             float* __restrict__ wfold)
{
    __shared__ float sc[8], tc[8];
    int tid = threadIdx.x;
    if (tid < 8) {
        double s = 0.0, s2 = 0.0;
        for (int i = 0; i < 64; ++i) {
            float2 p = partials[tid * 64 + i];
            s += p.x;
            s2 += p.y;
        }
        double N = (double)NBATCH * HW_;
        double mean = s / N;
        double var = s2 / N - mean * mean;
        float rstd = (float)(1.0 / sqrt(var + 1e-5));
        float scv = bn_w[tid] * rstd;
        sc[tid] = scv;
        tc[tid] = bn_b[tid] - (float)mean * scv;
    }
    __syncthreads();
    if (tid < 72) wfold[tid] = w11[tid] * sc[tid / 9];
    if (tid == 72) {
        float a = b11[0];
        for (int i = 0; i < 72; ++i) a += w11[i] * tc[i / 9];
        wfold[72] = a;
    }
}

// ---------------------------------------------------------------------------
// Final: att = sigmoid(conv8->1(gated; folded BN)), out = im*((1-g) + g*att)
// ---------------------------------------------------------------------------
__global__ __launch_bounds__(256) void final_k(
    const bf16* __restrict__ gated, const float* __restrict__ wf,
    const float* __restrict__ im, const float* __restrict__ gamma,
    float* __restrict__ out)
{
    __shared__ float s_g[8 * 1156];
    __shared__ float s_w[80];

    int b = blockIdx.z;
    int x0 = blockIdx.x * 32, y0 = blockIdx.y * 32;
    int tid = threadIdx.x;

    if (tid < 73) s_w[tid] = wf[tid];

    const bf16* gb = gated + (size_t)b * 8 * HW_;
    for (int i = tid; i < 8 * 1156; i += 256) {
        int ci = i / 1156;
        int r2 = i - ci * 1156;
        int ry = r2 / 34;
        int rx = r2 - ry * 34;
        int gy = y0 + ry - 1, gx = x0 + rx - 1;
        float v = 0.f;
        if (gy >= 0 && gy < H_ && gx >= 0 && gx < W_)
            v = ldv(&gb[(size_t)ci * HW_ + gy * W_ + gx]);
        s_g[i] = v;
    }
    __syncthreads();

    int qx = (tid & 15) * 2, qy = (tid >> 4) * 2;
    float acc[4];
    acc[0] = acc[1] = acc[2] = acc[3] = s_w[72];
    for (int ci = 0; ci < 8; ++ci) {
        float n[4][4];
#pragma unroll
        for (int r = 0; r < 4; ++r)
#pragma unroll
            for (int c = 0; c < 4; ++c)
                n[r][c] = s_g[ci * 1156 + (qy + r) * 34 + qx + c];
#pragma unroll
        for (int t = 0; t < 9; ++t) {
            int dy = t / 3, dx = t % 3;
            float wv = s_w[ci * 9 + t];
#pragma unroll
            for (int p = 0; p < 4; ++p)
                acc[p] += n[(p >> 1) + dy][(p & 1) + dx] * wv;
        }
    }

    int px = x0 + qx, py = y0 + qy;
    if (px < W_) {
        float gm = *gamma;
        float f[4];
#pragma unroll
        for (int p = 0; p < 4; ++p) f[p] = (1.f - gm) + gm * sigm(acc[p]);
#pragma unroll
        for (int ch = 0; ch < 3; ++ch) {
            const float* imb = im + ((size_t)b * 3 + ch) * HW_;
            float* ob = out + ((size_t)b * 3 + ch) * HW_;
#pragma unroll
            for (int pr = 0; pr < 2; ++pr) {
                if (py + pr < H_) {
                    float2 iv = *(const float2*)&imb[(size_t)(py + pr) * W_ + px];
                    float2 ov;
                    ov.x = iv.x * f[pr * 2 + 0];
                    ov.y = iv.y * f[pr * 2 + 1];
                    *(float2*)&ob[(size_t)(py + pr) * W_ + px] = ov;
                }
            }
        }
    }
}

// ---------------------------------------------------------------------------

extern "C" void kernel_launch(void* const* d_in, const int* in_sizes, int n_in,
                              void* d_out, int out_size, void* d_ws,
                              size_t ws_size, hipStream_t stream)
{
    (void)in_sizes; (void)n_in; (void)out_size;

    const float* im  = (const float*)d_in[0];
    const float* w1  = (const float*)d_in[1];
    const float* b1  = (const float*)d_in[2];
    const float* w2  = (const float*)d_in[3];
    const float* b2  = (const float*)d_in[4];
    const float* w3  = (const float*)d_in[5];
    const float* b3  = (const float*)d_in[6];
    const float* w4  = (const float*)d_in[7];
    const float* b4  = (const float*)d_in[8];
    const float* w5  = (const float*)d_in[9];
    const float* b5  = (const float*)d_in[10];
    const float* wc5 = (const float*)d_in[11];
    const float* bc5 = (const float*)d_in[12];
    const float* wc10= (const float*)d_in[13];
    const float* bc10= (const float*)d_in[14];
    const float* wc15= (const float*)d_in[15];
    const float* bc15= (const float*)d_in[16];
    const float* wg  = (const float*)d_in[17];
    const float* bg  = (const float*)d_in[18];
    const float* wm  = (const float*)d_in[19];
    const float* bm  = (const float*)d_in[20];
    const float* bnw = (const float*)d_in[21];
    const float* bnb = (const float*)d_in[22];
    const float* w11 = (const float*)d_in[23];
    const float* b11 = (const float*)d_in[24];
    const float* gam = (const float*)d_in[25];
    float* out = (float*)d_out;

    // ---- workspace plan: batch processed in chunks of `c` images ----------
    // persistent: gated (full batch, 8ch bf16)       = 46,080,000 B
    // per-chunk:  A (8ch) 1,440,000c  B (16ch) 2,880,000c
    //             C (32ch/24ch) 5,760,000c  pools ~78,400c  misc 8,448
    // pick the largest power-of-two chunk that fits ws_size (deterministic).
    const size_t GATED_B = 46080000;
    const size_t PER_IMG = 1440000 + 2880000 + 5760000 + 57600 + 14400 + 6656;
    const size_t MISC    = 16384;
    int c = 32;
    while (c > 1 && GATED_B + MISC + (size_t)c * PER_IMG + 2048 > ws_size)
        c >>= 1;

    char* p = (char*)d_ws;
    auto take = [&](size_t bytes) {
        char* r = p;
        p += (bytes + 255) & ~(size_t)255;
        return r;
    };
    bf16*  GATED = (bf16*)take(GATED_B);
    bf16*  A   = (bf16*)take((size_t)c * 1440000);
    bf16*  Bb  = (bf16*)take((size_t)c * 2880000);
    bf16*  C   = (bf16*)take((size_t)c * 5760000);
    bf16*  P5  = (bf16*)take((size_t)c * 57600);
    bf16*  P10 = (bf16*)take((size_t)c * 14400);
    bf16*  P15 = (bf16*)take((size_t)c * 6656);
    float2* parts = (float2*)take(4096);
    float*  wfold = (float*)take(512);

    dim3 blk(256);

    for (int b0 = 0; b0 < NBATCH; b0 += c) {
        dim3 gc(10, 10, c);
        const float* imc = im + (size_t)b0 * 3 * HW_;

        conv_k<float, 3, 3, 8><<<gc, blk, 0, stream>>>(imc, w1, b1, A, 8, 1);
        conv_k<bf16, 8, 8, 16><<<gc, blk, 0, stream>>>(A, w2, b2, Bb, 16, 1);
        conv_k<bf16, 16, 8, 16><<<dim3(10, 10, 2 * c), blk, 0, stream>>>(
            Bb, w3, b3, C, 32, 2);
        conv_k<bf16, 32, 8, 16><<<gc, blk, 0, stream>>>(C, w4, b4, Bb, 16, 1);
        conv_k<bf16, 16, 8, 8><<<gc, blk, 0, stream>>>(Bb, w5, b5, A, 8, 1);

        int n5 = c * 8 * 3600, n10 = c * 8 * 900, n15 = c * 8 * 400;
        pool5_k<<<dim3((n5 + 255) / 256), blk, 0, stream>>>(A, P5, n5);
        poolr_k<2, 30><<<dim3((n10 + 255) / 256), blk, 0, stream>>>(P5, P10, n10);
        poolr_k<3, 20><<<dim3((n15 + 255) / 256), blk, 0, stream>>>(P5, P15, n15);

        convc_k<5><<<gc, blk, 0, stream>>>(A, P5, wc5, bc5, C, 0);
        convc_k<10><<<gc, blk, 0, stream>>>(A, P10, wc10, bc10, C, 8);
        convc_k<15><<<gc, blk, 0, stream>>>(A, P15, wc15, bc15, C, 16);

        gated_k<<<gc, blk, 0, stream>>>(C, wg, bg, wm, bm,
                                        GATED + (size_t)b0 * 8 * HW_);
    }

    reduce_k<<<dim3(64, 8), blk, 0, stream>>>(GATED, parts);
    stats_fold_k<<<dim3(1), dim3(128), 0, stream>>>(parts, bnw, bnb, w11, b11,
                                                    wfold);
    final_k<<<dim3(10, 10, NBATCH), blk, 0, stream>>>(GATED, wfold, im, gam,
                                                      out);
}

// Round 3
// 1616.470 us; speedup vs baseline: 1.9721x; 1.9721x over previous
//
#include <hip/hip_runtime.h>
#include <hip/hip_bf16.h>
#include <math.h>

typedef __hip_bfloat16 bf16;
typedef __attribute__((ext_vector_type(8))) __bf16 bf16x8;
typedef __attribute__((ext_vector_type(4))) float f32x4;

#define H_ 300
#define W_ 300
#define HW_ 90000
#define NBATCH 32

struct alignas(4) bpack { bf16 a, b; };

__device__ __forceinline__ float ldv(const float* p) { return *p; }
__device__ __forceinline__ float ldv(const bf16* p) { return __bfloat162float(*p); }
__device__ __forceinline__ bf16 f2b(float v) { return __float2bfloat16(v); }
__device__ __forceinline__ unsigned short b2u(bf16 v) {
    return *reinterpret_cast<unsigned short*>(&v);
}
__device__ __forceinline__ float sigm(float x) { return 1.f / (1.f + __expf(-x)); }
__device__ __forceinline__ unsigned int packbf(float a, float b) {
    return (unsigned int)b2u(f2b(a)) | ((unsigned int)b2u(f2b(b)) << 16);
}

// ---------------------------------------------------------------------------
// conv1 only (fp32 input, 3ch): round-2 VALU conv. 32x32 tile, 2x2 px/thread.
// ---------------------------------------------------------------------------
template <typename TIN, int CIN, int CHUNK, int COUT>
__global__ __launch_bounds__(256) void conv_k(
    const TIN* __restrict__ in, const float* __restrict__ w,
    const float* __restrict__ bias, bf16* __restrict__ out,
    int co_total, int n_groups)
{
    __shared__ float s_in[CHUNK * 1156];
    __shared__ float s_w[CIN * 9 * COUT];

    int bz = blockIdx.z;
    int b = bz / n_groups;
    int g = bz % n_groups;
    int co_off = g * COUT;
    const float* wg_ = w + (size_t)co_off * CIN * 9;

    int x0 = blockIdx.x * 32, y0 = blockIdx.y * 32;
    int tid = threadIdx.x;

    for (int i = tid; i < CIN * 9 * COUT; i += 256) {
        int ci = i / (9 * COUT);
        int r = i - ci * 9 * COUT;
        int t = r / COUT;
        int co = r - t * COUT;
        s_w[i] = wg_[(co * CIN + ci) * 9 + t];
    }

    float acc[4][COUT];
#pragma unroll
    for (int co = 0; co < COUT; ++co) {
        float bv = bias[co_off + co];
        acc[0][co] = bv; acc[1][co] = bv; acc[2][co] = bv; acc[3][co] = bv;
    }

    int qx = (tid & 15) * 2, qy = (tid >> 4) * 2;
    const TIN* inb = in + (size_t)b * CIN * HW_;

    for (int c0 = 0; c0 < CIN; c0 += CHUNK) {
        __syncthreads();
        for (int i = tid; i < CHUNK * 1156; i += 256) {
            int ci = i / 1156;
            int r2 = i - ci * 1156;
            int ry = r2 / 34;
            int rx = r2 - ry * 34;
            int gy = y0 + ry - 1, gx = x0 + rx - 1;
            float v = 0.f;
            if (gy >= 0 && gy < H_ && gx >= 0 && gx < W_)
                v = ldv(&inb[(size_t)(c0 + ci) * HW_ + gy * W_ + gx]);
            s_in[i] = v;
        }
        __syncthreads();
        for (int ci = 0; ci < CHUNK; ++ci) {
            float n[4][4];
#pragma unroll
            for (int r = 0; r < 4; ++r)
#pragma unroll
                for (int c = 0; c < 4; ++c)
                    n[r][c] = s_in[ci * 1156 + (qy + r) * 34 + qx + c];
#pragma unroll
            for (int t = 0; t < 9; ++t) {
                int dy = t / 3, dx = t % 3;
#pragma unroll
                for (int co4 = 0; co4 < COUT / 4; ++co4) {
                    const float4 wv =
                        *(const float4*)&s_w[((c0 + ci) * 9 + t) * COUT + co4 * 4];
#pragma unroll
                    for (int p = 0; p < 4; ++p) {
                        float iv = n[(p >> 1) + dy][(p & 1) + dx];
                        acc[p][co4 * 4 + 0] += iv * wv.x;
                        acc[p][co4 * 4 + 1] += iv * wv.y;
                        acc[p][co4 * 4 + 2] += iv * wv.z;
                        acc[p][co4 * 4 + 3] += iv * wv.w;
                    }
                }
            }
        }
    }

    int px = x0 + qx, py = y0 + qy;
    if (px < W_) {
        bf16* ob = out + ((size_t)b * co_total + co_off) * HW_;
#pragma unroll
        for (int co = 0; co < COUT; ++co) {
#pragma unroll
            for (int pr = 0; pr < 2; ++pr) {
                if (py + pr < H_) {
                    bpack v{f2b(acc[pr * 2 + 0][co]), f2b(acc[pr * 2 + 1][co])};
                    *reinterpret_cast<bpack*>(
                        ob + (size_t)co * HW_ + (size_t)(py + pr) * W_ + px) = v;
                }
            }
        }
    }
}

// ---------------------------------------------------------------------------
// Weight prepack into MFMA B-fragment order: pack[step][g][lane][j] (bf16).
// k within a step: kk = (lane>>4)*8+j; tap = step*TPK + kk/CINP; ci = kk%CINP.
// col = lane&15 -> co = g*16+col. Zero-pad tap>=9, ci>=CIN, co>=COUT.
// co >= co_split reads w1 (gated mask conv), else w0.
// ---------------------------------------------------------------------------
__global__ void pack_k(const float* __restrict__ w0, const float* __restrict__ w1,
                       int co_split, int COUT, int CIN, int CINP, int NSTEP,
                       int NG, unsigned short* __restrict__ outp)
{
    int TPK = 32 / CINP;
    int total = NSTEP * NG * 512;
    for (int idx = threadIdx.x; idx < total; idx += 256) {
        int j = idx & 7;
        int lane = (idx >> 3) & 63;
        int g = (idx >> 9) % NG;
        int s = idx / (512 * NG);
        int col = lane & 15, kg = lane >> 4;
        int kk = kg * 8 + j;
        int tt = kk / CINP, ci = kk % CINP;
        int tap = s * TPK + tt;
        int co = g * 16 + col;
        float v = 0.f;
        if (tap < 9 && ci < CIN && co < COUT) {
            v = (co >= co_split) ? w1[((co - co_split) * CIN + ci) * 9 + tap]
                                 : w0[(co * CIN + ci) * 9 + tap];
        }
        outp[idx] = b2u(f2b(v));
    }
}

// ---------------------------------------------------------------------------
// MFMA implicit-GEMM 3x3 conv. Tile 32x16 px, 4 waves, 8 M-tiles(16px)/wave.
// LDS channel-last [y][x][ci] (stride CS, padded for bank spread); A-frag =
// one ds_read_b128/lane; B-frags prepacked in global, 1 dwordx4/lane/step.
// MODE 0: plain (CIN ch from src). MODE 1: ci<8 from src, ci>=8 upsampled
// pool (PK). MODE 2: gated (cols 0-7 g-conv, 8-15 m-conv; out = g*sigm(m)).
// ---------------------------------------------------------------------------
template <int CIN, int CINP, int CS, int COUTG, int NG, int MODE, int PK>
__global__ __launch_bounds__(256) void mfconv_k(
    const bf16* __restrict__ src, const bf16* __restrict__ pool,
    const unsigned short* __restrict__ wpack,
    const float* __restrict__ bias0, const float* __restrict__ bias1,
    bf16* __restrict__ out, int co_total, int co_off)
{
    constexpr int TPK = 32 / CINP;
    constexpr int NSTEP = (9 + TPK - 1) / TPK;
    constexpr int TH = 16;
    constexpr int PD = (MODE == 1) ? (300 / PK) : 1;

    __shared__ __align__(16) unsigned short s_in[(TH + 2) * 34 * CS];

    int bz = blockIdx.z;
    int b = bz / NG, g = bz % NG;
    int x0 = blockIdx.x * 32, y0 = blockIdx.y * TH;
    int tid = threadIdx.x;
    int lane = tid & 63, wv = tid >> 6;

    // ---- stage tile channel-last, zero-fill OOB and padded channels ----
    const bf16* sb = src + (size_t)b * CIN * HW_;
    const bf16* pb = (MODE == 1) ? pool + (size_t)b * 8 * PD * PD : nullptr;
    constexpr int NELEM = (TH + 2) * 34 * CINP;
    for (int e = tid; e < NELEM; e += 256) {
        int x = e % 34;
        int rem = e / 34;
        int ci = rem % CINP;
        int y = rem / CINP;
        int gy = y0 + y - 1, gx = x0 + x - 1;
        float v = 0.f;
        if (gy >= 0 && gy < H_ && gx >= 0 && gx < W_) {
            if (MODE == 1 && ci >= 8)
                v = ldv(&pb[(size_t)(ci - 8) * PD * PD + (gy / PK) * PD + gx / PK]);
            else if (ci < CIN)
                v = ldv(&sb[(size_t)ci * HW_ + (size_t)gy * W_ + gx]);
        }
        s_in[(y * 34 + x) * CS + ci] = b2u(f2b(v));
    }

    // ---- B fragments (registers) ----
    bf16x8 bw[NSTEP];
    const bf16x8* wp = (const bf16x8*)wpack;
#pragma unroll
    for (int s = 0; s < NSTEP; ++s) bw[s] = wp[(s * NG + g) * 64 + lane];

    int col = lane & 15, kg = lane >> 4;
    float bias_v = 0.f;
    if (MODE == 2) bias_v = (col < 8) ? bias0[col] : bias1[col - 8];
    else if (col < COUTG) bias_v = bias0[g * 16 + col];

    // per-step A-read offsets (elements): tap shift + ci-octet
    int offs[NSTEP];
#pragma unroll
    for (int s = 0; s < NSTEP; ++s) {
        int t = s * TPK + kg / (CINP / 8);
        if (t > 8) t = 8;  // padded taps read valid addr; B there is 0
        offs[s] = ((t / 3) * 34 + (t % 3)) * CS + (kg % (CINP / 8)) * 8;
    }

    __syncthreads();

#pragma unroll
    for (int i = 0; i < 8; ++i) {
        int m = wv * 8 + i;
        int my = m >> 1, tx = m & 1;
        int gy = y0 + my;
        if (gy >= H_) continue;  // wave-uniform
        int base = (my * 34 + tx * 16 + (lane & 15)) * CS;

        f32x4 acc = {0.f, 0.f, 0.f, 0.f};
#pragma unroll
        for (int s = 0; s < NSTEP; ++s) {
            bf16x8 a = *(const bf16x8*)&s_in[base + offs[s]];
            acc = __builtin_amdgcn_mfma_f32_16x16x32_bf16(a, bw[s], acc, 0, 0, 0);
        }

        int gx = x0 + tx * 16 + kg * 4;
        if (MODE == 2) {
            float v0 = acc.x + bias_v, v1 = acc.y + bias_v;
            float v2 = acc.z + bias_v, v3 = acc.w + bias_v;
            float m0 = __shfl_xor(v0, 8), m1 = __shfl_xor(v1, 8);
            float m2 = __shfl_xor(v2, 8), m3 = __shfl_xor(v3, 8);
            if (col < 8) {
                bf16* orow = out + ((size_t)b * co_total + col) * HW_ +
                             (size_t)gy * W_;
                float o0 = v0 * sigm(m0), o1 = v1 * sigm(m1);
                float o2 = v2 * sigm(m2), o3 = v3 * sigm(m3);
                if (gx + 3 < W_) {
                    uint2 st;
                    st.x = packbf(o0, o1);
                    st.y = packbf(o2, o3);
                    *(uint2*)&orow[gx] = st;
                } else {
                    float oo[4] = {o0, o1, o2, o3};
#pragma unroll
                    for (int r = 0; r < 4; ++r)
                        if (gx + r < W_) orow[gx + r] = f2b(oo[r]);
                }
            }
        } else if (col < COUTG) {
            int co = co_off + g * 16 + col;
            bf16* orow = out + ((size_t)b * co_total + co) * HW_ +
                         (size_t)gy * W_;
            float o0 = acc.x + bias_v, o1 = acc.y + bias_v;
            float o2 = acc.z + bias_v, o3 = acc.w + bias_v;
            if (gx + 3 < W_) {
                uint2 st;
                st.x = packbf(o0, o1);
                st.y = packbf(o2, o3);
                *(uint2*)&orow[gx] = st;
            } else {
                float oo[4] = {o0, o1, o2, o3};
#pragma unroll
                for (int r = 0; r < 4; ++r)
                    if (gx + r < W_) orow[gx + r] = f2b(oo[r]);
            }
        }
    }
}

// ---------------------------------------------------------------------------
// Pools (unchanged, chunk-local n).
// ---------------------------------------------------------------------------
__global__ __launch_bounds__(256) void pool5_k(const bf16* __restrict__ x,
                                               bf16* __restrict__ p5, int n)
{
    int idx = blockIdx.x * 256 + threadIdx.x;
    if (idx >= n) return;
    int j = idx % 60;
    int i = (idx / 60) % 60;
    int bc = idx / 3600;
    const bf16* src = x + (size_t)bc * HW_ + (size_t)(i * 5) * W_ + j * 5;
    float s = 0.f;
#pragma unroll
    for (int r = 0; r < 5; ++r)
#pragma unroll
        for (int c = 0; c < 5; ++c) s += ldv(&src[r * W_ + c]);
    p5[idx] = f2b(s * (1.f / 25.f));
}

template <int R, int OD>
__global__ __launch_bounds__(256) void poolr_k(const bf16* __restrict__ p5,
                                               bf16* __restrict__ po, int n)
{
    int idx = blockIdx.x * 256 + threadIdx.x;
    if (idx >= n) return;
    int j = idx % OD;
    int i = (idx / OD) % OD;
    int bc = idx / (OD * OD);
    const bf16* src = p5 + (size_t)bc * 3600 + (size_t)(i * R) * 60 + j * R;
    float s = 0.f;
#pragma unroll
    for (int r = 0; r < R; ++r)
#pragma unroll
        for (int c = 0; c < R; ++c) s += ldv(&src[r * 60 + c]);
    po[idx] = f2b(s * (1.f / (R * R)));
}

// ---------------------------------------------------------------------------
// BN stats + fold (unchanged).
// ---------------------------------------------------------------------------
__global__ __launch_bounds__(256) void reduce_k(const bf16* __restrict__ gated,
                                                float2* __restrict__ partials)
{
    int c = blockIdx.y;
    int bx = blockIdx.x;
    float s = 0.f, s2 = 0.f;
    for (int b = 0; b < NBATCH; ++b) {
        const bf16* p = gated + ((size_t)b * 8 + c) * HW_;
        for (int i = bx * 256 + threadIdx.x; i < HW_; i += 64 * 256) {
            float v = ldv(&p[i]);
            s += v;
            s2 += v * v;
        }
    }
#pragma unroll
    for (int off = 32; off > 0; off >>= 1) {
        s += __shfl_down(s, off);
        s2 += __shfl_down(s2, off);
    }
    __shared__ float2 red[4];
    int lane = threadIdx.x & 63, wv = threadIdx.x >> 6;
    if (lane == 0) red[wv] = make_float2(s, s2);
    __syncthreads();
    if (threadIdx.x == 0) {
        float a = 0.f, b2 = 0.f;
        for (int i = 0; i < 4; ++i) { a += red[i].x; b2 += red[i].y; }
        partials[c * 64 + bx] = make_float2(a, b2);
    }
}

__global__ void stats_fold_k(const float2* __restrict__ partials,
                             const float* __restrict__ bn_w,
                             const float* __restrict__ bn_b,
                             const float* __restrict__ w11,
                             const float* __restrict__ b11,
                             float* __restrict__ wfold)
{
    __shared__ float sc[8], tc[8];
    int tid = threadIdx.x;
    if (tid < 8) {
        double s = 0.0, s2 = 0.0;
        for (int i = 0; i < 64; ++i) {
            float2 p = partials[tid * 64 + i];
            s += p.x;
            s2 += p.y;
        }
        double N = (double)NBATCH * HW_;
        double mean = s / N;
        double var = s2 / N - mean * mean;
        float rstd = (float)(1.0 / sqrt(var + 1e-5));
        float scv = bn_w[tid] * rstd;
        sc[tid] = scv;
        tc[tid] = bn_b[tid] - (float)mean * scv;
    }
    __syncthreads();
    if (tid < 72) wfold[tid] = w11[tid] * sc[tid / 9];
    if (tid == 72) {
        float a = b11[0];
        for (int i = 0; i < 72; ++i) a += w11[i] * tc[i / 9];
        wfold[72] = a;
    }
}

// ---------------------------------------------------------------------------
// Final (unchanged): att = sigmoid(conv8->1(gated)), out = im*((1-g)+g*att)
// ---------------------------------------------------------------------------
__global__ __launch_bounds__(256) void final_k(
    const bf16* __restrict__ gated, const float* __restrict__ wf,
    const float* __restrict__ im, const float* __restrict__ gamma,
    float* __restrict__ out)
{
    __shared__ float s_g[8 * 1156];
    __shared__ float s_w[80];

    int b = blockIdx.z;
    int x0 = blockIdx.x * 32, y0 = blockIdx.y * 32;
    int tid = threadIdx.x;

    if (tid < 73) s_w[tid] = wf[tid];

    const bf16* gb = gated + (size_t)b * 8 * HW_;
    for (int i = tid; i < 8 * 1156; i += 256) {
        int ci = i / 1156;
        int r2 = i - ci * 1156;
        int ry = r2 / 34;
        int rx = r2 - ry * 34;
        int gy = y0 + ry - 1, gx = x0 + rx - 1;
        float v = 0.f;
        if (gy >= 0 && gy < H_ && gx >= 0 && gx < W_)
            v = ldv(&gb[(size_t)ci * HW_ + gy * W_ + gx]);
        s_g[i] = v;
    }
    __syncthreads();

    int qx = (tid & 15) * 2, qy = (tid >> 4) * 2;
    float acc[4];
    acc[0] = acc[1] = acc[2] = acc[3] = s_w[72];
    for (int ci = 0; ci < 8; ++ci) {
        float n[4][4];
#pragma unroll
        for (int r = 0; r < 4; ++r)
#pragma unroll
            for (int c = 0; c < 4; ++c)
                n[r][c] = s_g[ci * 1156 + (qy + r) * 34 + qx + c];
#pragma unroll
        for (int t = 0; t < 9; ++t) {
            int dy = t / 3, dx = t % 3;
            float wv = s_w[ci * 9 + t];
#pragma unroll
            for (int p = 0; p < 4; ++p)
                acc[p] += n[(p >> 1) + dy][(p & 1) + dx] * wv;
        }
    }

    int px = x0 + qx, py = y0 + qy;
    if (px < W_) {
        float gm = *gamma;
        float f[4];
#pragma unroll
        for (int p = 0; p < 4; ++p) f[p] = (1.f - gm) + gm * sigm(acc[p]);
#pragma unroll
        for (int ch = 0; ch < 3; ++ch) {
            const float* imb = im + ((size_t)b * 3 + ch) * HW_;
            float* ob = out + ((size_t)b * 3 + ch) * HW_;
#pragma unroll
            for (int pr = 0; pr < 2; ++pr) {
                if (py + pr < H_) {
                    float2 iv = *(const float2*)&imb[(size_t)(py + pr) * W_ + px];
                    float2 ov;
                    ov.x = iv.x * f[pr * 2 + 0];
                    ov.y = iv.y * f[pr * 2 + 1];
                    *(float2*)&ob[(size_t)(py + pr) * W_ + px] = ov;
                }
            }
        }
    }
}

// ---------------------------------------------------------------------------

extern "C" void kernel_launch(void* const* d_in, const int* in_sizes, int n_in,
                              void* d_out, int out_size, void* d_ws,
                              size_t ws_size, hipStream_t stream)
{
    (void)in_sizes; (void)n_in; (void)out_size;

    const float* im  = (const float*)d_in[0];
    const float* w1  = (const float*)d_in[1];
    const float* b1  = (const float*)d_in[2];
    const float* w2  = (const float*)d_in[3];
    const float* b2  = (const float*)d_in[4];
    const float* w3  = (const float*)d_in[5];
    const float* b3  = (const float*)d_in[6];
    const float* w4  = (const float*)d_in[7];
    const float* b4  = (const float*)d_in[8];
    const float* w5  = (const float*)d_in[9];
    const float* b5  = (const float*)d_in[10];
    const float* wc5 = (const float*)d_in[11];
    const float* bc5 = (const float*)d_in[12];
    const float* wc10= (const float*)d_in[13];
    const float* bc10= (const float*)d_in[14];
    const float* wc15= (const float*)d_in[15];
    const float* bc15= (const float*)d_in[16];
    const float* wg  = (const float*)d_in[17];
    const float* bg  = (const float*)d_in[18];
    const float* wm  = (const float*)d_in[19];
    const float* bm  = (const float*)d_in[20];
    const float* bnw = (const float*)d_in[21];
    const float* bnb = (const float*)d_in[22];
    const float* w11 = (const float*)d_in[23];
    const float* b11 = (const float*)d_in[24];
    const float* gam = (const float*)d_in[25];
    float* out = (float*)d_out;

    // ---- workspace plan (chunked batch; deterministic in ws_size) ----------
    const size_t GATED_B = 46080000;
    const size_t PER_IMG = 1440000 + 2880000 + 5760000 + 57600 + 14400 + 6656;
    const size_t MISC    = 262144;
    int c = 32;
    while (c > 1 && GATED_B + MISC + (size_t)c * PER_IMG + 2048 > ws_size)
        c >>= 1;

    char* p = (char*)d_ws;
    auto take = [&](size_t bytes) {
        char* r = p;
        p += (bytes + 255) & ~(size_t)255;
        return r;
    };
    bf16*  GATED = (bf16*)take(GATED_B);
    bf16*  A   = (bf16*)take((size_t)c * 1440000);
    bf16*  Bb  = (bf16*)take((size_t)c * 2880000);
    bf16*  C   = (bf16*)take((size_t)c * 5760000);
    bf16*  P5  = (bf16*)take((size_t)c * 57600);
    bf16*  P10 = (bf16*)take((size_t)c * 14400);
    bf16*  P15 = (bf16*)take((size_t)c * 6656);
    float2* parts = (float2*)take(4096);
    float*  wfold = (float*)take(512);
    unsigned short* WP = (unsigned short*)take(65536);

    unsigned short* PK2  = WP;          // conv2:  3 steps          (1536)
    unsigned short* PK3  = WP + 2048;   // conv3:  5 steps x NG2    (5120)
    unsigned short* PK4  = WP + 8192;   // conv4:  9 steps          (4608)
    unsigned short* PK5  = WP + 13312;  // conv5:  5 steps          (2560)
    unsigned short* PKc5 = WP + 16384;  // convc5                  (2560)
    unsigned short* PKc10= WP + 19456;  // convc10                 (2560)
    unsigned short* PKc15= WP + 22528;  // convc15                 (2560)
    unsigned short* PKg  = WP + 25600;  // gated:  9 steps          (4608)

    dim3 blk(256);

    // ---- prepack weights into B-fragment order ----
    pack_k<<<dim3(1), blk, 0, stream>>>(w2,  nullptr, 999, 16,  8,  8, 3, 1, PK2);
    pack_k<<<dim3(1), blk, 0, stream>>>(w3,  nullptr, 999, 32, 16, 16, 5, 2, PK3);
    pack_k<<<dim3(1), blk, 0, stream>>>(w4,  nullptr, 999, 16, 32, 32, 9, 1, PK4);
    pack_k<<<dim3(1), blk, 0, stream>>>(w5,  nullptr, 999,  8, 16, 16, 5, 1, PK5);
    pack_k<<<dim3(1), blk, 0, stream>>>(wc5, nullptr, 999,  8, 16, 16, 5, 1, PKc5);
    pack_k<<<dim3(1), blk, 0, stream>>>(wc10,nullptr, 999,  8, 16, 16, 5, 1, PKc10);
    pack_k<<<dim3(1), blk, 0, stream>>>(wc15,nullptr, 999,  8, 16, 16, 5, 1, PKc15);
    pack_k<<<dim3(1), blk, 0, stream>>>(wg,  wm,        8, 16, 24, 32, 9, 1, PKg);

    for (int b0 = 0; b0 < NBATCH; b0 += c) {
        dim3 gv(10, 10, c);    // conv1 (VALU, 32x32 tiles)
        dim3 gm(10, 19, c);    // mfconv (32x16 tiles)
        const float* imc = im + (size_t)b0 * 3 * HW_;

        conv_k<float, 3, 3, 8><<<gv, blk, 0, stream>>>(imc, w1, b1, A, 8, 1);

        mfconv_k<8, 8, 8, 16, 1, 0, 1><<<gm, blk, 0, stream>>>(
            A, nullptr, PK2, b2, nullptr, Bb, 16, 0);
        mfconv_k<16, 16, 24, 16, 2, 0, 1><<<dim3(10, 19, 2 * c), blk, 0, stream>>>(
            Bb, nullptr, PK3, b3, nullptr, C, 32, 0);
        mfconv_k<32, 32, 40, 16, 1, 0, 1><<<gm, blk, 0, stream>>>(
            C, nullptr, PK4, b4, nullptr, Bb, 16, 0);
        mfconv_k<16, 16, 24, 8, 1, 0, 1><<<gm, blk, 0, stream>>>(
            Bb, nullptr, PK5, b5, nullptr, A, 8, 0);

        int n5 = c * 8 * 3600, n10 = c * 8 * 900, n15 = c * 8 * 400;
        pool5_k<<<dim3((n5 + 255) / 256), blk, 0, stream>>>(A, P5, n5);
        poolr_k<2, 30><<<dim3((n10 + 255) / 256), blk, 0, stream>>>(P5, P10, n10);
        poolr_k<3, 20><<<dim3((n15 + 255) / 256), blk, 0, stream>>>(P5, P15, n15);

        mfconv_k<8, 16, 24, 8, 1, 1, 5><<<gm, blk, 0, stream>>>(
            A, P5, PKc5, bc5, nullptr, C, 24, 0);
        mfconv_k<8, 16, 24, 8, 1, 1, 10><<<gm, blk, 0, stream>>>(
            A, P10, PKc10, bc10, nullptr, C, 24, 8);
        mfconv_k<8, 16, 24, 8, 1, 1, 15><<<gm, blk, 0, stream>>>(
            A, P15, PKc15, bc15, nullptr, C, 24, 16);

        mfconv_k<24, 32, 40, 16, 1, 2, 1><<<gm, blk, 0, stream>>>(
            C, nullptr, PKg, bg, bm, GATED + (size_t)b0 * 8 * HW_, 8, 0);
    }

    reduce_k<<<dim3(64, 8), blk, 0, stream>>>(GATED, parts);
    stats_fold_k<<<dim3(1), dim3(128), 0, stream>>>(parts, bnw, bnb, w11, b11,
                                                    wfold);
    final_k<<<dim3(10, 10, NBATCH), blk, 0, stream>>>(GATED, wfold, im, gam,
                                                      out);
}

// Round 4
// 728.028 us; speedup vs baseline: 4.3787x; 2.2203x over previous
//
#include <hip/hip_runtime.h>
#include <hip/hip_bf16.h>
#include <math.h>

typedef __hip_bfloat16 bf16;
typedef __attribute__((ext_vector_type(8))) __bf16 bf16x8;
typedef __attribute__((ext_vector_type(8))) unsigned short u16x8;
typedef __attribute__((ext_vector_type(4))) float f32x4;

#define H_ 300
#define W_ 300
#define HW_ 90000
#define NBATCH 32

__device__ __forceinline__ float b2f(unsigned short u) {
    return __uint_as_float((unsigned int)u << 16);
}
__device__ __forceinline__ unsigned short f2u(float v) {
    bf16 b = __float2bfloat16(v);
    return *reinterpret_cast<unsigned short*>(&b);
}
__device__ __forceinline__ float sigm(float x) { return 1.f / (1.f + __expf(-x)); }
__device__ __forceinline__ unsigned int packbf(float a, float b) {
    return (unsigned int)f2u(a) | ((unsigned int)f2u(b) << 16);
}

// ---------------------------------------------------------------------------
// conv1 (fp32 NCHW input, 3ch -> 8ch NHWC bf16). VALU, 32x32 tile.
// ---------------------------------------------------------------------------
__global__ __launch_bounds__(256) void conv1_k(
    const float* __restrict__ in, const float* __restrict__ w,
    const float* __restrict__ bias, unsigned short* __restrict__ out)
{
    __shared__ float s_in[3 * 1156];
    __shared__ float s_w[3 * 9 * 8];

    int b = blockIdx.z;
    int x0 = blockIdx.x * 32, y0 = blockIdx.y * 32;
    int tid = threadIdx.x;

    for (int i = tid; i < 3 * 9 * 8; i += 256) {
        int ci = i / 72;
        int r = i - ci * 72;
        int t = r / 8;
        int co = r - t * 8;
        s_w[i] = w[(co * 3 + ci) * 9 + t];
    }

    const float* inb = in + (size_t)b * 3 * HW_;
    for (int i = tid; i < 3 * 1156; i += 256) {
        int ci = i / 1156;
        int r2 = i - ci * 1156;
        int ry = r2 / 34;
        int rx = r2 - ry * 34;
        int gy = y0 + ry - 1, gx = x0 + rx - 1;
        float v = 0.f;
        if (gy >= 0 && gy < H_ && gx >= 0 && gx < W_)
            v = inb[(size_t)ci * HW_ + (size_t)gy * W_ + gx];
        s_in[i] = v;
    }

    float acc[4][8];
#pragma unroll
    for (int co = 0; co < 8; ++co) {
        float bv = bias[co];
        acc[0][co] = bv; acc[1][co] = bv; acc[2][co] = bv; acc[3][co] = bv;
    }
    __syncthreads();

    int qx = (tid & 15) * 2, qy = (tid >> 4) * 2;
    for (int ci = 0; ci < 3; ++ci) {
        float n[4][4];
#pragma unroll
        for (int r = 0; r < 4; ++r)
#pragma unroll
            for (int c = 0; c < 4; ++c)
                n[r][c] = s_in[ci * 1156 + (qy + r) * 34 + qx + c];
#pragma unroll
        for (int t = 0; t < 9; ++t) {
            int dy = t / 3, dx = t % 3;
#pragma unroll
            for (int co4 = 0; co4 < 2; ++co4) {
                const float4 wv = *(const float4*)&s_w[(ci * 9 + t) * 8 + co4 * 4];
#pragma unroll
                for (int p = 0; p < 4; ++p) {
                    float iv = n[(p >> 1) + dy][(p & 1) + dx];
                    acc[p][co4 * 4 + 0] += iv * wv.x;
                    acc[p][co4 * 4 + 1] += iv * wv.y;
                    acc[p][co4 * 4 + 2] += iv * wv.z;
                    acc[p][co4 * 4 + 3] += iv * wv.w;
                }
            }
        }
    }

    unsigned short* ob = out + (size_t)b * HW_ * 8;
#pragma unroll
    for (int p = 0; p < 4; ++p) {
        int py = y0 + qy + (p >> 1), px = x0 + qx + (p & 1);
        if (py < H_ && px < W_) {
            uint4 st;
            st.x = packbf(acc[p][0], acc[p][1]);
            st.y = packbf(acc[p][2], acc[p][3]);
            st.z = packbf(acc[p][4], acc[p][5]);
            st.w = packbf(acc[p][6], acc[p][7]);
            *(uint4*)&ob[((size_t)py * W_ + px) * 8] = st;
        }
    }
}

// ---------------------------------------------------------------------------
// Weight prepack (unchanged layout; now consumed as the MFMA *A* operand:
// row = lane&15 = co, k = (lane>>4)*8+j). pack[step][g][lane][j] bf16.
// ---------------------------------------------------------------------------
__global__ void pack_k(const float* __restrict__ w0, const float* __restrict__ w1,
                       int co_split, int COUT, int CIN, int CINP, int NSTEP,
                       int NG, unsigned short* __restrict__ outp)
{
    int TPK = 32 / CINP;
    int total = NSTEP * NG * 512;
    for (int idx = threadIdx.x; idx < total; idx += 256) {
        int j = idx & 7;
        int lane = (idx >> 3) & 63;
        int g = (idx >> 9) % NG;
        int s = idx / (512 * NG);
        int col = lane & 15, kg = lane >> 4;
        int kk = kg * 8 + j;
        int tt = kk / CINP, ci = kk % CINP;
        int tap = s * TPK + tt;
        int co = g * 16 + col;
        float v = 0.f;
        if (tap < 9 && ci < CIN && co < COUT) {
            v = (co >= co_split) ? w1[((co - co_split) * CIN + ci) * 9 + tap]
                                 : w0[(co * CIN + ci) * 9 + tap];
        }
        outp[idx] = f2u(v);
    }
}

// ---------------------------------------------------------------------------
// MFMA implicit-GEMM 3x3 conv, NHWC in/out. Tile 32x16 px, 4 waves.
// A = prepacked weights (row=co), B = pixel fragment from LDS (col=px).
// D: lane holds 4 consecutive co (kg*4..+3) for pixel col -> uint2 store.
// MODE 0: plain. MODE 1: oct0 = x(8ch), oct1 = upsampled pool. MODE 2: gated
// (rows 0-7 = g-conv, 8-15 = m-conv; out = g*sigm(m), shfl_xor 32).
// ---------------------------------------------------------------------------
template <int CIN, int CINP, int CS, int COUT, int NG, int MODE, int PK>
__global__ __launch_bounds__(256) void mfconv_k(
    const unsigned short* __restrict__ src, const unsigned short* __restrict__ pool,
    const unsigned short* __restrict__ wpack,
    const float* __restrict__ bias0, const float* __restrict__ bias1,
    unsigned short* __restrict__ out, int co_total, int co_off)
{
    constexpr int TPK = 32 / CINP;
    constexpr int NSTEP = (9 + TPK - 1) / TPK;
    constexpr int OCT = CINP / 8;
    constexpr int OCT_SH = (OCT == 1) ? 0 : (OCT == 2) ? 1 : 2;
    constexpr int PD = (MODE == 1) ? (300 / PK) : 1;
    constexpr int NPX = 18 * 34;

    __shared__ __align__(16) unsigned short s_in[NPX * CS];

    int bz = blockIdx.z;
    int b = bz / NG, g = bz % NG;
    int x0 = blockIdx.x * 32, y0 = blockIdx.y * 16;
    int tid = threadIdx.x;
    int lane = tid & 63, wv = tid >> 6;

    // ---- vectorized NHWC staging: one u16x8 per (pixel, channel-octet) ----
    const unsigned short* sb = src + (size_t)b * CIN * HW_;
    const unsigned short* pb =
        (MODE == 1) ? pool + (size_t)b * 8 * PD * PD : nullptr;
    for (int e = tid; e < NPX * OCT; e += 256) {
        int px = e >> OCT_SH, oct = e & (OCT - 1);
        int y = px / 34, x = px - y * 34;
        int gy = y0 + y - 1, gx = x0 + x - 1;
        u16x8 v = {0, 0, 0, 0, 0, 0, 0, 0};
        if (gy >= 0 && gy < H_ && gx >= 0 && gx < W_) {
            if (MODE == 1) {
                if (oct == 0)
                    v = *(const u16x8*)&sb[((size_t)gy * W_ + gx) * 8];
                else
                    v = *(const u16x8*)&pb[((size_t)(gy / PK) * PD + gx / PK) * 8];
            } else if (oct * 8 < CIN) {
                v = *(const u16x8*)&sb[((size_t)gy * W_ + gx) * CIN + oct * 8];
            }
        }
        *(u16x8*)&s_in[(y * 34 + x) * CS + oct * 8] = v;
    }

    // ---- weight fragments ----
    bf16x8 bw[NSTEP];
#pragma unroll
    for (int s = 0; s < NSTEP; ++s)
        bw[s] = *(const bf16x8*)&wpack[((s * NG + g) * 64 + lane) * 8];

    int col = lane & 15, kg = lane >> 4;

    float bias_r[4];
#pragma unroll
    for (int r = 0; r < 4; ++r) {
        if (MODE == 2)
            bias_r[r] = (kg < 2) ? bias0[kg * 4 + r] : bias1[(kg - 2) * 4 + r];
        else {
            int co_l = g * 16 + kg * 4 + r;
            bias_r[r] = (co_l < COUT) ? bias0[co_l] : 0.f;
        }
    }

    int offs[NSTEP];
#pragma unroll
    for (int s = 0; s < NSTEP; ++s) {
        int t = s * TPK + kg / OCT;
        if (t > 8) t = 8;  // padded taps: B weights are zero there
        offs[s] = ((t / 3) * 34 + (t % 3)) * CS + (kg % OCT) * 8;
    }

    __syncthreads();

    int gx = x0 + col;  // tx added per M-tile
#pragma unroll
    for (int i = 0; i < 8; ++i) {
        int m = wv * 8 + i;
        int my = m >> 1, tx = m & 1;
        int gy = y0 + my;
        if (gy >= H_) continue;  // wave-uniform
        int base = (my * 34 + tx * 16 + col) * CS;

        f32x4 acc = {0.f, 0.f, 0.f, 0.f};
#pragma unroll
        for (int s = 0; s < NSTEP; ++s) {
            bf16x8 a = *(const bf16x8*)&s_in[base + offs[s]];
            acc = __builtin_amdgcn_mfma_f32_16x16x32_bf16(bw[s], a, acc, 0, 0, 0);
        }

        int gxx = gx + tx * 16;
        if (MODE == 2) {
            float v0 = acc.x + bias_r[0], v1 = acc.y + bias_r[1];
            float v2 = acc.z + bias_r[2], v3 = acc.w + bias_r[3];
            float m0 = __shfl_xor(v0, 32), m1 = __shfl_xor(v1, 32);
            float m2 = __shfl_xor(v2, 32), m3 = __shfl_xor(v3, 32);
            if (kg < 2 && gxx < W_) {
                uint2 st;
                st.x = packbf(v0 * sigm(m0), v1 * sigm(m1));
                st.y = packbf(v2 * sigm(m2), v3 * sigm(m3));
                *(uint2*)&out[(((size_t)b * HW_ + (size_t)gy * W_ + gxx) * 8) +
                              kg * 4] = st;
            }
        } else {
            int co_g = g * 16 + kg * 4;
            if (co_g < COUT && gxx < W_) {
                uint2 st;
                st.x = packbf(acc.x + bias_r[0], acc.y + bias_r[1]);
                st.y = packbf(acc.z + bias_r[2], acc.w + bias_r[3]);
                *(uint2*)&out[((size_t)b * HW_ + (size_t)gy * W_ + gxx) *
                                  co_total + co_off + co_g] = st;
            }
        }
    }
}

// ---------------------------------------------------------------------------
// Pools, NHWC (8ch vector per pixel).
// ---------------------------------------------------------------------------
__global__ __launch_bounds__(256) void pool5_k(const unsigned short* __restrict__ x,
                                               unsigned short* __restrict__ p5,
                                               int n)
{
    int idx = blockIdx.x * 256 + threadIdx.x;
    if (idx >= n) return;
    int b = idx / 3600;
    int rem = idx - b * 3600;
    int i = rem / 60, j = rem - i * 60;
    const unsigned short* src =
        x + ((size_t)b * HW_ + (size_t)(i * 5) * W_ + j * 5) * 8;
    float ss[8] = {0, 0, 0, 0, 0, 0, 0, 0};
#pragma unroll
    for (int r = 0; r < 5; ++r)
#pragma unroll
        for (int c = 0; c < 5; ++c) {
            u16x8 v = *(const u16x8*)&src[((size_t)r * W_ + c) * 8];
#pragma unroll
            for (int k = 0; k < 8; ++k) ss[k] += b2f(v[k]);
        }
    uint4 st;
    st.x = packbf(ss[0] * 0.04f, ss[1] * 0.04f);
    st.y = packbf(ss[2] * 0.04f, ss[3] * 0.04f);
    st.z = packbf(ss[4] * 0.04f, ss[5] * 0.04f);
    st.w = packbf(ss[6] * 0.04f, ss[7] * 0.04f);
    *(uint4*)&p5[(size_t)idx * 8] = st;
}

template <int R, int OD>
__global__ __launch_bounds__(256) void poolr_k(const unsigned short* __restrict__ p5,
                                               unsigned short* __restrict__ po,
                                               int n)
{
    int idx = blockIdx.x * 256 + threadIdx.x;
    if (idx >= n) return;
    int b = idx / (OD * OD);
    int rem = idx - b * OD * OD;
    int i = rem / OD, j = rem - i * OD;
    const unsigned short* src =
        p5 + ((size_t)b * 3600 + (size_t)(i * R) * 60 + j * R) * 8;
    float ss[8] = {0, 0, 0, 0, 0, 0, 0, 0};
    const float inv = 1.f / (R * R);
#pragma unroll
    for (int r = 0; r < R; ++r)
#pragma unroll
        for (int c = 0; c < R; ++c) {
            u16x8 v = *(const u16x8*)&src[((size_t)r * 60 + c) * 8];
#pragma unroll
            for (int k = 0; k < 8; ++k) ss[k] += b2f(v[k]);
        }
    uint4 st;
    st.x = packbf(ss[0] * inv, ss[1] * inv);
    st.y = packbf(ss[2] * inv, ss[3] * inv);
    st.z = packbf(ss[4] * inv, ss[5] * inv);
    st.w = packbf(ss[6] * inv, ss[7] * inv);
    *(uint4*)&po[(size_t)idx * 8] = st;
}

// ---------------------------------------------------------------------------
// BN stats over NHWC gated: each thread accumulates all 8 channels.
// ---------------------------------------------------------------------------
__global__ __launch_bounds__(256) void reduce_k(
    const unsigned short* __restrict__ gated, float2* __restrict__ partials)
{
    int bx = blockIdx.x;
    int tid = threadIdx.x;
    float s[8] = {0, 0, 0, 0, 0, 0, 0, 0};
    float s2[8] = {0, 0, 0, 0, 0, 0, 0, 0};
    const size_t N = (size_t)NBATCH * HW_;
    for (size_t i = (size_t)bx * 256 + tid; i < N; i += 64 * 256) {
        u16x8 v = *(const u16x8*)&gated[i * 8];
#pragma unroll
        for (int k = 0; k < 8; ++k) {
            float f = b2f(v[k]);
            s[k] += f;
            s2[k] += f * f;
        }
    }
#pragma unroll
    for (int off = 32; off > 0; off >>= 1) {
#pragma unroll
        for (int k = 0; k < 8; ++k) {
            s[k] += __shfl_down(s[k], off);
            s2[k] += __shfl_down(s2[k], off);
        }
    }
    __shared__ float2 red[4][8];
    int lane = tid & 63, wvi = tid >> 6;
    if (lane == 0) {
#pragma unroll
        for (int k = 0; k < 8; ++k) red[wvi][k] = make_float2(s[k], s2[k]);
    }
    __syncthreads();
    if (tid < 8) {
        float a = 0.f, b2 = 0.f;
        for (int i = 0; i < 4; ++i) { a += red[i][tid].x; b2 += red[i][tid].y; }
        partials[tid * 64 + bx] = make_float2(a, b2);
    }
}

// Fold BN into conv11 weights; output layout wfold[t*8+ci], bias at [72].
__global__ void stats_fold_k(const float2* __restrict__ partials,
                             const float* __restrict__ bn_w,
                             const float* __restrict__ bn_b,
                             const float* __restrict__ w11,
                             const float* __restrict__ b11,
                             float* __restrict__ wfold)
{
    __shared__ float sc[8], tc[8];
    int tid = threadIdx.x;
    if (tid < 8) {
        double s = 0.0, s2 = 0.0;
        for (int i = 0; i < 64; ++i) {
            float2 p = partials[tid * 64 + i];
            s += p.x;
            s2 += p.y;
        }
        double N = (double)NBATCH * HW_;
        double mean = s / N;
        double var = s2 / N - mean * mean;
        float rstd = (float)(1.0 / sqrt(var + 1e-5));
        float scv = bn_w[tid] * rstd;
        sc[tid] = scv;
        tc[tid] = bn_b[tid] - (float)mean * scv;
    }
    __syncthreads();
    if (tid < 72) {
        int t = tid >> 3, ci = tid & 7;
        wfold[tid] = w11[ci * 9 + t] * sc[ci];
    }
    if (tid == 72) {
        float a = b11[0];
        for (int i = 0; i < 72; ++i) a += w11[i] * tc[i / 9];
        wfold[72] = a;
    }
}

// ---------------------------------------------------------------------------
// Final: att = sigmoid(conv 8->1 over NHWC gated), blend with im (NCHW fp32).
// ---------------------------------------------------------------------------
__global__ __launch_bounds__(256) void final_k(
    const unsigned short* __restrict__ gated, const float* __restrict__ wf,
    const float* __restrict__ im, const float* __restrict__ gamma,
    float* __restrict__ out)
{
    __shared__ __align__(16) unsigned short s_g[1156 * 8];
    __shared__ float s_w[80];

    int b = blockIdx.z;
    int x0 = blockIdx.x * 32, y0 = blockIdx.y * 32;
    int tid = threadIdx.x;

    if (tid < 73) s_w[tid] = wf[tid];

    const unsigned short* gb = gated + (size_t)b * HW_ * 8;
    for (int e = tid; e < 1156; e += 256) {
        int y = e / 34, x = e - y * 34;
        int gy = y0 + y - 1, gx = x0 + x - 1;
        u16x8 v = {0, 0, 0, 0, 0, 0, 0, 0};
        if (gy >= 0 && gy < H_ && gx >= 0 && gx < W_)
            v = *(const u16x8*)&gb[((size_t)gy * W_ + gx) * 8];
        *(u16x8*)&s_g[e * 8] = v;
    }
    __syncthreads();

    int qx = (tid & 15) * 2, qy = (tid >> 4) * 2;
    float f[4];
    float gm = *gamma;
#pragma unroll
    for (int p = 0; p < 4; ++p) {
        int ly = qy + (p >> 1), lx = qx + (p & 1);
        float acc = s_w[72];
#pragma unroll
        for (int t = 0; t < 9; ++t) {
            u16x8 n = *(const u16x8*)&s_g[((ly + t / 3) * 34 + lx + t % 3) * 8];
#pragma unroll
            for (int ci = 0; ci < 8; ++ci) acc += b2f(n[ci]) * s_w[t * 8 + ci];
        }
        f[p] = (1.f - gm) + gm * sigm(acc);
    }

    int px = x0 + qx, py = y0 + qy;
    if (px < W_) {
#pragma unroll
        for (int ch = 0; ch < 3; ++ch) {
            const float* imb = im + ((size_t)b * 3 + ch) * HW_;
            float* ob = out + ((size_t)b * 3 + ch) * HW_;
#pragma unroll
            for (int pr = 0; pr < 2; ++pr) {
                if (py + pr < H_) {
                    float2 iv = *(const float2*)&imb[(size_t)(py + pr) * W_ + px];
                    float2 ov;
                    ov.x = iv.x * f[pr * 2 + 0];
                    ov.y = iv.y * f[pr * 2 + 1];
                    *(float2*)&ob[(size_t)(py + pr) * W_ + px] = ov;
                }
            }
        }
    }
}

// ---------------------------------------------------------------------------

extern "C" void kernel_launch(void* const* d_in, const int* in_sizes, int n_in,
                              void* d_out, int out_size, void* d_ws,
                              size_t ws_size, hipStream_t stream)
{
    (void)in_sizes; (void)n_in; (void)out_size;

    const float* im  = (const float*)d_in[0];
    const float* w1  = (const float*)d_in[1];
    const float* b1  = (const float*)d_in[2];
    const float* w2  = (const float*)d_in[3];
    const float* b2  = (const float*)d_in[4];
    const float* w3  = (const float*)d_in[5];
    const float* b3  = (const float*)d_in[6];
    const float* w4  = (const float*)d_in[7];
    const float* b4  = (const float*)d_in[8];
    const float* w5  = (const float*)d_in[9];
    const float* b5  = (const float*)d_in[10];
    const float* wc5 = (const float*)d_in[11];
    const float* bc5 = (const float*)d_in[12];
    const float* wc10= (const float*)d_in[13];
    const float* bc10= (const float*)d_in[14];
    const float* wc15= (const float*)d_in[15];
    const float* bc15= (const float*)d_in[16];
    const float* wg  = (const float*)d_in[17];
    const float* bg  = (const float*)d_in[18];
    const float* wm  = (const float*)d_in[19];
    const float* bm  = (const float*)d_in[20];
    const float* bnw = (const float*)d_in[21];
    const float* bnb = (const float*)d_in[22];
    const float* w11 = (const float*)d_in[23];
    const float* b11 = (const float*)d_in[24];
    const float* gam = (const float*)d_in[25];
    float* out = (float*)d_out;

    // ---- workspace plan (chunked batch; deterministic in ws_size) ----------
    const size_t GATED_B = 46080000;
    const size_t PER_IMG = 1440000 + 2880000 + 5760000 + 57600 + 14400 + 6656;
    const size_t MISC    = 262144;
    int c = 32;
    while (c > 1 && GATED_B + MISC + (size_t)c * PER_IMG + 2048 > ws_size)
        c >>= 1;

    char* p = (char*)d_ws;
    auto take = [&](size_t bytes) {
        char* r = p;
        p += (bytes + 255) & ~(size_t)255;
        return r;
    };
    unsigned short* GATED = (unsigned short*)take(GATED_B);
    unsigned short* A   = (unsigned short*)take((size_t)c * 1440000);
    unsigned short* Bb  = (unsigned short*)take((size_t)c * 2880000);
    unsigned short* C   = (unsigned short*)take((size_t)c * 5760000);
    unsigned short* P5  = (unsigned short*)take((size_t)c * 57600);
    unsigned short* P10 = (unsigned short*)take((size_t)c * 14400);
    unsigned short* P15 = (unsigned short*)take((size_t)c * 6656);
    float2* parts = (float2*)take(4096);
    float*  wfold = (float*)take(512);
    unsigned short* WP = (unsigned short*)take(65536);

    unsigned short* PK2  = WP;
    unsigned short* PK3  = WP + 2048;
    unsigned short* PK4  = WP + 8192;
    unsigned short* PK5  = WP + 13312;
    unsigned short* PKc5 = WP + 16384;
    unsigned short* PKc10= WP + 19456;
    unsigned short* PKc15= WP + 22528;
    unsigned short* PKg  = WP + 25600;

    dim3 blk(256);

    pack_k<<<dim3(1), blk, 0, stream>>>(w2,  nullptr, 999, 16,  8,  8, 3, 1, PK2);
    pack_k<<<dim3(1), blk, 0, stream>>>(w3,  nullptr, 999, 32, 16, 16, 5, 2, PK3);
    pack_k<<<dim3(1), blk, 0, stream>>>(w4,  nullptr, 999, 16, 32, 32, 9, 1, PK4);
    pack_k<<<dim3(1), blk, 0, stream>>>(w5,  nullptr, 999,  8, 16, 16, 5, 1, PK5);
    pack_k<<<dim3(1), blk, 0, stream>>>(wc5, nullptr, 999,  8, 16, 16, 5, 1, PKc5);
    pack_k<<<dim3(1), blk, 0, stream>>>(wc10,nullptr, 999,  8, 16, 16, 5, 1, PKc10);
    pack_k<<<dim3(1), blk, 0, stream>>>(wc15,nullptr, 999,  8, 16, 16, 5, 1, PKc15);
    pack_k<<<dim3(1), blk, 0, stream>>>(wg,  wm,        8, 16, 24, 32, 9, 1, PKg);

    for (int b0 = 0; b0 < NBATCH; b0 += c) {
        dim3 gv(10, 10, c);    // conv1 / final (32x32 tiles)
        dim3 gm(10, 19, c);    // mfconv (32x16 tiles)
        const float* imc = im + (size_t)b0 * 3 * HW_;

        conv1_k<<<gv, blk, 0, stream>>>(imc, w1, b1, A);

        mfconv_k<8, 8, 8, 16, 1, 0, 1><<<gm, blk, 0, stream>>>(
            A, nullptr, PK2, b2, nullptr, Bb, 16, 0);
        mfconv_k<16, 16, 24, 32, 2, 0, 1><<<dim3(10, 19, 2 * c), blk, 0, stream>>>(
            Bb, nullptr, PK3, b3, nullptr, C, 32, 0);
        mfconv_k<32, 32, 40, 16, 1, 0, 1><<<gm, blk, 0, stream>>>(
            C, nullptr, PK4, b4, nullptr, Bb, 16, 0);
        mfconv_k<16, 16, 24, 8, 1, 0, 1><<<gm, blk, 0, stream>>>(
            Bb, nullptr, PK5, b5, nullptr, A, 8, 0);

        int n5 = c * 3600, n10 = c * 900, n15 = c * 400;
        pool5_k<<<dim3((n5 + 255) / 256), blk, 0, stream>>>(A, P5, n5);
        poolr_k<2, 30><<<dim3((n10 + 255) / 256), blk, 0, stream>>>(P5, P10, n10);
        poolr_k<3, 20><<<dim3((n15 + 255) / 256), blk, 0, stream>>>(P5, P15, n15);

        mfconv_k<8, 16, 24, 8, 1, 1, 5><<<gm, blk, 0, stream>>>(
            A, P5, PKc5, bc5, nullptr, C, 24, 0);
        mfconv_k<8, 16, 24, 8, 1, 1, 10><<<gm, blk, 0, stream>>>(
            A, P10, PKc10, bc10, nullptr, C, 24, 8);
        mfconv_k<8, 16, 24, 8, 1, 1, 15><<<gm, blk, 0, stream>>>(
            A, P15, PKc15, bc15, nullptr, C, 24, 16);

        mfconv_k<24, 32, 40, 16, 1, 2, 1><<<gm, blk, 0, stream>>>(
            C, nullptr, PKg, bg, bm, GATED + (size_t)b0 * HW_ * 8, 8, 0);
    }

    reduce_k<<<dim3(64), blk, 0, stream>>>(GATED, parts);
    stats_fold_k<<<dim3(1), dim3(128), 0, stream>>>(parts, bnw, bnb, w11, b11,
                                                    wfold);
    final_k<<<dim3(10, 10, NBATCH), blk, 0, stream>>>(GATED, wfold, im, gam,
                                                      out);
}

// Round 5
// 640.222 us; speedup vs baseline: 4.9793x; 1.1371x over previous
//
#include <hip/hip_runtime.h>
#include <hip/hip_bf16.h>
#include <math.h>

typedef __hip_bfloat16 bf16;
typedef __attribute__((ext_vector_type(8))) __bf16 bf16x8;
typedef __attribute__((ext_vector_type(8))) unsigned short u16x8;
typedef __attribute__((ext_vector_type(4))) float f32x4;

#define H_ 300
#define W_ 300
#define HW_ 90000
#define NBATCH 32

__device__ __forceinline__ float b2f(unsigned short u) {
    return __uint_as_float((unsigned int)u << 16);
}
__device__ __forceinline__ unsigned short f2u(float v) {
    bf16 b = __float2bfloat16(v);
    return *reinterpret_cast<unsigned short*>(&b);
}
__device__ __forceinline__ float sigm(float x) { return 1.f / (1.f + __expf(-x)); }
__device__ __forceinline__ unsigned int packbf(float a, float b) {
    return (unsigned int)f2u(a) | ((unsigned int)f2u(b) << 16);
}

// ---------------------------------------------------------------------------
// Weight prepack into MFMA fragment order (consumed as the A operand:
// row = lane&15 = co, k = (lane>>4)*8+j). pack[step][g][lane][j] bf16.
// ---------------------------------------------------------------------------
__global__ void pack_k(const float* __restrict__ w0, const float* __restrict__ w1,
                       int co_split, int COUT, int CIN, int CINP, int NSTEP,
                       int NG, unsigned short* __restrict__ outp)
{
    int TPK = 32 / CINP;
    int total = NSTEP * NG * 512;
    for (int idx = threadIdx.x; idx < total; idx += 256) {
        int j = idx & 7;
        int lane = (idx >> 3) & 63;
        int g = (idx >> 9) % NG;
        int s = idx / (512 * NG);
        int col = lane & 15, kg = lane >> 4;
        int kk = kg * 8 + j;
        int tt = kk / CINP, ci = kk % CINP;
        int tap = s * TPK + tt;
        int co = g * 16 + col;
        float v = 0.f;
        if (tap < 9 && ci < CIN && co < COUT) {
            v = (co >= co_split) ? w1[((co - co_split) * CIN + ci) * 9 + tap]
                                 : w0[(co * CIN + ci) * 9 + tap];
        }
        outp[idx] = f2u(v);
    }
}

// ---------------------------------------------------------------------------
// MFMA implicit-GEMM 3x3 conv, NHWC in/out. Tile 32x16 px, 4 waves.
// A = prepacked weights (row=co), B = pixel fragment from LDS (col=px).
// D: lane holds 4 consecutive co (kg*4..+3) for pixel col -> uint2 store.
// MODE 0: plain. MODE 1: oct0 = x(8ch), oct1 = upsampled pool.
// MODE 2: gated (rows 0-7 g-conv, 8-15 m-conv; out = g*sigm(m), shfl_xor 32).
// MODE 3: conv1 (src is fp32 NCHW, 3ch -> bf16 LDS channels 0-2, 3-7 zero).
// ---------------------------------------------------------------------------
template <int CIN, int CINP, int CS, int COUT, int NG, int MODE, int PK>
__global__ __launch_bounds__(256) void mfconv_k(
    const unsigned short* __restrict__ src, const unsigned short* __restrict__ pool,
    const unsigned short* __restrict__ wpack,
    const float* __restrict__ bias0, const float* __restrict__ bias1,
    unsigned short* __restrict__ out, int co_total, int co_off)
{
    constexpr int TPK = 32 / CINP;
    constexpr int NSTEP = (9 + TPK - 1) / TPK;
    constexpr int OCT = CINP / 8;
    constexpr int OCT_SH = (OCT == 1) ? 0 : (OCT == 2) ? 1 : 2;
    constexpr int PD = (MODE == 1) ? (300 / PK) : 1;
    constexpr int NPX = 18 * 34;

    __shared__ __align__(16) unsigned short s_in[NPX * CS];

    int bz = blockIdx.z;
    int b = bz / NG, g = bz % NG;
    int x0 = blockIdx.x * 32, y0 = blockIdx.y * 16;
    int tid = threadIdx.x;
    int lane = tid & 63, wv = tid >> 6;

    // ---- staging ----
    if (MODE == 3) {
        const float* sf = reinterpret_cast<const float*>(src) + (size_t)b * 3 * HW_;
        for (int e = tid; e < NPX; e += 256) {
            int y = e / 34, x = e - y * 34;
            int gy = y0 + y - 1, gx = x0 + x - 1;
            u16x8 v = {0, 0, 0, 0, 0, 0, 0, 0};
            if (gy >= 0 && gy < H_ && gx >= 0 && gx < W_) {
                size_t o = (size_t)gy * W_ + gx;
                v[0] = f2u(sf[o]);
                v[1] = f2u(sf[HW_ + o]);
                v[2] = f2u(sf[2 * HW_ + o]);
            }
            *(u16x8*)&s_in[(y * 34 + x) * CS] = v;
        }
    } else {
        const unsigned short* sb = src + (size_t)b * CIN * HW_;
        const unsigned short* pb =
            (MODE == 1) ? pool + (size_t)b * 8 * PD * PD : nullptr;
        for (int e = tid; e < NPX * OCT; e += 256) {
            int px = e >> OCT_SH, oct = e & (OCT - 1);
            int y = px / 34, x = px - y * 34;
            int gy = y0 + y - 1, gx = x0 + x - 1;
            u16x8 v = {0, 0, 0, 0, 0, 0, 0, 0};
            if (gy >= 0 && gy < H_ && gx >= 0 && gx < W_) {
                if (MODE == 1) {
                    if (oct == 0)
                        v = *(const u16x8*)&sb[((size_t)gy * W_ + gx) * 8];
                    else
                        v = *(const u16x8*)&pb[((size_t)(gy / PK) * PD + gx / PK) * 8];
                } else if (oct * 8 < CIN) {
                    v = *(const u16x8*)&sb[((size_t)gy * W_ + gx) * CIN + oct * 8];
                }
            }
            *(u16x8*)&s_in[(y * 34 + x) * CS + oct * 8] = v;
        }
    }

    // ---- weight fragments ----
    bf16x8 bw[NSTEP];
#pragma unroll
    for (int s = 0; s < NSTEP; ++s)
        bw[s] = *(const bf16x8*)&wpack[((s * NG + g) * 64 + lane) * 8];

    int col = lane & 15, kg = lane >> 4;

    float bias_r[4];
#pragma unroll
    for (int r = 0; r < 4; ++r) {
        if (MODE == 2)
            bias_r[r] = (kg < 2) ? bias0[kg * 4 + r] : bias1[(kg - 2) * 4 + r];
        else {
            int co_l = g * 16 + kg * 4 + r;
            bias_r[r] = (co_l < COUT) ? bias0[co_l] : 0.f;
        }
    }

    int offs[NSTEP];
#pragma unroll
    for (int s = 0; s < NSTEP; ++s) {
        int t = s * TPK + kg / OCT;
        if (t > 8) t = 8;  // padded taps: weights are zero there
        offs[s] = ((t / 3) * 34 + (t % 3)) * CS + (kg % OCT) * 8;
    }

    __syncthreads();

    int gx = x0 + col;
#pragma unroll
    for (int i = 0; i < 8; ++i) {
        int m = wv * 8 + i;
        int my = m >> 1, tx = m & 1;
        int gy = y0 + my;
        if (gy >= H_) continue;  // wave-uniform
        int base = (my * 34 + tx * 16 + col) * CS;

        f32x4 acc = {0.f, 0.f, 0.f, 0.f};
#pragma unroll
        for (int s = 0; s < NSTEP; ++s) {
            bf16x8 a = *(const bf16x8*)&s_in[base + offs[s]];
            acc = __builtin_amdgcn_mfma_f32_16x16x32_bf16(bw[s], a, acc, 0, 0, 0);
        }

        int gxx = gx + tx * 16;
        if (MODE == 2) {
            float v0 = acc.x + bias_r[0], v1 = acc.y + bias_r[1];
            float v2 = acc.z + bias_r[2], v3 = acc.w + bias_r[3];
            float m0 = __shfl_xor(v0, 32), m1 = __shfl_xor(v1, 32);
            float m2 = __shfl_xor(v2, 32), m3 = __shfl_xor(v3, 32);
            if (kg < 2 && gxx < W_) {
                uint2 st;
                st.x = packbf(v0 * sigm(m0), v1 * sigm(m1));
                st.y = packbf(v2 * sigm(m2), v3 * sigm(m3));
                *(uint2*)&out[(((size_t)b * HW_ + (size_t)gy * W_ + gxx) * 8) +
                              kg * 4] = st;
            }
        } else {
            int co_g = g * 16 + kg * 4;
            if (co_g < COUT && gxx < W_) {
                uint2 st;
                st.x = packbf(acc.x + bias_r[0], acc.y + bias_r[1]);
                st.y = packbf(acc.z + bias_r[2], acc.w + bias_r[3]);
                *(uint2*)&out[((size_t)b * HW_ + (size_t)gy * W_ + gxx) *
                                  co_total + co_off + co_g] = st;
            }
        }
    }
}

// ---------------------------------------------------------------------------
// Fused cK trio: stage x + up5 + up10 + up15 as 4 octets (CS=40), run the
// three 16->8 convs off the shared tile, write 24-ch NHWC g_in directly.
// wpack = PKc5 | PKc10 | PKc15 contiguous (5 steps x 512 each).
// ---------------------------------------------------------------------------
__global__ __launch_bounds__(256) void convc3_k(
    const unsigned short* __restrict__ src,
    const unsigned short* __restrict__ p5, const unsigned short* __restrict__ p10,
    const unsigned short* __restrict__ p15,
    const unsigned short* __restrict__ wpack,
    const float* __restrict__ bc5, const float* __restrict__ bc10,
    const float* __restrict__ bc15, unsigned short* __restrict__ out)
{
    constexpr int CS = 40;
    constexpr int NPX = 18 * 34;
    __shared__ __align__(16) unsigned short s_in[NPX * CS];

    int b = blockIdx.z;
    int x0 = blockIdx.x * 32, y0 = blockIdx.y * 16;
    int tid = threadIdx.x;
    int lane = tid & 63, wv = tid >> 6;

    const unsigned short* sb = src + (size_t)b * 8 * HW_;
    const unsigned short* pb5 = p5 + (size_t)b * 8 * 3600;
    const unsigned short* pb10 = p10 + (size_t)b * 8 * 900;
    const unsigned short* pb15 = p15 + (size_t)b * 8 * 400;

    for (int e = tid; e < NPX * 4; e += 256) {
        int px = e >> 2, oct = e & 3;
        int y = px / 34, x = px - y * 34;
        int gy = y0 + y - 1, gx = x0 + x - 1;
        u16x8 v = {0, 0, 0, 0, 0, 0, 0, 0};
        if (gy >= 0 && gy < H_ && gx >= 0 && gx < W_) {
            if (oct == 0)
                v = *(const u16x8*)&sb[((size_t)gy * W_ + gx) * 8];
            else if (oct == 1)
                v = *(const u16x8*)&pb5[((size_t)(gy / 5) * 60 + gx / 5) * 8];
            else if (oct == 2)
                v = *(const u16x8*)&pb10[((size_t)(gy / 10) * 30 + gx / 10) * 8];
            else
                v = *(const u16x8*)&pb15[((size_t)(gy / 15) * 20 + gx / 15) * 8];
        }
        *(u16x8*)&s_in[(y * 34 + x) * CS + oct * 8] = v;
    }

    bf16x8 bw[3][5];
#pragma unroll
    for (int i = 0; i < 3; ++i)
#pragma unroll
        for (int s = 0; s < 5; ++s)
            bw[i][s] = *(const bf16x8*)&wpack[((i * 5 + s) * 64 + lane) * 8];

    int col = lane & 15, kg = lane >> 4;
    float bias_r[3][4];
#pragma unroll
    for (int r = 0; r < 4; ++r) {
        int co_l = kg * 4 + r;
        bias_r[0][r] = (kg < 2) ? bc5[co_l] : 0.f;
        bias_r[1][r] = (kg < 2) ? bc10[co_l] : 0.f;
        bias_r[2][r] = (kg < 2) ? bc15[co_l] : 0.f;
    }

    int offt[5];
#pragma unroll
    for (int s = 0; s < 5; ++s) {
        int t = s * 2 + (kg >> 1);
        if (t > 8) t = 8;
        offt[s] = ((t / 3) * 34 + (t % 3)) * CS;
    }
    int octoff[3];
#pragma unroll
    for (int i = 0; i < 3; ++i) octoff[i] = ((kg & 1) ? (1 + i) : 0) * 8;

    __syncthreads();

#pragma unroll
    for (int i8 = 0; i8 < 8; ++i8) {
        int m = wv * 8 + i8;
        int my = m >> 1, tx = m & 1;
        int gy = y0 + my;
        if (gy >= H_) continue;
        int base = (my * 34 + tx * 16 + col) * CS;

        f32x4 acc[3];
#pragma unroll
        for (int i = 0; i < 3; ++i) acc[i] = {0.f, 0.f, 0.f, 0.f};
#pragma unroll
        for (int s = 0; s < 5; ++s) {
#pragma unroll
            for (int i = 0; i < 3; ++i) {
                bf16x8 a = *(const bf16x8*)&s_in[base + offt[s] + octoff[i]];
                acc[i] =
                    __builtin_amdgcn_mfma_f32_16x16x32_bf16(bw[i][s], a, acc[i], 0, 0, 0);
            }
        }

        int gxx = x0 + tx * 16 + col;
        if (kg < 2 && gxx < W_) {
            size_t pxo = ((size_t)b * HW_ + (size_t)gy * W_ + gxx) * 24;
#pragma unroll
            for (int i = 0; i < 3; ++i) {
                uint2 st;
                st.x = packbf(acc[i].x + bias_r[i][0], acc[i].y + bias_r[i][1]);
                st.y = packbf(acc[i].z + bias_r[i][2], acc[i].w + bias_r[i][3]);
                *(uint2*)&out[pxo + i * 8 + kg * 4] = st;
            }
        }
    }
}

// ---------------------------------------------------------------------------
// Pools, NHWC (8ch vector per pixel).
// ---------------------------------------------------------------------------
__global__ __launch_bounds__(256) void pool5_k(const unsigned short* __restrict__ x,
                                               unsigned short* __restrict__ p5,
                                               int n)
{
    int idx = blockIdx.x * 256 + threadIdx.x;
    if (idx >= n) return;
    int b = idx / 3600;
    int rem = idx - b * 3600;
    int i = rem / 60, j = rem - i * 60;
    const unsigned short* src =
        x + ((size_t)b * HW_ + (size_t)(i * 5) * W_ + j * 5) * 8;
    float ss[8] = {0, 0, 0, 0, 0, 0, 0, 0};
#pragma unroll
    for (int r = 0; r < 5; ++r)
#pragma unroll
        for (int c = 0; c < 5; ++c) {
            u16x8 v = *(const u16x8*)&src[((size_t)r * W_ + c) * 8];
#pragma unroll
            for (int k = 0; k < 8; ++k) ss[k] += b2f(v[k]);
        }
    uint4 st;
    st.x = packbf(ss[0] * 0.04f, ss[1] * 0.04f);
    st.y = packbf(ss[2] * 0.04f, ss[3] * 0.04f);
    st.z = packbf(ss[4] * 0.04f, ss[5] * 0.04f);
    st.w = packbf(ss[6] * 0.04f, ss[7] * 0.04f);
    *(uint4*)&p5[(size_t)idx * 8] = st;
}

template <int R, int OD>
__global__ __launch_bounds__(256) void poolr_k(const unsigned short* __restrict__ p5,
                                               unsigned short* __restrict__ po,
                                               int n)
{
    int idx = blockIdx.x * 256 + threadIdx.x;
    if (idx >= n) return;
    int b = idx / (OD * OD);
    int rem = idx - b * OD * OD;
    int i = rem / OD, j = rem - i * OD;
    const unsigned short* src =
        p5 + ((size_t)b * 3600 + (size_t)(i * R) * 60 + j * R) * 8;
    float ss[8] = {0, 0, 0, 0, 0, 0, 0, 0};
    const float inv = 1.f / (R * R);
#pragma unroll
    for (int r = 0; r < R; ++r)
#pragma unroll
        for (int c = 0; c < R; ++c) {
            u16x8 v = *(const u16x8*)&src[((size_t)r * 60 + c) * 8];
#pragma unroll
            for (int k = 0; k < 8; ++k) ss[k] += b2f(v[k]);
        }
    uint4 st;
    st.x = packbf(ss[0] * inv, ss[1] * inv);
    st.y = packbf(ss[2] * inv, ss[3] * inv);
    st.z = packbf(ss[4] * inv, ss[5] * inv);
    st.w = packbf(ss[6] * inv, ss[7] * inv);
    *(uint4*)&po[(size_t)idx * 8] = st;
}

// ---------------------------------------------------------------------------
// BN stats over NHWC gated.
// ---------------------------------------------------------------------------
__global__ __launch_bounds__(256) void reduce_k(
    const unsigned short* __restrict__ gated, float2* __restrict__ partials)
{
    int bx = blockIdx.x;
    int tid = threadIdx.x;
    float s[8] = {0, 0, 0, 0, 0, 0, 0, 0};
    float s2[8] = {0, 0, 0, 0, 0, 0, 0, 0};
    const size_t N = (size_t)NBATCH * HW_;
    for (size_t i = (size_t)bx * 256 + tid; i < N; i += 64 * 256) {
        u16x8 v = *(const u16x8*)&gated[i * 8];
#pragma unroll
        for (int k = 0; k < 8; ++k) {
            float f = b2f(v[k]);
            s[k] += f;
            s2[k] += f * f;
        }
    }
#pragma unroll
    for (int off = 32; off > 0; off >>= 1) {
#pragma unroll
        for (int k = 0; k < 8; ++k) {
            s[k] += __shfl_down(s[k], off);
            s2[k] += __shfl_down(s2[k], off);
        }
    }
    __shared__ float2 red[4][8];
    int lane = tid & 63, wvi = tid >> 6;
    if (lane == 0) {
#pragma unroll
        for (int k = 0; k < 8; ++k) red[wvi][k] = make_float2(s[k], s2[k]);
    }
    __syncthreads();
    if (tid < 8) {
        float a = 0.f, b2 = 0.f;
        for (int i = 0; i < 4; ++i) { a += red[i][tid].x; b2 += red[i][tid].y; }
        partials[tid * 64 + bx] = make_float2(a, b2);
    }
}

// Fold BN into conv11 weights; output layout wfold[t*8+ci], bias at [72].
__global__ void stats_fold_k(const float2* __restrict__ partials,
                             const float* __restrict__ bn_w,
                             const float* __restrict__ bn_b,
                             const float* __restrict__ w11,
                             const float* __restrict__ b11,
                             float* __restrict__ wfold)
{
    __shared__ float sc[8], tc[8];
    int tid = threadIdx.x;
    if (tid < 8) {
        double s = 0.0, s2 = 0.0;
        for (int i = 0; i < 64; ++i) {
            float2 p = partials[tid * 64 + i];
            s += p.x;
            s2 += p.y;
        }
        double N = (double)NBATCH * HW_;
        double mean = s / N;
        double var = s2 / N - mean * mean;
        float rstd = (float)(1.0 / sqrt(var + 1e-5));
        float scv = bn_w[tid] * rstd;
        sc[tid] = scv;
        tc[tid] = bn_b[tid] - (float)mean * scv;
    }
    __syncthreads();
    if (tid < 72) {
        int t = tid >> 3, ci = tid & 7;
        wfold[tid] = w11[ci * 9 + t] * sc[ci];
    }
    if (tid == 72) {
        float a = b11[0];
        for (int i = 0; i < 72; ++i) a += w11[i] * tc[i / 9];
        wfold[72] = a;
    }
}

// ---------------------------------------------------------------------------
// Final: att = sigmoid(conv 8->1 over NHWC gated), blend with im (NCHW fp32).
// ---------------------------------------------------------------------------
__global__ __launch_bounds__(256) void final_k(
    const unsigned short* __restrict__ gated, const float* __restrict__ wf,
    const float* __restrict__ im, const float* __restrict__ gamma,
    float* __restrict__ out)
{
    __shared__ __align__(16) unsigned short s_g[1156 * 8];
    __shared__ float s_w[80];

    int b = blockIdx.z;
    int x0 = blockIdx.x * 32, y0 = blockIdx.y * 32;
    int tid = threadIdx.x;

    if (tid < 73) s_w[tid] = wf[tid];

    const unsigned short* gb = gated + (size_t)b * HW_ * 8;
    for (int e = tid; e < 1156; e += 256) {
        int y = e / 34, x = e - y * 34;
        int gy = y0 + y - 1, gx = x0 + x - 1;
        u16x8 v = {0, 0, 0, 0, 0, 0, 0, 0};
        if (gy >= 0 && gy < H_ && gx >= 0 && gx < W_)
            v = *(const u16x8*)&gb[((size_t)gy * W_ + gx) * 8];
        *(u16x8*)&s_g[e * 8] = v;
    }
    __syncthreads();

    int qx = (tid & 15) * 2, qy = (tid >> 4) * 2;
    float f[4];
    float gm = *gamma;
#pragma unroll
    for (int p = 0; p < 4; ++p) {
        int ly = qy + (p >> 1), lx = qx + (p & 1);
        float acc = s_w[72];
#pragma unroll
        for (int t = 0; t < 9; ++t) {
            u16x8 n = *(const u16x8*)&s_g[((ly + t / 3) * 34 + lx + t % 3) * 8];
#pragma unroll
            for (int ci = 0; ci < 8; ++ci) acc += b2f(n[ci]) * s_w[t * 8 + ci];
        }
        f[p] = (1.f - gm) + gm * sigm(acc);
    }

    int px = x0 + qx, py = y0 + qy;
    if (px < W_) {
#pragma unroll
        for (int ch = 0; ch < 3; ++ch) {
            const float* imb = im + ((size_t)b * 3 + ch) * HW_;
            float* ob = out + ((size_t)b * 3 + ch) * HW_;
#pragma unroll
            for (int pr = 0; pr < 2; ++pr) {
                if (py + pr < H_) {
                    float2 iv = *(const float2*)&imb[(size_t)(py + pr) * W_ + px];
                    float2 ov;
                    ov.x = iv.x * f[pr * 2 + 0];
                    ov.y = iv.y * f[pr * 2 + 1];
                    *(float2*)&ob[(size_t)(py + pr) * W_ + px] = ov;
                }
            }
        }
    }
}

// ---------------------------------------------------------------------------

extern "C" void kernel_launch(void* const* d_in, const int* in_sizes, int n_in,
                              void* d_out, int out_size, void* d_ws,
                              size_t ws_size, hipStream_t stream)
{
    (void)in_sizes; (void)n_in; (void)out_size;

    const float* im  = (const float*)d_in[0];
    const float* w1  = (const float*)d_in[1];
    const float* b1  = (const float*)d_in[2];
    const float* w2  = (const float*)d_in[3];
    const float* b2  = (const float*)d_in[4];
    const float* w3  = (const float*)d_in[5];
    const float* b3  = (const float*)d_in[6];
    const float* w4  = (const float*)d_in[7];
    const float* b4  = (const float*)d_in[8];
    const float* w5  = (const float*)d_in[9];
    const float* b5  = (const float*)d_in[10];
    const float* wc5 = (const float*)d_in[11];
    const float* bc5 = (const float*)d_in[12];
    const float* wc10= (const float*)d_in[13];
    const float* bc10= (const float*)d_in[14];
    const float* wc15= (const float*)d_in[15];
    const float* bc15= (const float*)d_in[16];
    const float* wg  = (const float*)d_in[17];
    const float* bg  = (const float*)d_in[18];
    const float* wm  = (const float*)d_in[19];
    const float* bm  = (const float*)d_in[20];
    const float* bnw = (const float*)d_in[21];
    const float* bnb = (const float*)d_in[22];
    const float* w11 = (const float*)d_in[23];
    const float* b11 = (const float*)d_in[24];
    const float* gam = (const float*)d_in[25];
    float* out = (float*)d_out;

    // ---- workspace plan (chunked batch; deterministic in ws_size) ----------
    const size_t GATED_B = 46080000;
    const size_t PER_IMG = 1440000 + 2880000 + 5760000 + 57600 + 14400 + 6656;
    const size_t MISC    = 262144;
    int c = 32;
    while (c > 1 && GATED_B + MISC + (size_t)c * PER_IMG + 2048 > ws_size)
        c >>= 1;

    char* p = (char*)d_ws;
    auto take = [&](size_t bytes) {
        char* r = p;
        p += (bytes + 255) & ~(size_t)255;
        return r;
    };
    unsigned short* GATED = (unsigned short*)take(GATED_B);
    unsigned short* A   = (unsigned short*)take((size_t)c * 1440000);
    unsigned short* Bb  = (unsigned short*)take((size_t)c * 2880000);
    unsigned short* C   = (unsigned short*)take((size_t)c * 5760000);
    unsigned short* P5  = (unsigned short*)take((size_t)c * 57600);
    unsigned short* P10 = (unsigned short*)take((size_t)c * 14400);
    unsigned short* P15 = (unsigned short*)take((size_t)c * 6656);
    float2* parts = (float2*)take(4096);
    float*  wfold = (float*)take(512);
    unsigned short* WP = (unsigned short*)take(65536);

    unsigned short* PK2  = WP;            // conv2: 3 steps (1536)
    unsigned short* PK3  = WP + 2048;     // conv3: 5x2    (5120)
    unsigned short* PK4  = WP + 8192;     // conv4: 9      (4608)
    unsigned short* PK5  = WP + 13312;    // conv5: 5      (2560)
    unsigned short* PKc  = WP + 16384;    // c5|c10|c15 contiguous (3x2560)
    unsigned short* PKg  = WP + 25600;    // gated: 9     (4608)
    unsigned short* PK1  = WP + 30720;    // conv1: 3     (1536)

    dim3 blk(256);

    pack_k<<<dim3(1), blk, 0, stream>>>(w1,  nullptr, 999,  8,  3,  8, 3, 1, PK1);
    pack_k<<<dim3(1), blk, 0, stream>>>(w2,  nullptr, 999, 16,  8,  8, 3, 1, PK2);
    pack_k<<<dim3(1), blk, 0, stream>>>(w3,  nullptr, 999, 32, 16, 16, 5, 2, PK3);
    pack_k<<<dim3(1), blk, 0, stream>>>(w4,  nullptr, 999, 16, 32, 32, 9, 1, PK4);
    pack_k<<<dim3(1), blk, 0, stream>>>(w5,  nullptr, 999,  8, 16, 16, 5, 1, PK5);
    pack_k<<<dim3(1), blk, 0, stream>>>(wc5, nullptr, 999,  8, 16, 16, 5, 1, PKc);
    pack_k<<<dim3(1), blk, 0, stream>>>(wc10,nullptr, 999,  8, 16, 16, 5, 1, PKc + 2560);
    pack_k<<<dim3(1), blk, 0, stream>>>(wc15,nullptr, 999,  8, 16, 16, 5, 1, PKc + 5120);
    pack_k<<<dim3(1), blk, 0, stream>>>(wg,  wm,        8, 16, 24, 32, 9, 1, PKg);

    for (int b0 = 0; b0 < NBATCH; b0 += c) {
        dim3 gm(10, 19, c);    // mfconv / convc3 (32x16 tiles)
        const float* imc = im + (size_t)b0 * 3 * HW_;

        mfconv_k<8, 8, 8, 8, 1, 3, 1><<<gm, blk, 0, stream>>>(
            (const unsigned short*)imc, nullptr, PK1, b1, nullptr, A, 8, 0);

        mfconv_k<8, 8, 8, 16, 1, 0, 1><<<gm, blk, 0, stream>>>(
            A, nullptr, PK2, b2, nullptr, Bb, 16, 0);
        mfconv_k<16, 16, 24, 32, 2, 0, 1><<<dim3(10, 19, 2 * c), blk, 0, stream>>>(
            Bb, nullptr, PK3, b3, nullptr, C, 32, 0);
        mfconv_k<32, 32, 40, 16, 1, 0, 1><<<gm, blk, 0, stream>>>(
            C, nullptr, PK4, b4, nullptr, Bb, 16, 0);
        mfconv_k<16, 16, 24, 8, 1, 0, 1><<<gm, blk, 0, stream>>>(
            Bb, nullptr, PK5, b5, nullptr, A, 8, 0);

        int n5 = c * 3600, n10 = c * 900, n15 = c * 400;
        pool5_k<<<dim3((n5 + 255) / 256), blk, 0, stream>>>(A, P5, n5);
        poolr_k<2, 30><<<dim3((n10 + 255) / 256), blk, 0, stream>>>(P5, P10, n10);
        poolr_k<3, 20><<<dim3((n15 + 255) / 256), blk, 0, stream>>>(P5, P15, n15);

        convc3_k<<<gm, blk, 0, stream>>>(A, P5, P10, P15, PKc, bc5, bc10, bc15, C);

        mfconv_k<24, 32, 40, 16, 1, 2, 1><<<gm, blk, 0, stream>>>(
            C, nullptr, PKg, bg, bm, GATED + (size_t)b0 * HW_ * 8, 8, 0);
    }

    reduce_k<<<dim3(64), blk, 0, stream>>>(GATED, parts);
    stats_fold_k<<<dim3(1), dim3(128), 0, stream>>>(parts, bnw, bnb, w11, b11,
                                                    wfold);
    final_k<<<dim3(10, 10, NBATCH), blk, 0, stream>>>(GATED, wfold, im, gam,
                                                      out);
}

// Round 6
// 570.176 us; speedup vs baseline: 5.5910x; 1.1229x over previous
//
#include <hip/hip_runtime.h>
#include <hip/hip_bf16.h>
#include <math.h>

typedef __hip_bfloat16 bf16;
typedef __attribute__((ext_vector_type(8))) __bf16 bf16x8;
typedef __attribute__((ext_vector_type(8))) unsigned short u16x8;
typedef __attribute__((ext_vector_type(4))) float f32x4;

#define H_ 300
#define W_ 300
#define HW_ 90000
#define NBATCH 32

__device__ __forceinline__ float b2f(unsigned short u) {
    return __uint_as_float((unsigned int)u << 16);
}
__device__ __forceinline__ unsigned short f2u(float v) {
    bf16 b = __float2bfloat16(v);
    return *reinterpret_cast<unsigned short*>(&b);
}
__device__ __forceinline__ float sigm(float x) { return 1.f / (1.f + __expf(-x)); }
__device__ __forceinline__ unsigned int packbf(float a, float b) {
    return (unsigned int)f2u(a) | ((unsigned int)f2u(b) << 16);
}

// ---------------------------------------------------------------------------
// Weight prepack into MFMA fragment order (consumed as the A operand:
// row = lane&15 = co, k = (lane>>4)*8+j). pack[step][g][lane][j] bf16.
// ---------------------------------------------------------------------------
__global__ void pack_k(const float* __restrict__ w0, const float* __restrict__ w1,
                       int co_split, int COUT, int CIN, int CINP, int NSTEP,
                       int NG, unsigned short* __restrict__ outp)
{
    int TPK = 32 / CINP;
    int total = NSTEP * NG * 512;
    for (int idx = threadIdx.x; idx < total; idx += 256) {
        int j = idx & 7;
        int lane = (idx >> 3) & 63;
        int g = (idx >> 9) % NG;
        int s = idx / (512 * NG);
        int col = lane & 15, kg = lane >> 4;
        int kk = kg * 8 + j;
        int tt = kk / CINP, ci = kk % CINP;
        int tap = s * TPK + tt;
        int co = g * 16 + col;
        float v = 0.f;
        if (tap < 9 && ci < CIN && co < COUT) {
            v = (co >= co_split) ? w1[((co - co_split) * CIN + ci) * 9 + tap]
                                 : w0[(co * CIN + ci) * 9 + tap];
        }
        outp[idx] = f2u(v);
    }
}

// ---------------------------------------------------------------------------
// MFMA implicit-GEMM 3x3 conv, NHWC in/out. Tile 32x16 px, 4 waves.
// LDS is OCTET-PLANAR: s_in[oct][18*34 px][8ch] -> a lane's fragment is 16
// consecutive bytes at 16B pixel stride => bank-conflict-free ds_read_b128.
// A = prepacked weights (row=co), B = pixel fragment from LDS (col=px).
// NGI output groups per block share every A-fragment read (conv3: NGI=2).
// MODE 0: plain. MODE 2: gated (rows 0-7 g, 8-15 m; out = g*sigm(m)).
// MODE 3: conv1 (src fp32 NCHW 3ch -> LDS ch 0-2, 3-7 zero).
// ---------------------------------------------------------------------------
template <int CIN, int CINP, int COUT, int NGI, int MODE, int PK>
__global__ __launch_bounds__(256) void mfconv_k(
    const unsigned short* __restrict__ src, const unsigned short* __restrict__ pool,
    const unsigned short* __restrict__ wpack,
    const float* __restrict__ bias0, const float* __restrict__ bias1,
    unsigned short* __restrict__ out, int co_total, int co_off)
{
    constexpr int TPK = 32 / CINP;
    constexpr int NSTEP = (9 + TPK - 1) / TPK;
    constexpr int OCT = CINP / 8;
    constexpr int OCT_SH = (OCT == 1) ? 0 : (OCT == 2) ? 1 : 2;
    constexpr int NPX = 18 * 34;
    (void)pool;

    __shared__ __align__(16) unsigned short s_in[OCT * NPX * 8];

    int b = blockIdx.z;
    int x0 = blockIdx.x * 32, y0 = blockIdx.y * 16;
    int tid = threadIdx.x;
    int lane = tid & 63, wv = tid >> 6;

    // ---- staging (planar octets) ----
    if (MODE == 3) {
        const float* sf = reinterpret_cast<const float*>(src) + (size_t)b * 3 * HW_;
        for (int e = tid; e < NPX; e += 256) {
            int y = e / 34, x = e - y * 34;
            int gy = y0 + y - 1, gx = x0 + x - 1;
            u16x8 v = {0, 0, 0, 0, 0, 0, 0, 0};
            if (gy >= 0 && gy < H_ && gx >= 0 && gx < W_) {
                size_t o = (size_t)gy * W_ + gx;
                v[0] = f2u(sf[o]);
                v[1] = f2u(sf[HW_ + o]);
                v[2] = f2u(sf[2 * HW_ + o]);
            }
            *(u16x8*)&s_in[(y * 34 + x) * 8] = v;
        }
    } else {
        const unsigned short* sb = src + (size_t)b * CIN * HW_;
        for (int e = tid; e < NPX * OCT; e += 256) {
            int px = e >> OCT_SH, oct = e & (OCT - 1);
            int y = px / 34, x = px - y * 34;
            int gy = y0 + y - 1, gx = x0 + x - 1;
            u16x8 v = {0, 0, 0, 0, 0, 0, 0, 0};
            if (gy >= 0 && gy < H_ && gx >= 0 && gx < W_ && oct * 8 < CIN)
                v = *(const u16x8*)&sb[((size_t)gy * W_ + gx) * CIN + oct * 8];
            *(u16x8*)&s_in[(oct * NPX + y * 34 + x) * 8] = v;
        }
    }

    // ---- weight fragments (NGI groups) ----
    bf16x8 bw[NGI][NSTEP];
#pragma unroll
    for (int gi = 0; gi < NGI; ++gi)
#pragma unroll
        for (int s = 0; s < NSTEP; ++s)
            bw[gi][s] = *(const bf16x8*)&wpack[((s * NGI + gi) * 64 + lane) * 8];

    int col = lane & 15, kg = lane >> 4;

    float bias_r[NGI][4];
#pragma unroll
    for (int gi = 0; gi < NGI; ++gi)
#pragma unroll
        for (int r = 0; r < 4; ++r) {
            if (MODE == 2)
                bias_r[0][r] = (kg < 2) ? bias0[kg * 4 + r] : bias1[(kg - 2) * 4 + r];
            else {
                int co_l = gi * 16 + kg * 4 + r;
                bias_r[gi][r] = (co_l < COUT) ? bias0[co_l] : 0.f;
            }
        }

    int offs[NSTEP];
#pragma unroll
    for (int s = 0; s < NSTEP; ++s) {
        int t = s * TPK + kg / OCT;
        if (t > 8) t = 8;  // padded taps: weights are zero there
        offs[s] = ((t / 3) * 34 + (t % 3)) * 8 + (kg % OCT) * (NPX * 8);
    }

    __syncthreads();

#pragma unroll
    for (int i = 0; i < 8; ++i) {
        int m = wv * 8 + i;
        int my = m >> 1, tx = m & 1;
        int gy = y0 + my;
        if (gy >= H_) continue;  // wave-uniform
        int base = (my * 34 + tx * 16 + col) * 8;

        f32x4 acc[NGI];
#pragma unroll
        for (int gi = 0; gi < NGI; ++gi) acc[gi] = {0.f, 0.f, 0.f, 0.f};
#pragma unroll
        for (int s = 0; s < NSTEP; ++s) {
            bf16x8 a = *(const bf16x8*)&s_in[base + offs[s]];
#pragma unroll
            for (int gi = 0; gi < NGI; ++gi)
                acc[gi] =
                    __builtin_amdgcn_mfma_f32_16x16x32_bf16(bw[gi][s], a, acc[gi], 0, 0, 0);
        }

        int gxx = x0 + tx * 16 + col;
        if (MODE == 2) {
            float v0 = acc[0].x + bias_r[0][0], v1 = acc[0].y + bias_r[0][1];
            float v2 = acc[0].z + bias_r[0][2], v3 = acc[0].w + bias_r[0][3];
            float m0 = __shfl_xor(v0, 32), m1 = __shfl_xor(v1, 32);
            float m2 = __shfl_xor(v2, 32), m3 = __shfl_xor(v3, 32);
            if (kg < 2 && gxx < W_) {
                uint2 st;
                st.x = packbf(v0 * sigm(m0), v1 * sigm(m1));
                st.y = packbf(v2 * sigm(m2), v3 * sigm(m3));
                *(uint2*)&out[(((size_t)b * HW_ + (size_t)gy * W_ + gxx) * 8) +
                              kg * 4] = st;
            }
        } else {
#pragma unroll
            for (int gi = 0; gi < NGI; ++gi) {
                int co_g = gi * 16 + kg * 4;
                if (co_g < COUT && gxx < W_) {
                    uint2 st;
                    st.x = packbf(acc[gi].x + bias_r[gi][0], acc[gi].y + bias_r[gi][1]);
                    st.y = packbf(acc[gi].z + bias_r[gi][2], acc[gi].w + bias_r[gi][3]);
                    *(uint2*)&out[((size_t)b * HW_ + (size_t)gy * W_ + gxx) *
                                      co_total + co_off + co_g] = st;
                }
            }
        }
    }
}

// ---------------------------------------------------------------------------
// Fused cK trio, octet-planar LDS: plane0 = x, 1 = up5, 2 = up10, 3 = up15.
// Three 16->8 convs off the shared tile; writes 24-ch NHWC g_in.
// wpack = PKc5 | PKc10 | PKc15 contiguous (5 steps x 512 each).
// ---------------------------------------------------------------------------
__global__ __launch_bounds__(256) void convc3_k(
    const unsigned short* __restrict__ src,
    const unsigned short* __restrict__ p5, const unsigned short* __restrict__ p10,
    const unsigned short* __restrict__ p15,
    const unsigned short* __restrict__ wpack,
    const float* __restrict__ bc5, const float* __restrict__ bc10,
    const float* __restrict__ bc15, unsigned short* __restrict__ out)
{
    constexpr int NPX = 18 * 34;
    __shared__ __align__(16) unsigned short s_in[4 * NPX * 8];

    int b = blockIdx.z;
    int x0 = blockIdx.x * 32, y0 = blockIdx.y * 16;
    int tid = threadIdx.x;
    int lane = tid & 63, wv = tid >> 6;

    const unsigned short* sb = src + (size_t)b * 8 * HW_;
    const unsigned short* pb5 = p5 + (size_t)b * 8 * 3600;
    const unsigned short* pb10 = p10 + (size_t)b * 8 * 900;
    const unsigned short* pb15 = p15 + (size_t)b * 8 * 400;

    for (int e = tid; e < NPX * 4; e += 256) {
        int px = e >> 2, oct = e & 3;
        int y = px / 34, x = px - y * 34;
        int gy = y0 + y - 1, gx = x0 + x - 1;
        u16x8 v = {0, 0, 0, 0, 0, 0, 0, 0};
        if (gy >= 0 && gy < H_ && gx >= 0 && gx < W_) {
            if (oct == 0)
                v = *(const u16x8*)&sb[((size_t)gy * W_ + gx) * 8];
            else if (oct == 1)
                v = *(const u16x8*)&pb5[((size_t)(gy / 5) * 60 + gx / 5) * 8];
            else if (oct == 2)
                v = *(const u16x8*)&pb10[((size_t)(gy / 10) * 30 + gx / 10) * 8];
            else
                v = *(const u16x8*)&pb15[((size_t)(gy / 15) * 20 + gx / 15) * 8];
        }
        *(u16x8*)&s_in[(oct * NPX + y * 34 + x) * 8] = v;
    }

    bf16x8 bw[3][5];
#pragma unroll
    for (int i = 0; i < 3; ++i)
#pragma unroll
        for (int s = 0; s < 5; ++s)
            bw[i][s] = *(const bf16x8*)&wpack[((i * 5 + s) * 64 + lane) * 8];

    int col = lane & 15, kg = lane >> 4;
    float bias_r[3][4];
#pragma unroll
    for (int r = 0; r < 4; ++r) {
        int co_l = kg * 4 + r;
        bias_r[0][r] = (kg < 2) ? bc5[co_l] : 0.f;
        bias_r[1][r] = (kg < 2) ? bc10[co_l] : 0.f;
        bias_r[2][r] = (kg < 2) ? bc15[co_l] : 0.f;
    }

    int offt[5];
#pragma unroll
    for (int s = 0; s < 5; ++s) {
        int t = s * 2 + (kg >> 1);
        if (t > 8) t = 8;
        offt[s] = ((t / 3) * 34 + (t % 3)) * 8;
    }
    int octoff[3];
#pragma unroll
    for (int i = 0; i < 3; ++i)
        octoff[i] = ((kg & 1) ? (1 + i) : 0) * (NPX * 8);

    __syncthreads();

#pragma unroll
    for (int i8 = 0; i8 < 8; ++i8) {
        int m = wv * 8 + i8;
        int my = m >> 1, tx = m & 1;
        int gy = y0 + my;
        if (gy >= H_) continue;
        int base = (my * 34 + tx * 16 + col) * 8;

        f32x4 acc[3];
#pragma unroll
        for (int i = 0; i < 3; ++i) acc[i] = {0.f, 0.f, 0.f, 0.f};
#pragma unroll
        for (int s = 0; s < 5; ++s) {
#pragma unroll
            for (int i = 0; i < 3; ++i) {
                bf16x8 a = *(const bf16x8*)&s_in[base + offt[s] + octoff[i]];
                acc[i] =
                    __builtin_amdgcn_mfma_f32_16x16x32_bf16(bw[i][s], a, acc[i], 0, 0, 0);
            }
        }

        int gxx = x0 + tx * 16 + col;
        if (kg < 2 && gxx < W_) {
            size_t pxo = ((size_t)b * HW_ + (size_t)gy * W_ + gxx) * 24;
#pragma unroll
            for (int i = 0; i < 3; ++i) {
                uint2 st;
                st.x = packbf(acc[i].x + bias_r[i][0], acc[i].y + bias_r[i][1]);
                st.y = packbf(acc[i].z + bias_r[i][2], acc[i].w + bias_r[i][3]);
                *(uint2*)&out[pxo + i * 8 + kg * 4] = st;
            }
        }
    }
}

// ---------------------------------------------------------------------------
// Pools, NHWC (8ch vector per pixel).
// ---------------------------------------------------------------------------
__global__ __launch_bounds__(256) void pool5_k(const unsigned short* __restrict__ x,
                                               unsigned short* __restrict__ p5,
                                               int n)
{
    int idx = blockIdx.x * 256 + threadIdx.x;
    if (idx >= n) return;
    int b = idx / 3600;
    int rem = idx - b * 3600;
    int i = rem / 60, j = rem - i * 60;
    const unsigned short* src =
        x + ((size_t)b * HW_ + (size_t)(i * 5) * W_ + j * 5) * 8;
    float ss[8] = {0, 0, 0, 0, 0, 0, 0, 0};
#pragma unroll
    for (int r = 0; r < 5; ++r)
#pragma unroll
        for (int c = 0; c < 5; ++c) {
            u16x8 v = *(const u16x8*)&src[((size_t)r * W_ + c) * 8];
#pragma unroll
            for (int k = 0; k < 8; ++k) ss[k] += b2f(v[k]);
        }
    uint4 st;
    st.x = packbf(ss[0] * 0.04f, ss[1] * 0.04f);
    st.y = packbf(ss[2] * 0.04f, ss[3] * 0.04f);
    st.z = packbf(ss[4] * 0.04f, ss[5] * 0.04f);
    st.w = packbf(ss[6] * 0.04f, ss[7] * 0.04f);
    *(uint4*)&p5[(size_t)idx * 8] = st;
}

template <int R, int OD>
__global__ __launch_bounds__(256) void poolr_k(const unsigned short* __restrict__ p5,
                                               unsigned short* __restrict__ po,
                                               int n)
{
    int idx = blockIdx.x * 256 + threadIdx.x;
    if (idx >= n) return;
    int b = idx / (OD * OD);
    int rem = idx - b * OD * OD;
    int i = rem / OD, j = rem - i * OD;
    const unsigned short* src =
        p5 + ((size_t)b * 3600 + (size_t)(i * R) * 60 + j * R) * 8;
    float ss[8] = {0, 0, 0, 0, 0, 0, 0, 0};
    const float inv = 1.f / (R * R);
#pragma unroll
    for (int r = 0; r < R; ++r)
#pragma unroll
        for (int c = 0; c < R; ++c) {
            u16x8 v = *(const u16x8*)&src[((size_t)r * 60 + c) * 8];
#pragma unroll
            for (int k = 0; k < 8; ++k) ss[k] += b2f(v[k]);
        }
    uint4 st;
    st.x = packbf(ss[0] * inv, ss[1] * inv);
    st.y = packbf(ss[2] * inv, ss[3] * inv);
    st.z = packbf(ss[4] * inv, ss[5] * inv);
    st.w = packbf(ss[6] * inv, ss[7] * inv);
    *(uint4*)&po[(size_t)idx * 8] = st;
}

// ---------------------------------------------------------------------------
// BN stats over NHWC gated.
// ---------------------------------------------------------------------------
__global__ __launch_bounds__(256) void reduce_k(
    const unsigned short* __restrict__ gated, float2* __restrict__ partials)
{
    int bx = blockIdx.x;
    int tid = threadIdx.x;
    float s[8] = {0, 0, 0, 0, 0, 0, 0, 0};
    float s2[8] = {0, 0, 0, 0, 0, 0, 0, 0};
    const size_t N = (size_t)NBATCH * HW_;
    for (size_t i = (size_t)bx * 256 + tid; i < N; i += 64 * 256) {
        u16x8 v = *(const u16x8*)&gated[i * 8];
#pragma unroll
        for (int k = 0; k < 8; ++k) {
            float f = b2f(v[k]);
            s[k] += f;
            s2[k] += f * f;
        }
    }
#pragma unroll
    for (int off = 32; off > 0; off >>= 1) {
#pragma unroll
        for (int k = 0; k < 8; ++k) {
            s[k] += __shfl_down(s[k], off);
            s2[k] += __shfl_down(s2[k], off);
        }
    }
    __shared__ float2 red[4][8];
    int lane = tid & 63, wvi = tid >> 6;
    if (lane == 0) {
#pragma unroll
        for (int k = 0; k < 8; ++k) red[wvi][k] = make_float2(s[k], s2[k]);
    }
    __syncthreads();
    if (tid < 8) {
        float a = 0.f, b2 = 0.f;
        for (int i = 0; i < 4; ++i) { a += red[i][tid].x; b2 += red[i][tid].y; }
        partials[tid * 64 + bx] = make_float2(a, b2);
    }
}

// Fold BN into conv11 weights; output layout wfold[t*8+ci], bias at [72].
__global__ void stats_fold_k(const float2* __restrict__ partials,
                             const float* __restrict__ bn_w,
                             const float* __restrict__ bn_b,
                             const float* __restrict__ w11,
                             const float* __restrict__ b11,
                             float* __restrict__ wfold)
{
    __shared__ float sc[8], tc[8];
    int tid = threadIdx.x;
    if (tid < 8) {
        double s = 0.0, s2 = 0.0;
        for (int i = 0; i < 64; ++i) {
            float2 p = partials[tid * 64 + i];
            s += p.x;
            s2 += p.y;
        }
        double N = (double)NBATCH * HW_;
        double mean = s / N;
        double var = s2 / N - mean * mean;
        float rstd = (float)(1.0 / sqrt(var + 1e-5));
        float scv = bn_w[tid] * rstd;
        sc[tid] = scv;
        tc[tid] = bn_b[tid] - (float)mean * scv;
    }
    __syncthreads();
    if (tid < 72) {
        int t = tid >> 3, ci = tid & 7;
        wfold[tid] = w11[ci * 9 + t] * sc[ci];
    }
    if (tid == 72) {
        float a = b11[0];
        for (int i = 0; i < 72; ++i) a += w11[i] * tc[i / 9];
        wfold[72] = a;
    }
}

// ---------------------------------------------------------------------------
// Final: att = sigmoid(conv 8->1 over NHWC gated), blend with im (NCHW fp32).
// ---------------------------------------------------------------------------
__global__ __launch_bounds__(256) void final_k(
    const unsigned short* __restrict__ gated, const float* __restrict__ wf,
    const float* __restrict__ im, const float* __restrict__ gamma,
    float* __restrict__ out)
{
    __shared__ __align__(16) unsigned short s_g[1156 * 8];
    __shared__ float s_w[80];

    int b = blockIdx.z;
    int x0 = blockIdx.x * 32, y0 = blockIdx.y * 32;
    int tid = threadIdx.x;

    if (tid < 73) s_w[tid] = wf[tid];

    const unsigned short* gb = gated + (size_t)b * HW_ * 8;
    for (int e = tid; e < 1156; e += 256) {
        int y = e / 34, x = e - y * 34;
        int gy = y0 + y - 1, gx = x0 + x - 1;
        u16x8 v = {0, 0, 0, 0, 0, 0, 0, 0};
        if (gy >= 0 && gy < H_ && gx >= 0 && gx < W_)
            v = *(const u16x8*)&gb[((size_t)gy * W_ + gx) * 8];
        *(u16x8*)&s_g[e * 8] = v;
    }
    __syncthreads();

    int qx = (tid & 15) * 2, qy = (tid >> 4) * 2;
    float f[4];
    float gm = *gamma;
#pragma unroll
    for (int p = 0; p < 4; ++p) {
        int ly = qy + (p >> 1), lx = qx + (p & 1);
        float acc = s_w[72];
#pragma unroll
        for (int t = 0; t < 9; ++t) {
            u16x8 n = *(const u16x8*)&s_g[((ly + t / 3) * 34 + lx + t % 3) * 8];
#pragma unroll
            for (int ci = 0; ci < 8; ++ci) acc += b2f(n[ci]) * s_w[t * 8 + ci];
        }
        f[p] = (1.f - gm) + gm * sigm(acc);
    }

    int px = x0 + qx, py = y0 + qy;
    if (px < W_) {
#pragma unroll
        for (int ch = 0; ch < 3; ++ch) {
            const float* imb = im + ((size_t)b * 3 + ch) * HW_;
            float* ob = out + ((size_t)b * 3 + ch) * HW_;
#pragma unroll
            for (int pr = 0; pr < 2; ++pr) {
                if (py + pr < H_) {
                    float2 iv = *(const float2*)&imb[(size_t)(py + pr) * W_ + px];
                    float2 ov;
                    ov.x = iv.x * f[pr * 2 + 0];
                    ov.y = iv.y * f[pr * 2 + 1];
                    *(float2*)&ob[(size_t)(py + pr) * W_ + px] = ov;
                }
            }
        }
    }
}

// ---------------------------------------------------------------------------

extern "C" void kernel_launch(void* const* d_in, const int* in_sizes, int n_in,
                              void* d_out, int out_size, void* d_ws,
                              size_t ws_size, hipStream_t stream)
{
    (void)in_sizes; (void)n_in; (void)out_size;

    const float* im  = (const float*)d_in[0];
    const float* w1  = (const float*)d_in[1];
    const float* b1  = (const float*)d_in[2];
    const float* w2  = (const float*)d_in[3];
    const float* b2  = (const float*)d_in[4];
    const float* w3  = (const float*)d_in[5];
    const float* b3  = (const float*)d_in[6];
    const float* w4  = (const float*)d_in[7];
    const float* b4  = (const float*)d_in[8];
    const float* w5  = (const float*)d_in[9];
    const float* b5  = (const float*)d_in[10];
    const float* wc5 = (const float*)d_in[11];
    const float* bc5 = (const float*)d_in[12];
    const float* wc10= (const float*)d_in[13];
    const float* bc10= (const float*)d_in[14];
    const float* wc15= (const float*)d_in[15];
    const float* bc15= (const float*)d_in[16];
    const float* wg  = (const float*)d_in[17];
    const float* bg  = (const float*)d_in[18];
    const float* wm  = (const float*)d_in[19];
    const float* bm  = (const float*)d_in[20];
    const float* bnw = (const float*)d_in[21];
    const float* bnb = (const float*)d_in[22];
    const float* w11 = (const float*)d_in[23];
    const float* b11 = (const float*)d_in[24];
    const float* gam = (const float*)d_in[25];
    float* out = (float*)d_out;

    // ---- workspace plan (chunked batch; deterministic in ws_size) ----------
    const size_t GATED_B = 46080000;
    const size_t PER_IMG = 1440000 + 2880000 + 5760000 + 57600 + 14400 + 6656;
    const size_t MISC    = 262144;
    int c = 32;
    while (c > 1 && GATED_B + MISC + (size_t)c * PER_IMG + 2048 > ws_size)
        c >>= 1;

    char* p = (char*)d_ws;
    auto take = [&](size_t bytes) {
        char* r = p;
        p += (bytes + 255) & ~(size_t)255;
        return r;
    };
    unsigned short* GATED = (unsigned short*)take(GATED_B);
    unsigned short* A   = (unsigned short*)take((size_t)c * 1440000);
    unsigned short* Bb  = (unsigned short*)take((size_t)c * 2880000);
    unsigned short* C   = (unsigned short*)take((size_t)c * 5760000);
    unsigned short* P5  = (unsigned short*)take((size_t)c * 57600);
    unsigned short* P10 = (unsigned short*)take((size_t)c * 14400);
    unsigned short* P15 = (unsigned short*)take((size_t)c * 6656);
    float2* parts = (float2*)take(4096);
    float*  wfold = (float*)take(512);
    unsigned short* WP = (unsigned short*)take(65536);

    unsigned short* PK2  = WP;            // conv2: 3 steps (1536)
    unsigned short* PK3  = WP + 2048;     // conv3: 5x2    (5120)
    unsigned short* PK4  = WP + 8192;     // conv4: 9      (4608)
    unsigned short* PK5  = WP + 13312;    // conv5: 5      (2560)
    unsigned short* PKc  = WP + 16384;    // c5|c10|c15 contiguous (3x2560)
    unsigned short* PKg  = WP + 25600;    // gated: 9     (4608)
    unsigned short* PK1  = WP + 30720;    // conv1: 3     (1536)

    dim3 blk(256);

    pack_k<<<dim3(1), blk, 0, stream>>>(w1,  nullptr, 999,  8,  3,  8, 3, 1, PK1);
    pack_k<<<dim3(1), blk, 0, stream>>>(w2,  nullptr, 999, 16,  8,  8, 3, 1, PK2);
    pack_k<<<dim3(1), blk, 0, stream>>>(w3,  nullptr, 999, 32, 16, 16, 5, 2, PK3);
    pack_k<<<dim3(1), blk, 0, stream>>>(w4,  nullptr, 999, 16, 32, 32, 9, 1, PK4);
    pack_k<<<dim3(1), blk, 0, stream>>>(w5,  nullptr, 999,  8, 16, 16, 5, 1, PK5);
    pack_k<<<dim3(1), blk, 0, stream>>>(wc5, nullptr, 999,  8, 16, 16, 5, 1, PKc);
    pack_k<<<dim3(1), blk, 0, stream>>>(wc10,nullptr, 999,  8, 16, 16, 5, 1, PKc + 2560);
    pack_k<<<dim3(1), blk, 0, stream>>>(wc15,nullptr, 999,  8, 16, 16, 5, 1, PKc + 5120);
    pack_k<<<dim3(1), blk, 0, stream>>>(wg,  wm,        8, 16, 24, 32, 9, 1, PKg);

    for (int b0 = 0; b0 < NBATCH; b0 += c) {
        dim3 gm(10, 19, c);    // mfconv / convc3 (32x16 tiles)
        const float* imc = im + (size_t)b0 * 3 * HW_;

        mfconv_k<8, 8, 8, 1, 3, 1><<<gm, blk, 0, stream>>>(
            (const unsigned short*)imc, nullptr, PK1, b1, nullptr, A, 8, 0);

        mfconv_k<8, 8, 16, 1, 0, 1><<<gm, blk, 0, stream>>>(
            A, nullptr, PK2, b2, nullptr, Bb, 16, 0);
        mfconv_k<16, 16, 32, 2, 0, 1><<<gm, blk, 0, stream>>>(
            Bb, nullptr, PK3, b3, nullptr, C, 32, 0);
        mfconv_k<32, 32, 16, 1, 0, 1><<<gm, blk, 0, stream>>>(
            C, nullptr, PK4, b4, nullptr, Bb, 16, 0);
        mfconv_k<16, 16, 8, 1, 0, 1><<<gm, blk, 0, stream>>>(
            Bb, nullptr, PK5, b5, nullptr, A, 8, 0);

        int n5 = c * 3600, n10 = c * 900, n15 = c * 400;
        pool5_k<<<dim3((n5 + 255) / 256), blk, 0, stream>>>(A, P5, n5);
        poolr_k<2, 30><<<dim3((n10 + 255) / 256), blk, 0, stream>>>(P5, P10, n10);
        poolr_k<3, 20><<<dim3((n15 + 255) / 256), blk, 0, stream>>>(P5, P15, n15);

        convc3_k<<<gm, blk, 0, stream>>>(A, P5, P10, P15, PKc, bc5, bc10, bc15, C);

        mfconv_k<24, 32, 16, 1, 2, 1><<<gm, blk, 0, stream>>>(
            C, nullptr, PKg, bg, bm, GATED + (size_t)b0 * HW_ * 8, 8, 0);
    }

    reduce_k<<<dim3(64), blk, 0, stream>>>(GATED, parts);
    stats_fold_k<<<dim3(1), dim3(128), 0, stream>>>(parts, bnw, bnb, w11, b11,
                                                    wfold);
    final_k<<<dim3(10, 10, NBATCH), blk, 0, stream>>>(GATED, wfold, im, gam,
                                                      out);
}

// Round 7
// 472.657 us; speedup vs baseline: 6.7445x; 1.2063x over previous
//
#include <hip/hip_runtime.h>
#include <hip/hip_bf16.h>
#include <math.h>

typedef __hip_bfloat16 bf16;
typedef __attribute__((ext_vector_type(8))) __bf16 bf16x8;
typedef __attribute__((ext_vector_type(8))) unsigned short u16x8;
typedef __attribute__((ext_vector_type(4))) float f32x4;

#define H_ 300
#define W_ 300
#define HW_ 90000
#define NBATCH 32
#define RB 512   // reduce_k blocks

__device__ __forceinline__ float b2f(unsigned short u) {
    return __uint_as_float((unsigned int)u << 16);
}
__device__ __forceinline__ unsigned short f2u(float v) {
    bf16 b = __float2bfloat16(v);
    return *reinterpret_cast<unsigned short*>(&b);
}
__device__ __forceinline__ float sigm(float x) { return 1.f / (1.f + __expf(-x)); }
__device__ __forceinline__ unsigned int packbf(float a, float b) {
    return (unsigned int)f2u(a) | ((unsigned int)f2u(b) << 16);
}

// ---------------------------------------------------------------------------
// All weight prepacks in ONE launch (9 blocks). Fragment order: A operand,
// row = lane&15 = co, k = (lane>>4)*8+j; pack[step][g][lane][j] bf16.
// ---------------------------------------------------------------------------
__global__ void pack_all_k(
    const float* __restrict__ w1, const float* __restrict__ w2,
    const float* __restrict__ w3, const float* __restrict__ w4,
    const float* __restrict__ w5, const float* __restrict__ wc5,
    const float* __restrict__ wc10, const float* __restrict__ wc15,
    const float* __restrict__ wg, const float* __restrict__ wm,
    unsigned short* __restrict__ WP)
{
    const float *a = nullptr, *bsec = nullptr;
    int cs = 999, CO = 0, CI = 0, CP = 8, NS = 3, NG = 1, off = 0;
    switch (blockIdx.x) {
        case 0: a = w2;  CO = 16; CI = 8;  CP = 8;  NS = 3; off = 0;     break;
        case 1: a = w3;  CO = 32; CI = 16; CP = 16; NS = 5; NG = 2; off = 2048;  break;
        case 2: a = w4;  CO = 16; CI = 32; CP = 32; NS = 9; off = 8192;  break;
        case 3: a = w5;  CO = 8;  CI = 16; CP = 16; NS = 5; off = 13312; break;
        case 4: a = wc5; CO = 8;  CI = 16; CP = 16; NS = 5; off = 16384; break;
        case 5: a = wc10;CO = 8;  CI = 16; CP = 16; NS = 5; off = 18944; break;
        case 6: a = wc15;CO = 8;  CI = 16; CP = 16; NS = 5; off = 21504; break;
        case 7: a = wg; bsec = wm; cs = 8; CO = 16; CI = 24; CP = 32; NS = 9;
                off = 25600; break;
        case 8: a = w1;  CO = 8;  CI = 3;  CP = 8;  NS = 3; off = 30720; break;
    }
    unsigned short* outp = WP + off;
    int TPK = 32 / CP;
    int total = NS * NG * 512;
    for (int idx = threadIdx.x; idx < total; idx += 256) {
        int j = idx & 7;
        int lane = (idx >> 3) & 63;
        int g = (idx >> 9) % NG;
        int s = idx / (512 * NG);
        int col = lane & 15, kg = lane >> 4;
        int kk = kg * 8 + j;
        int tt = kk / CP, ci = kk % CP;
        int tap = s * TPK + tt;
        int co = g * 16 + col;
        float v = 0.f;
        if (tap < 9 && ci < CI && co < CO)
            v = (co >= cs) ? bsec[((co - cs) * CI + ci) * 9 + tap]
                           : a[(co * CI + ci) * 9 + tap];
        outp[idx] = f2u(v);
    }
}

// ---------------------------------------------------------------------------
// MFMA implicit-GEMM 3x3 conv, NHWC in/out. Tile 32xTH px, 4 waves.
// Octet-planar LDS s_in[oct][(TH+2)*34 px][8ch]; staging is wave-uniform in
// oct (oct = wave%OCT) and has an interior fast path (no bounds checks).
// MODE 0: plain. MODE 2: gated (rows 0-7 g, 8-15 m; out = g*sigm(m)).
// MODE 3: conv1 (src fp32 NCHW 3ch -> LDS ch 0-2, 3-7 zero).
// ---------------------------------------------------------------------------
template <int CIN, int CINP, int COUT, int NGI, int MODE, int TH>
__global__ __launch_bounds__(256) void mfconv_k(
    const unsigned short* __restrict__ src,
    const unsigned short* __restrict__ wpack,
    const float* __restrict__ bias0, const float* __restrict__ bias1,
    unsigned short* __restrict__ out, int co_total, int co_off)
{
    constexpr int TPK = 32 / CINP;
    constexpr int NSTEP = (9 + TPK - 1) / TPK;
    constexpr int OCT = CINP / 8;
    constexpr int NPX = (TH + 2) * 34;

    __shared__ __align__(16) unsigned short s_in[OCT * NPX * 8];

    int b = blockIdx.z;
    int x0 = blockIdx.x * 32, y0 = blockIdx.y * TH;
    int tid = threadIdx.x;
    int lane = tid & 63, wv = tid >> 6;
    bool interior = (x0 >= 1) && (x0 + 32 < W_) && (y0 >= 1) && (y0 + TH < H_);

    // ---- staging: wave-uniform oct, px = lane + phase*64 ----
    if (MODE == 3) {
        const float* sf = reinterpret_cast<const float*>(src) + (size_t)b * 3 * HW_;
        if (interior) {
            const float* sf0 = sf + (size_t)(y0 - 1) * W_ + (x0 - 1);
            for (int e = tid; e < NPX; e += 256) {
                int y = e / 34;
                size_t o = (size_t)e + (size_t)y * 266;
                u16x8 v = {0, 0, 0, 0, 0, 0, 0, 0};
                v[0] = f2u(sf0[o]);
                v[1] = f2u(sf0[HW_ + o]);
                v[2] = f2u(sf0[2 * HW_ + o]);
                *(u16x8*)&s_in[e * 8] = v;
            }
        } else {
            for (int e = tid; e < NPX; e += 256) {
                int y = e / 34, x = e - y * 34;
                int gy = y0 + y - 1, gx = x0 + x - 1;
                u16x8 v = {0, 0, 0, 0, 0, 0, 0, 0};
                if (gy >= 0 && gy < H_ && gx >= 0 && gx < W_) {
                    size_t o = (size_t)gy * W_ + gx;
                    v[0] = f2u(sf[o]);
                    v[1] = f2u(sf[HW_ + o]);
                    v[2] = f2u(sf[2 * HW_ + o]);
                }
                *(u16x8*)&s_in[e * 8] = v;
            }
        }
    } else {
        const unsigned short* sb = src + (size_t)b * CIN * HW_;
        int oct = (OCT == 1) ? 0 : (wv % OCT);
        int phase = (OCT == 4) ? 0 : (wv / OCT);
        if (interior) {
            const unsigned short* sb0 =
                sb + ((size_t)(y0 - 1) * W_ + (x0 - 1)) * CIN + oct * 8;
            for (int px = lane + phase * 64; px < NPX; px += 256 / OCT) {
                int y = px / 34;
                u16x8 v;
                if (CIN == CINP || oct * 8 < CIN)
                    v = *(const u16x8*)&sb0[(size_t)(px + y * 266) * CIN];
                else
                    v = (u16x8){0, 0, 0, 0, 0, 0, 0, 0};
                *(u16x8*)&s_in[(oct * NPX + px) * 8] = v;
            }
        } else {
            for (int px = lane + phase * 64; px < NPX; px += 256 / OCT) {
                int y = px / 34, x = px - y * 34;
                int gy = y0 + y - 1, gx = x0 + x - 1;
                u16x8 v = {0, 0, 0, 0, 0, 0, 0, 0};
                if (gy >= 0 && gy < H_ && gx >= 0 && gx < W_ &&
                    (CIN == CINP || oct * 8 < CIN))
                    v = *(const u16x8*)&sb[((size_t)gy * W_ + gx) * CIN + oct * 8];
                *(u16x8*)&s_in[(oct * NPX + px) * 8] = v;
            }
        }
    }

    // ---- weight fragments (NGI groups) ----
    bf16x8 bw[NGI][NSTEP];
#pragma unroll
    for (int gi = 0; gi < NGI; ++gi)
#pragma unroll
        for (int s = 0; s < NSTEP; ++s)
            bw[gi][s] = *(const bf16x8*)&wpack[((s * NGI + gi) * 64 + lane) * 8];

    int col = lane & 15, kg = lane >> 4;

    float bias_r[NGI][4];
#pragma unroll
    for (int gi = 0; gi < NGI; ++gi)
#pragma unroll
        for (int r = 0; r < 4; ++r) {
            if (MODE == 2)
                bias_r[0][r] = (kg < 2) ? bias0[kg * 4 + r] : bias1[(kg - 2) * 4 + r];
            else {
                int co_l = gi * 16 + kg * 4 + r;
                bias_r[gi][r] = (co_l < COUT) ? bias0[co_l] : 0.f;
            }
        }

    int offs[NSTEP];
#pragma unroll
    for (int s = 0; s < NSTEP; ++s) {
        int t = s * TPK + kg / OCT;
        if (t > 8) t = 8;  // padded taps: weights are zero there
        offs[s] = ((t / 3) * 34 + (t % 3)) * 8 + (kg % OCT) * (NPX * 8);
    }

    __syncthreads();

#pragma unroll
    for (int i = 0; i < TH / 2; ++i) {
        int m = wv * (TH / 2) + i;
        int my = m >> 1, tx = m & 1;
        int gy = y0 + my;
        if (gy >= H_) continue;  // wave-uniform
        int base = (my * 34 + tx * 16 + col) * 8;

        f32x4 acc[NGI];
#pragma unroll
        for (int gi = 0; gi < NGI; ++gi) acc[gi] = {0.f, 0.f, 0.f, 0.f};
#pragma unroll
        for (int s = 0; s < NSTEP; ++s) {
            bf16x8 a = *(const bf16x8*)&s_in[base + offs[s]];
#pragma unroll
            for (int gi = 0; gi < NGI; ++gi)
                acc[gi] =
                    __builtin_amdgcn_mfma_f32_16x16x32_bf16(bw[gi][s], a, acc[gi], 0, 0, 0);
        }

        int gxx = x0 + tx * 16 + col;
        if (MODE == 2) {
            float v0 = acc[0].x + bias_r[0][0], v1 = acc[0].y + bias_r[0][1];
            float v2 = acc[0].z + bias_r[0][2], v3 = acc[0].w + bias_r[0][3];
            float m0 = __shfl_xor(v0, 32), m1 = __shfl_xor(v1, 32);
            float m2 = __shfl_xor(v2, 32), m3 = __shfl_xor(v3, 32);
            if (kg < 2 && gxx < W_) {
                uint2 st;
                st.x = packbf(v0 * sigm(m0), v1 * sigm(m1));
                st.y = packbf(v2 * sigm(m2), v3 * sigm(m3));
                *(uint2*)&out[(((size_t)b * HW_ + (size_t)gy * W_ + gxx) * 8) +
                              kg * 4] = st;
            }
        } else {
#pragma unroll
            for (int gi = 0; gi < NGI; ++gi) {
                int co_g = gi * 16 + kg * 4;
                if (co_g < COUT && gxx < W_) {
                    uint2 st;
                    st.x = packbf(acc[gi].x + bias_r[gi][0], acc[gi].y + bias_r[gi][1]);
                    st.y = packbf(acc[gi].z + bias_r[gi][2], acc[gi].w + bias_r[gi][3]);
                    *(uint2*)&out[((size_t)b * HW_ + (size_t)gy * W_ + gxx) *
                                      co_total + co_off + co_g] = st;
                }
            }
        }
    }
}

// ---------------------------------------------------------------------------
// Fused cK trio, octet-planar LDS (plane0 = x, 1/2/3 = up5/up10/up15).
// Wave-uniform plane staging + interior fast path. Writes 24-ch NHWC g_in.
// ---------------------------------------------------------------------------
__global__ __launch_bounds__(256) void convc3_k(
    const unsigned short* __restrict__ src,
    const unsigned short* __restrict__ p5, const unsigned short* __restrict__ p10,
    const unsigned short* __restrict__ p15,
    const unsigned short* __restrict__ wpack,
    const float* __restrict__ bc5, const float* __restrict__ bc10,
    const float* __restrict__ bc15, unsigned short* __restrict__ out)
{
    constexpr int NPX = 18 * 34;
    __shared__ __align__(16) unsigned short s_in[4 * NPX * 8];

    int b = blockIdx.z;
    int x0 = blockIdx.x * 32, y0 = blockIdx.y * 16;
    int tid = threadIdx.x;
    int lane = tid & 63, wv = tid >> 6;
    bool interior = (x0 >= 1) && (x0 + 32 < W_) && (y0 >= 1) && (y0 + 16 < H_);

    const unsigned short* sb = src + (size_t)b * 8 * HW_;
    const unsigned short* pb5 = p5 + (size_t)b * 8 * 3600;
    const unsigned short* pb10 = p10 + (size_t)b * 8 * 900;
    const unsigned short* pb15 = p15 + (size_t)b * 8 * 400;

    int oct = wv;  // wave-uniform plane
    if (interior) {
        const unsigned short* sb0 = sb + ((size_t)(y0 - 1) * W_ + (x0 - 1)) * 8;
        for (int px = lane; px < NPX; px += 64) {
            int y = px / 34;
            u16x8 v;
            if (oct == 0) {
                v = *(const u16x8*)&sb0[(size_t)(px + y * 266) * 8];
            } else {
                int x = px - y * 34;
                int gy = y0 - 1 + y, gx = x0 - 1 + x;
                const unsigned short* pp =
                    (oct == 1) ? &pb5[((size_t)(gy / 5) * 60 + gx / 5) * 8]
                    : (oct == 2) ? &pb10[((size_t)(gy / 10) * 30 + gx / 10) * 8]
                                 : &pb15[((size_t)(gy / 15) * 20 + gx / 15) * 8];
                v = *(const u16x8*)pp;
            }
            *(u16x8*)&s_in[(oct * NPX + px) * 8] = v;
        }
    } else {
        for (int px = lane; px < NPX; px += 64) {
            int y = px / 34, x = px - y * 34;
            int gy = y0 + y - 1, gx = x0 + x - 1;
            u16x8 v = {0, 0, 0, 0, 0, 0, 0, 0};
            if (gy >= 0 && gy < H_ && gx >= 0 && gx < W_) {
                if (oct == 0)
                    v = *(const u16x8*)&sb[((size_t)gy * W_ + gx) * 8];
                else if (oct == 1)
                    v = *(const u16x8*)&pb5[((size_t)(gy / 5) * 60 + gx / 5) * 8];
                else if (oct == 2)
                    v = *(const u16x8*)&pb10[((size_t)(gy / 10) * 30 + gx / 10) * 8];
                else
                    v = *(const u16x8*)&pb15[((size_t)(gy / 15) * 20 + gx / 15) * 8];
            }
            *(u16x8*)&s_in[(oct * NPX + px) * 8] = v;
        }
    }

    bf16x8 bw[3][5];
#pragma unroll
    for (int i = 0; i < 3; ++i)
#pragma unroll
        for (int s = 0; s < 5; ++s)
            bw[i][s] = *(const bf16x8*)&wpack[((i * 5 + s) * 64 + lane) * 8];

    int col = lane & 15, kg = lane >> 4;
    float bias_r[3][4];
#pragma unroll
    for (int r = 0; r < 4; ++r) {
        int co_l = kg * 4 + r;
        bias_r[0][r] = (kg < 2) ? bc5[co_l] : 0.f;
        bias_r[1][r] = (kg < 2) ? bc10[co_l] : 0.f;
        bias_r[2][r] = (kg < 2) ? bc15[co_l] : 0.f;
    }

    int offt[5];
#pragma unroll
    for (int s = 0; s < 5; ++s) {
        int t = s * 2 + (kg >> 1);
        if (t > 8) t = 8;
        offt[s] = ((t / 3) * 34 + (t % 3)) * 8;
    }
    int octoff[3];
#pragma unroll
    for (int i = 0; i < 3; ++i)
        octoff[i] = ((kg & 1) ? (1 + i) : 0) * (NPX * 8);

    __syncthreads();

#pragma unroll
    for (int i8 = 0; i8 < 8; ++i8) {
        int m = wv * 8 + i8;
        int my = m >> 1, tx = m & 1;
        int gy = y0 + my;
        if (gy >= H_) continue;
        int base = (my * 34 + tx * 16 + col) * 8;

        f32x4 acc[3];
#pragma unroll
        for (int i = 0; i < 3; ++i) acc[i] = {0.f, 0.f, 0.f, 0.f};
#pragma unroll
        for (int s = 0; s < 5; ++s) {
#pragma unroll
            for (int i = 0; i < 3; ++i) {
                bf16x8 a = *(const bf16x8*)&s_in[base + offt[s] + octoff[i]];
                acc[i] =
                    __builtin_amdgcn_mfma_f32_16x16x32_bf16(bw[i][s], a, acc[i], 0, 0, 0);
            }
        }

        int gxx = x0 + tx * 16 + col;
        if (kg < 2 && gxx < W_) {
            size_t pxo = ((size_t)b * HW_ + (size_t)gy * W_ + gxx) * 24;
#pragma unroll
            for (int i = 0; i < 3; ++i) {
                uint2 st;
                st.x = packbf(acc[i].x + bias_r[i][0], acc[i].y + bias_r[i][1]);
                st.y = packbf(acc[i].z + bias_r[i][2], acc[i].w + bias_r[i][3]);
                *(uint2*)&out[pxo + i * 8 + kg * 4] = st;
            }
        }
    }
}

// ---------------------------------------------------------------------------
// Pools, NHWC (8ch vector per pixel). p10/p15 merged in one launch.
// ---------------------------------------------------------------------------
__global__ __launch_bounds__(256) void pool5_k(const unsigned short* __restrict__ x,
                                               unsigned short* __restrict__ p5,
                                               int n)
{
    int idx = blockIdx.x * 256 + threadIdx.x;
    if (idx >= n) return;
    int b = idx / 3600;
    int rem = idx - b * 3600;
    int i = rem / 60, j = rem - i * 60;
    const unsigned short* src =
        x + ((size_t)b * HW_ + (size_t)(i * 5) * W_ + j * 5) * 8;
    float ss[8] = {0, 0, 0, 0, 0, 0, 0, 0};
#pragma unroll
    for (int r = 0; r < 5; ++r)
#pragma unroll
        for (int c = 0; c < 5; ++c) {
            u16x8 v = *(const u16x8*)&src[((size_t)r * W_ + c) * 8];
#pragma unroll
            for (int k = 0; k < 8; ++k) ss[k] += b2f(v[k]);
        }
    uint4 st;
    st.x = packbf(ss[0] * 0.04f, ss[1] * 0.04f);
    st.y = packbf(ss[2] * 0.04f, ss[3] * 0.04f);
    st.z = packbf(ss[4] * 0.04f, ss[5] * 0.04f);
    st.w = packbf(ss[6] * 0.04f, ss[7] * 0.04f);
    *(uint4*)&p5[(size_t)idx * 8] = st;
}

template <int R, int OD>
__device__ __forceinline__ void poolr_body(const unsigned short* __restrict__ p5,
                                           unsigned short* __restrict__ po, int idx)
{
    int b = idx / (OD * OD);
    int rem = idx - b * OD * OD;
    int i = rem / OD, j = rem - i * OD;
    const unsigned short* src =
        p5 + ((size_t)b * 3600 + (size_t)(i * R) * 60 + j * R) * 8;
    float ss[8] = {0, 0, 0, 0, 0, 0, 0, 0};
    const float inv = 1.f / (R * R);
#pragma unroll
    for (int r = 0; r < R; ++r)
#pragma unroll
        for (int c = 0; c < R; ++c) {
            u16x8 v = *(const u16x8*)&src[((size_t)r * 60 + c) * 8];
#pragma unroll
            for (int k = 0; k < 8; ++k) ss[k] += b2f(v[k]);
        }
    uint4 st;
    st.x = packbf(ss[0] * inv, ss[1] * inv);
    st.y = packbf(ss[2] * inv, ss[3] * inv);
    st.z = packbf(ss[4] * inv, ss[5] * inv);
    st.w = packbf(ss[6] * inv, ss[7] * inv);
    *(uint4*)&po[(size_t)idx * 8] = st;
}

__global__ __launch_bounds__(256) void poolrs_k(const unsigned short* __restrict__ p5,
                                                unsigned short* __restrict__ p10,
                                                unsigned short* __restrict__ p15,
                                                int n10, int n15)
{
    int idx = blockIdx.x * 256 + threadIdx.x;
    if (idx < n10) {
        poolr_body<2, 30>(p5, p10, idx);
    } else {
        idx -= n10;
        if (idx < n15) poolr_body<3, 20>(p5, p15, idx);
    }
}

// ---------------------------------------------------------------------------
// BN stats over NHWC gated: RB blocks (BW-bound, not 64-latency-bound).
// ---------------------------------------------------------------------------
__global__ __launch_bounds__(256) void reduce_k(
    const unsigned short* __restrict__ gated, float2* __restrict__ partials)
{
    int bx = blockIdx.x;
    int tid = threadIdx.x;
    float s[8] = {0, 0, 0, 0, 0, 0, 0, 0};
    float s2[8] = {0, 0, 0, 0, 0, 0, 0, 0};
    const size_t N = (size_t)NBATCH * HW_;
    for (size_t i = (size_t)bx * 256 + tid; i < N; i += (size_t)RB * 256) {
        u16x8 v = *(const u16x8*)&gated[i * 8];
#pragma unroll
        for (int k = 0; k < 8; ++k) {
            float f = b2f(v[k]);
            s[k] += f;
            s2[k] += f * f;
        }
    }
#pragma unroll
    for (int off = 32; off > 0; off >>= 1) {
#pragma unroll
        for (int k = 0; k < 8; ++k) {
            s[k] += __shfl_down(s[k], off);
            s2[k] += __shfl_down(s2[k], off);
        }
    }
    __shared__ float2 red[4][8];
    int lane = tid & 63, wvi = tid >> 6;
    if (lane == 0) {
#pragma unroll
        for (int k = 0; k < 8; ++k) red[wvi][k] = make_float2(s[k], s2[k]);
    }
    __syncthreads();
    if (tid < 8) {
        float a = 0.f, b2 = 0.f;
        for (int i = 0; i < 4; ++i) { a += red[i][tid].x; b2 += red[i][tid].y; }
        partials[tid * RB + bx] = make_float2(a, b2);
    }
}

// Parallel fold: 256 threads (32 per channel) reduce RB partials, then fold
// BN into conv11 weights; wfold[t*8+ci] layout, bias at [72].
__global__ __launch_bounds__(256) void stats_fold_k(
    const float2* __restrict__ partials, const float* __restrict__ bn_w,
    const float* __restrict__ bn_b, const float* __restrict__ w11,
    const float* __restrict__ b11, float* __restrict__ wfold)
{
    __shared__ float sc[8], tc[8];
    __shared__ float2 acc8[8];
    int tid = threadIdx.x;
    int c = tid >> 5, sl = tid & 31;
    float s = 0.f, s2 = 0.f;
    for (int i = sl; i < RB; i += 32) {
        float2 p = partials[c * RB + i];
        s += p.x;
        s2 += p.y;
    }
#pragma unroll
    for (int off = 16; off > 0; off >>= 1) {
        s += __shfl_down(s, off, 32);
        s2 += __shfl_down(s2, off, 32);
    }
    if (sl == 0) acc8[c] = make_float2(s, s2);
    __syncthreads();
    if (tid < 8) {
        double ds = acc8[tid].x, ds2 = acc8[tid].y;
        double N = (double)NBATCH * HW_;
        double mean = ds / N;
        double var = ds2 / N - mean * mean;
        float rstd = (float)(1.0 / sqrt(var + 1e-5));
        float scv = bn_w[tid] * rstd;
        sc[tid] = scv;
        tc[tid] = bn_b[tid] - (float)mean * scv;
    }
    __syncthreads();
    if (tid < 72) {
        int t = tid >> 3, ci = tid & 7;
        wfold[tid] = w11[ci * 9 + t] * sc[ci];
    }
    if (tid == 72) {
        float a = b11[0];
        for (int i = 0; i < 72; ++i) a += w11[i] * tc[i / 9];
        wfold[72] = a;
    }
}

// ---------------------------------------------------------------------------
// Final: att = sigmoid(conv 8->1 over NHWC gated), blend with im (NCHW fp32).
// ---------------------------------------------------------------------------
__global__ __launch_bounds__(256) void final_k(
    const unsigned short* __restrict__ gated, const float* __restrict__ wf,
    const float* __restrict__ im, const float* __restrict__ gamma,
    float* __restrict__ out)
{
    __shared__ __align__(16) unsigned short s_g[1156 * 8];
    __shared__ float s_w[80];

    int b = blockIdx.z;
    int x0 = blockIdx.x * 32, y0 = blockIdx.y * 32;
    int tid = threadIdx.x;
    bool interior = (x0 >= 1) && (x0 + 32 < W_) && (y0 >= 1) && (y0 + 32 < H_);

    if (tid < 73) s_w[tid] = wf[tid];

    const unsigned short* gb = gated + (size_t)b * HW_ * 8;
    if (interior) {
        const unsigned short* gb0 = gb + ((size_t)(y0 - 1) * W_ + (x0 - 1)) * 8;
        for (int e = tid; e < 1156; e += 256) {
            int y = e / 34;
            u16x8 v = *(const u16x8*)&gb0[(size_t)(e + y * 266) * 8];
            *(u16x8*)&s_g[e * 8] = v;
        }
    } else {
        for (int e = tid; e < 1156; e += 256) {
            int y = e / 34, x = e - y * 34;
            int gy = y0 + y - 1, gx = x0 + x - 1;
            u16x8 v = {0, 0, 0, 0, 0, 0, 0, 0};
            if (gy >= 0 && gy < H_ && gx >= 0 && gx < W_)
                v = *(const u16x8*)&gb[((size_t)gy * W_ + gx) * 8];
            *(u16x8*)&s_g[e * 8] = v;
        }
    }
    __syncthreads();

    int qx = (tid & 15) * 2, qy = (tid >> 4) * 2;
    float f[4];
    float gm = *gamma;
#pragma unroll
    for (int p = 0; p < 4; ++p) {
        int ly = qy + (p >> 1), lx = qx + (p & 1);
        float acc = s_w[72];
#pragma unroll
        for (int t = 0; t < 9; ++t) {
            u16x8 n = *(const u16x8*)&s_g[((ly + t / 3) * 34 + lx + t % 3) * 8];
#pragma unroll
            for (int ci = 0; ci < 8; ++ci) acc += b2f(n[ci]) * s_w[t * 8 + ci];
        }
        f[p] = (1.f - gm) + gm * sigm(acc);
    }

    int px = x0 + qx, py = y0 + qy;
    if (px < W_) {
#pragma unroll
        for (int ch = 0; ch < 3; ++ch) {
            const float* imb = im + ((size_t)b * 3 + ch) * HW_;
            float* ob = out + ((size_t)b * 3 + ch) * HW_;
#pragma unroll
            for (int pr = 0; pr < 2; ++pr) {
                if (py + pr < H_) {
                    float2 iv = *(const float2*)&imb[(size_t)(py + pr) * W_ + px];
                    float2 ov;
                    ov.x = iv.x * f[pr * 2 + 0];
                    ov.y = iv.y * f[pr * 2 + 1];
                    *(float2*)&ob[(size_t)(py + pr) * W_ + px] = ov;
                }
            }
        }
    }
}

// ---------------------------------------------------------------------------

extern "C" void kernel_launch(void* const* d_in, const int* in_sizes, int n_in,
                              void* d_out, int out_size, void* d_ws,
                              size_t ws_size, hipStream_t stream)
{
    (void)in_sizes; (void)n_in; (void)out_size;

    const float* im  = (const float*)d_in[0];
    const float* w1  = (const float*)d_in[1];
    const float* b1  = (const float*)d_in[2];
    const float* w2  = (const float*)d_in[3];
    const float* b2  = (const float*)d_in[4];
    const float* w3  = (const float*)d_in[5];
    const float* b3  = (const float*)d_in[6];
    const float* w4  = (const float*)d_in[7];
    const float* b4  = (const float*)d_in[8];
    const float* w5  = (const float*)d_in[9];
    const float* b5  = (const float*)d_in[10];
    const float* wc5 = (const float*)d_in[11];
    const float* bc5 = (const float*)d_in[12];
    const float* wc10= (const float*)d_in[13];
    const float* bc10= (const float*)d_in[14];
    const float* wc15= (const float*)d_in[15];
    const float* bc15= (const float*)d_in[16];
    const float* wg  = (const float*)d_in[17];
    const float* bg  = (const float*)d_in[18];
    const float* wm  = (const float*)d_in[19];
    const float* bm  = (const float*)d_in[20];
    const float* bnw = (const float*)d_in[21];
    const float* bnb = (const float*)d_in[22];
    const float* w11 = (const float*)d_in[23];
    const float* b11 = (const float*)d_in[24];
    const float* gam = (const float*)d_in[25];
    float* out = (float*)d_out;

    // ---- workspace plan (chunked batch; deterministic in ws_size) ----------
    const size_t GATED_B = 46080000;
    const size_t PER_IMG = 1440000 + 2880000 + 5760000 + 57600 + 14400 + 6656;
    const size_t MISC    = 262144;
    int c = 32;
    while (c > 1 && GATED_B + MISC + (size_t)c * PER_IMG + 2048 > ws_size)
        c >>= 1;

    char* p = (char*)d_ws;
    auto take = [&](size_t bytes) {
        char* r = p;
        p += (bytes + 255) & ~(size_t)255;
        return r;
    };
    unsigned short* GATED = (unsigned short*)take(GATED_B);
    unsigned short* A   = (unsigned short*)take((size_t)c * 1440000);
    unsigned short* Bb  = (unsigned short*)take((size_t)c * 2880000);
    unsigned short* C   = (unsigned short*)take((size_t)c * 5760000);
    unsigned short* P5  = (unsigned short*)take((size_t)c * 57600);
    unsigned short* P10 = (unsigned short*)take((size_t)c * 14400);
    unsigned short* P15 = (unsigned short*)take((size_t)c * 6656);
    float2* parts = (float2*)take(8 * RB * sizeof(float2));
    float*  wfold = (float*)take(512);
    unsigned short* WP = (unsigned short*)take(65536);

    unsigned short* PK2 = WP;            // conv2: 3 steps
    unsigned short* PK3 = WP + 2048;     // conv3: 5x2
    unsigned short* PK4 = WP + 8192;     // conv4: 9
    unsigned short* PK5 = WP + 13312;    // conv5: 5
    unsigned short* PKc = WP + 16384;    // c5|c10|c15
    unsigned short* PKg = WP + 25600;    // gated: 9
    unsigned short* PK1 = WP + 30720;    // conv1: 3

    dim3 blk(256);

    pack_all_k<<<dim3(9), blk, 0, stream>>>(w1, w2, w3, w4, w5, wc5, wc10, wc15,
                                            wg, wm, WP);

    for (int b0 = 0; b0 < NBATCH; b0 += c) {
        dim3 g32(10, 10, c);   // TH=32 kernels
        dim3 g16(10, 19, c);   // TH=16 kernels
        const float* imc = im + (size_t)b0 * 3 * HW_;

        mfconv_k<8, 8, 8, 1, 3, 32><<<g32, blk, 0, stream>>>(
            (const unsigned short*)imc, PK1, b1, nullptr, A, 8, 0);
        mfconv_k<8, 8, 16, 1, 0, 32><<<g32, blk, 0, stream>>>(
            A, PK2, b2, nullptr, Bb, 16, 0);
        mfconv_k<16, 16, 32, 2, 0, 32><<<g32, blk, 0, stream>>>(
            Bb, PK3, b3, nullptr, C, 32, 0);
        mfconv_k<32, 32, 16, 1, 0, 16><<<g16, blk, 0, stream>>>(
            C, PK4, b4, nullptr, Bb, 16, 0);
        mfconv_k<16, 16, 8, 1, 0, 32><<<g32, blk, 0, stream>>>(
            Bb, PK5, b5, nullptr, A, 8, 0);

        int n5 = c * 3600, n10 = c * 900, n15 = c * 400;
        pool5_k<<<dim3((n5 + 255) / 256), blk, 0, stream>>>(A, P5, n5);
        poolrs_k<<<dim3((n10 + n15 + 255) / 256), blk, 0, stream>>>(P5, P10, P15,
                                                                    n10, n15);

        convc3_k<<<g16, blk, 0, stream>>>(A, P5, P10, P15, PKc, bc5, bc10, bc15, C);

        mfconv_k<24, 32, 16, 1, 2, 16><<<g16, blk, 0, stream>>>(
            C, PKg, bg, bm, GATED + (size_t)b0 * HW_ * 8, 8, 0);
    }

    reduce_k<<<dim3(RB), blk, 0, stream>>>(GATED, parts);
    stats_fold_k<<<dim3(1), blk, 0, stream>>>(parts, bnw, bnb, w11, b11, wfold);
    final_k<<<dim3(10, 10, NBATCH), blk, 0, stream>>>(GATED, wfold, im, gam,
                                                      out);
}

// Round 8
// 463.624 us; speedup vs baseline: 6.8759x; 1.0195x over previous
//
#include <hip/hip_runtime.h>
#include <hip/hip_bf16.h>
#include <math.h>

typedef __hip_bfloat16 bf16;
typedef __attribute__((ext_vector_type(8))) __bf16 bf16x8;
typedef __attribute__((ext_vector_type(8))) unsigned short u16x8;
typedef __attribute__((ext_vector_type(4))) float f32x4;

#define H_ 300
#define W_ 300
#define HW_ 90000
#define NBATCH 32
#define RB 512   // reduce_k blocks

__device__ __forceinline__ float b2f(unsigned short u) {
    return __uint_as_float((unsigned int)u << 16);
}
__device__ __forceinline__ unsigned short f2u(float v) {
    bf16 b = __float2bfloat16(v);
    return *reinterpret_cast<unsigned short*>(&b);
}
__device__ __forceinline__ float sigm(float x) { return 1.f / (1.f + __expf(-x)); }
__device__ __forceinline__ unsigned int packbf(float a, float b) {
    return (unsigned int)f2u(a) | ((unsigned int)f2u(b) << 16);
}

// ---------------------------------------------------------------------------
// All weight prepacks in ONE launch (7 blocks). Fragment order: A operand,
// row = lane&15 = co, k = (lane>>4)*8+j; pack[step][g][lane][j] bf16.
// Block 4 is the convc composite: 32ch input = x|up5|up10|up15; group0 cols
// 0-7 = c5 (octets 0,1), cols 8-15 = c10 (octets 0,2); group1 cols 0-7 = c15
// (octets 0,3), cols 8-15 zero.
// ---------------------------------------------------------------------------
__global__ void pack_all_k(
    const float* __restrict__ w1, const float* __restrict__ w2,
    const float* __restrict__ w3, const float* __restrict__ w4,
    const float* __restrict__ w5, const float* __restrict__ wc5,
    const float* __restrict__ wc10, const float* __restrict__ wc15,
    const float* __restrict__ wg, const float* __restrict__ wm,
    unsigned short* __restrict__ WP)
{
    const float *a = nullptr, *bsec = nullptr;
    int cs = 999, CO = 0, CI = 0, CP = 8, NS = 3, NG = 1, off = 0, special = 0;
    switch (blockIdx.x) {
        case 0: a = w2;  CO = 16; CI = 8;  CP = 8;  NS = 3; off = 0;     break;
        case 1: a = w3;  CO = 32; CI = 16; CP = 16; NS = 5; NG = 2; off = 2048;  break;
        case 2: a = w4;  CO = 16; CI = 32; CP = 32; NS = 9; off = 8192;  break;
        case 3: a = w5;  CO = 8;  CI = 16; CP = 16; NS = 5; off = 13312; break;
        case 4: special = 1; CO = 32; CI = 32; CP = 32; NS = 9; NG = 2;
                off = 16384; break;
        case 5: a = wg; bsec = wm; cs = 8; CO = 16; CI = 24; CP = 32; NS = 9;
                off = 25600; break;
        case 6: a = w1;  CO = 8;  CI = 3;  CP = 8;  NS = 3; off = 30720; break;
    }
    unsigned short* outp = WP + off;
    int TPK = 32 / CP;
    int total = NS * NG * 512;
    for (int idx = threadIdx.x; idx < total; idx += 256) {
        int j = idx & 7;
        int lane = (idx >> 3) & 63;
        int g = (idx >> 9) % NG;
        int s = idx / (512 * NG);
        int col = lane & 15, kg = lane >> 4;
        int kk = kg * 8 + j;
        int tt = kk / CP, ci = kk % CP;
        int tap = s * TPK + tt;
        float v = 0.f;
        if (special) {
            // composite convc: ci in 0..31, octet o = ci/8
            int o = ci >> 3, c8 = ci & 7;
            int convid = (g == 0) ? (col < 8 ? 0 : 1) : (col < 8 ? 2 : -1);
            if (tap < 9 && convid >= 0) {
                const float* wc = (convid == 0) ? wc5 : (convid == 1) ? wc10 : wc15;
                int colc = col & 7;
                if (o == 0) v = wc[(colc * 16 + c8) * 9 + tap];
                else if (o == convid + 1) v = wc[(colc * 16 + 8 + c8) * 9 + tap];
            }
        } else {
            int co = g * 16 + col;
            if (tap < 9 && ci < CI && co < CO)
                v = (co >= cs) ? bsec[((co - cs) * CI + ci) * 9 + tap]
                               : a[(co * CI + ci) * 9 + tap];
        }
        outp[idx] = f2u(v);
    }
}

// ---------------------------------------------------------------------------
// MFMA implicit-GEMM 3x3 conv, NHWC in/out. Tile 32xTH px, 4 waves.
// Octet-planar LDS s_in[oct][(TH+2)*34 px][8ch]. OCT==4 kernels use a
// ROW-CACHED inner loop: fr[3][3] fragments live in VGPRs, 3 new ds_reads
// per output row instead of 9 (the 3x3 neighborhood is shift-closed in y).
// MODE 0: plain. MODE 2: gated (rows 0-7 g, 8-15 m; out = g*sigm(m)).
// MODE 3: conv1 (src fp32 NCHW 3ch -> LDS ch 0-2, 3-7 zero).
// ---------------------------------------------------------------------------
template <int CIN, int CINP, int COUT, int NGI, int MODE, int TH>
__global__ __launch_bounds__(256) void mfconv_k(
    const unsigned short* __restrict__ src,
    const unsigned short* __restrict__ wpack,
    const float* __restrict__ bias0, const float* __restrict__ bias1,
    unsigned short* __restrict__ out, int co_total, int co_off)
{
    constexpr int TPK = 32 / CINP;
    constexpr int NSTEP = (9 + TPK - 1) / TPK;
    constexpr int OCT = CINP / 8;
    constexpr int NPX = (TH + 2) * 34;

    __shared__ __align__(16) unsigned short s_in[OCT * NPX * 8];

    int b = blockIdx.z;
    int x0 = blockIdx.x * 32, y0 = blockIdx.y * TH;
    int tid = threadIdx.x;
    int lane = tid & 63, wv = tid >> 6;
    bool interior = (x0 >= 1) && (x0 + 32 < W_) && (y0 >= 1) && (y0 + TH < H_);

    // ---- staging: wave-uniform oct, px = lane + phase*64 ----
    if (MODE == 3) {
        const float* sf = reinterpret_cast<const float*>(src) + (size_t)b * 3 * HW_;
        if (interior) {
            const float* sf0 = sf + (size_t)(y0 - 1) * W_ + (x0 - 1);
            for (int e = tid; e < NPX; e += 256) {
                int y = e / 34;
                size_t o = (size_t)e + (size_t)y * 266;
                u16x8 v = {0, 0, 0, 0, 0, 0, 0, 0};
                v[0] = f2u(sf0[o]);
                v[1] = f2u(sf0[HW_ + o]);
                v[2] = f2u(sf0[2 * HW_ + o]);
                *(u16x8*)&s_in[e * 8] = v;
            }
        } else {
            for (int e = tid; e < NPX; e += 256) {
                int y = e / 34, x = e - y * 34;
                int gy = y0 + y - 1, gx = x0 + x - 1;
                u16x8 v = {0, 0, 0, 0, 0, 0, 0, 0};
                if (gy >= 0 && gy < H_ && gx >= 0 && gx < W_) {
                    size_t o = (size_t)gy * W_ + gx;
                    v[0] = f2u(sf[o]);
                    v[1] = f2u(sf[HW_ + o]);
                    v[2] = f2u(sf[2 * HW_ + o]);
                }
                *(u16x8*)&s_in[e * 8] = v;
            }
        }
    } else {
        const unsigned short* sb = src + (size_t)b * CIN * HW_;
        int oct = (OCT == 1) ? 0 : (wv % OCT);
        int phase = (OCT == 4) ? 0 : (wv / OCT);
        if (interior) {
            const unsigned short* sb0 =
                sb + ((size_t)(y0 - 1) * W_ + (x0 - 1)) * CIN + oct * 8;
            for (int px = lane + phase * 64; px < NPX; px += 256 / OCT) {
                int y = px / 34;
                u16x8 v;
                if (CIN == CINP || oct * 8 < CIN)
                    v = *(const u16x8*)&sb0[(size_t)(px + y * 266) * CIN];
                else
                    v = (u16x8){0, 0, 0, 0, 0, 0, 0, 0};
                *(u16x8*)&s_in[(oct * NPX + px) * 8] = v;
            }
        } else {
            for (int px = lane + phase * 64; px < NPX; px += 256 / OCT) {
                int y = px / 34, x = px - y * 34;
                int gy = y0 + y - 1, gx = x0 + x - 1;
                u16x8 v = {0, 0, 0, 0, 0, 0, 0, 0};
                if (gy >= 0 && gy < H_ && gx >= 0 && gx < W_ &&
                    (CIN == CINP || oct * 8 < CIN))
                    v = *(const u16x8*)&sb[((size_t)gy * W_ + gx) * CIN + oct * 8];
                *(u16x8*)&s_in[(oct * NPX + px) * 8] = v;
            }
        }
    }

    // ---- weight fragments (NGI groups) ----
    bf16x8 bw[NGI][NSTEP];
#pragma unroll
    for (int gi = 0; gi < NGI; ++gi)
#pragma unroll
        for (int s = 0; s < NSTEP; ++s)
            bw[gi][s] = *(const bf16x8*)&wpack[((s * NGI + gi) * 64 + lane) * 8];

    int col = lane & 15, kg = lane >> 4;

    float bias_r[NGI][4];
#pragma unroll
    for (int gi = 0; gi < NGI; ++gi)
#pragma unroll
        for (int r = 0; r < 4; ++r) {
            if (MODE == 2)
                bias_r[0][r] = (kg < 2) ? bias0[kg * 4 + r] : bias1[(kg - 2) * 4 + r];
            else {
                int co_l = gi * 16 + kg * 4 + r;
                bias_r[gi][r] = (co_l < COUT) ? bias0[co_l] : 0.f;
            }
        }

    __syncthreads();

    if constexpr (OCT == 4) {
        // ---- row-cached inner loop (TPK==1: step s == tap s) ----
        int myb = wv * (TH / 4);
#pragma unroll
        for (int tx = 0; tx < 2; ++tx) {
            int pbase = kg * NPX + tx * 16 + col;
            bf16x8 fr[3][3];
#pragma unroll
            for (int r = 0; r < 2; ++r)
#pragma unroll
                for (int dx = 0; dx < 3; ++dx)
                    fr[r][dx] =
                        *(const bf16x8*)&s_in[(pbase + (myb + r) * 34 + dx) * 8];
#pragma unroll
            for (int ii = 0; ii < TH / 4; ++ii) {
#pragma unroll
                for (int dx = 0; dx < 3; ++dx)
                    fr[(ii + 2) % 3][dx] =
                        *(const bf16x8*)&s_in[(pbase + (myb + ii + 2) * 34 + dx) * 8];

                f32x4 acc[NGI];
#pragma unroll
                for (int gi = 0; gi < NGI; ++gi) acc[gi] = {0.f, 0.f, 0.f, 0.f};
#pragma unroll
                for (int dy = 0; dy < 3; ++dy)
#pragma unroll
                    for (int dx = 0; dx < 3; ++dx) {
                        bf16x8 a = fr[(ii + dy) % 3][dx];
#pragma unroll
                        for (int gi = 0; gi < NGI; ++gi)
                            acc[gi] = __builtin_amdgcn_mfma_f32_16x16x32_bf16(
                                bw[gi][dy * 3 + dx], a, acc[gi], 0, 0, 0);
                    }

                int gy = y0 + myb + ii;
                int gxx = x0 + tx * 16 + col;
                if (gy < H_) {
                    if (MODE == 2) {
                        float v0 = acc[0].x + bias_r[0][0];
                        float v1 = acc[0].y + bias_r[0][1];
                        float v2 = acc[0].z + bias_r[0][2];
                        float v3 = acc[0].w + bias_r[0][3];
                        float m0 = __shfl_xor(v0, 32), m1 = __shfl_xor(v1, 32);
                        float m2 = __shfl_xor(v2, 32), m3 = __shfl_xor(v3, 32);
                        if (kg < 2 && gxx < W_) {
                            uint2 st;
                            st.x = packbf(v0 * sigm(m0), v1 * sigm(m1));
                            st.y = packbf(v2 * sigm(m2), v3 * sigm(m3));
                            *(uint2*)&out[(((size_t)b * HW_ + (size_t)gy * W_ +
                                            gxx) * 8) + kg * 4] = st;
                        }
                    } else {
#pragma unroll
                        for (int gi = 0; gi < NGI; ++gi) {
                            int co_g = gi * 16 + kg * 4;
                            if (co_g < COUT && gxx < W_) {
                                uint2 st;
                                st.x = packbf(acc[gi].x + bias_r[gi][0],
                                              acc[gi].y + bias_r[gi][1]);
                                st.y = packbf(acc[gi].z + bias_r[gi][2],
                                              acc[gi].w + bias_r[gi][3]);
                                *(uint2*)&out[((size_t)b * HW_ +
                                               (size_t)gy * W_ + gxx) *
                                                  co_total + co_off + co_g] = st;
                            }
                        }
                    }
                }
            }
        }
    } else {
        // ---- original loop for OCT<=2 ----
        int offs[NSTEP];
#pragma unroll
        for (int s = 0; s < NSTEP; ++s) {
            int t = s * TPK + kg / OCT;
            if (t > 8) t = 8;  // padded taps: weights are zero there
            offs[s] = ((t / 3) * 34 + (t % 3)) * 8 + (kg % OCT) * (NPX * 8);
        }

#pragma unroll
        for (int i = 0; i < TH / 2; ++i) {
            int m = wv * (TH / 2) + i;
            int my = m >> 1, tx = m & 1;
            int gy = y0 + my;
            if (gy >= H_) continue;  // wave-uniform
            int base = (my * 34 + tx * 16 + col) * 8;

            f32x4 acc[NGI];
#pragma unroll
            for (int gi = 0; gi < NGI; ++gi) acc[gi] = {0.f, 0.f, 0.f, 0.f};
#pragma unroll
            for (int s = 0; s < NSTEP; ++s) {
                bf16x8 a = *(const bf16x8*)&s_in[base + offs[s]];
#pragma unroll
                for (int gi = 0; gi < NGI; ++gi)
                    acc[gi] = __builtin_amdgcn_mfma_f32_16x16x32_bf16(
                        bw[gi][s], a, acc[gi], 0, 0, 0);
            }

            int gxx = x0 + tx * 16 + col;
#pragma unroll
            for (int gi = 0; gi < NGI; ++gi) {
                int co_g = gi * 16 + kg * 4;
                if (co_g < COUT && gxx < W_) {
                    uint2 st;
                    st.x = packbf(acc[gi].x + bias_r[gi][0],
                                  acc[gi].y + bias_r[gi][1]);
                    st.y = packbf(acc[gi].z + bias_r[gi][2],
                                  acc[gi].w + bias_r[gi][3]);
                    *(uint2*)&out[((size_t)b * HW_ + (size_t)gy * W_ + gxx) *
                                      co_total + co_off + co_g] = st;
                }
            }
        }
    }
}

// ---------------------------------------------------------------------------
// Fused cK trio as ONE composite 32-ch conv (planes x|up5|up10|up15) with
// NGI=2 column groups ({c5,c10}, {c15}) and the row-cached inner loop.
// Writes 24-ch NHWC g_in.
// ---------------------------------------------------------------------------
__global__ __launch_bounds__(256) void convc3_k(
    const unsigned short* __restrict__ src,
    const unsigned short* __restrict__ p5, const unsigned short* __restrict__ p10,
    const unsigned short* __restrict__ p15,
    const unsigned short* __restrict__ wpack,
    const float* __restrict__ bc5, const float* __restrict__ bc10,
    const float* __restrict__ bc15, unsigned short* __restrict__ out)
{
    constexpr int TH = 16;
    constexpr int NPX = (TH + 2) * 34;
    __shared__ __align__(16) unsigned short s_in[4 * NPX * 8];

    int b = blockIdx.z;
    int x0 = blockIdx.x * 32, y0 = blockIdx.y * TH;
    int tid = threadIdx.x;
    int lane = tid & 63, wv = tid >> 6;
    bool interior = (x0 >= 1) && (x0 + 32 < W_) && (y0 >= 1) && (y0 + TH < H_);

    const unsigned short* sb = src + (size_t)b * 8 * HW_;
    const unsigned short* pb5 = p5 + (size_t)b * 8 * 3600;
    const unsigned short* pb10 = p10 + (size_t)b * 8 * 900;
    const unsigned short* pb15 = p15 + (size_t)b * 8 * 400;

    int oct = wv;  // wave-uniform plane
    if (interior) {
        const unsigned short* sb0 = sb + ((size_t)(y0 - 1) * W_ + (x0 - 1)) * 8;
        for (int px = lane; px < NPX; px += 64) {
            int y = px / 34;
            u16x8 v;
            if (oct == 0) {
                v = *(const u16x8*)&sb0[(size_t)(px + y * 266) * 8];
            } else {
                int x = px - y * 34;
                int gy = y0 - 1 + y, gx = x0 - 1 + x;
                const unsigned short* pp =
                    (oct == 1) ? &pb5[((size_t)(gy / 5) * 60 + gx / 5) * 8]
                    : (oct == 2) ? &pb10[((size_t)(gy / 10) * 30 + gx / 10) * 8]
                                 : &pb15[((size_t)(gy / 15) * 20 + gx / 15) * 8];
                v = *(const u16x8*)pp;
            }
            *(u16x8*)&s_in[(oct * NPX + px) * 8] = v;
        }
    } else {
        for (int px = lane; px < NPX; px += 64) {
            int y = px / 34, x = px - y * 34;
            int gy = y0 + y - 1, gx = x0 + x - 1;
            u16x8 v = {0, 0, 0, 0, 0, 0, 0, 0};
            if (gy >= 0 && gy < H_ && gx >= 0 && gx < W_) {
                if (oct == 0)
                    v = *(const u16x8*)&sb[((size_t)gy * W_ + gx) * 8];
                else if (oct == 1)
                    v = *(const u16x8*)&pb5[((size_t)(gy / 5) * 60 + gx / 5) * 8];
                else if (oct == 2)
                    v = *(const u16x8*)&pb10[((size_t)(gy / 10) * 30 + gx / 10) * 8];
                else
                    v = *(const u16x8*)&pb15[((size_t)(gy / 15) * 20 + gx / 15) * 8];
            }
            *(u16x8*)&s_in[(oct * NPX + px) * 8] = v;
        }
    }

    bf16x8 bw[2][9];
#pragma unroll
    for (int g = 0; g < 2; ++g)
#pragma unroll
        for (int s = 0; s < 9; ++s)
            bw[g][s] = *(const bf16x8*)&wpack[((s * 2 + g) * 64 + lane) * 8];

    int col = lane & 15, kg = lane >> 4;
    float bias_r[2][4];
#pragma unroll
    for (int r = 0; r < 4; ++r) {
        bias_r[0][r] = (kg < 2) ? bc5[kg * 4 + r] : bc10[(kg - 2) * 4 + r];
        bias_r[1][r] = (kg < 2) ? bc15[kg * 4 + r] : 0.f;
    }

    __syncthreads();

    int myb = wv * (TH / 4);
#pragma unroll
    for (int tx = 0; tx < 2; ++tx) {
        int pbase = kg * NPX + tx * 16 + col;
        bf16x8 fr[3][3];
#pragma unroll
        for (int r = 0; r < 2; ++r)
#pragma unroll
            for (int dx = 0; dx < 3; ++dx)
                fr[r][dx] = *(const bf16x8*)&s_in[(pbase + (myb + r) * 34 + dx) * 8];
#pragma unroll
        for (int ii = 0; ii < TH / 4; ++ii) {
#pragma unroll
            for (int dx = 0; dx < 3; ++dx)
                fr[(ii + 2) % 3][dx] =
                    *(const bf16x8*)&s_in[(pbase + (myb + ii + 2) * 34 + dx) * 8];

            f32x4 acc[2];
            acc[0] = {0.f, 0.f, 0.f, 0.f};
            acc[1] = {0.f, 0.f, 0.f, 0.f};
#pragma unroll
            for (int dy = 0; dy < 3; ++dy)
#pragma unroll
                for (int dx = 0; dx < 3; ++dx) {
                    bf16x8 a = fr[(ii + dy) % 3][dx];
                    acc[0] = __builtin_amdgcn_mfma_f32_16x16x32_bf16(
                        bw[0][dy * 3 + dx], a, acc[0], 0, 0, 0);
                    acc[1] = __builtin_amdgcn_mfma_f32_16x16x32_bf16(
                        bw[1][dy * 3 + dx], a, acc[1], 0, 0, 0);
                }

            int gy = y0 + myb + ii;
            int gxx = x0 + tx * 16 + col;
            if (gy < H_ && gxx < W_) {
                size_t pxo = ((size_t)b * HW_ + (size_t)gy * W_ + gxx) * 24;
                uint2 st0;
                st0.x = packbf(acc[0].x + bias_r[0][0], acc[0].y + bias_r[0][1]);
                st0.y = packbf(acc[0].z + bias_r[0][2], acc[0].w + bias_r[0][3]);
                *(uint2*)&out[pxo + kg * 4] = st0;  // ch 0-15: c5|c10
                if (kg < 2) {
                    uint2 st1;
                    st1.x = packbf(acc[1].x + bias_r[1][0], acc[1].y + bias_r[1][1]);
                    st1.y = packbf(acc[1].z + bias_r[1][2], acc[1].w + bias_r[1][3]);
                    *(uint2*)&out[pxo + 16 + kg * 4] = st1;  // ch 16-23: c15
                }
            }
        }
    }
}

// ---------------------------------------------------------------------------
// Pools, NHWC (8ch vector per pixel). p10/p15 merged in one launch.
// ---------------------------------------------------------------------------
__global__ __launch_bounds__(256) void pool5_k(const unsigned short* __restrict__ x,
                                               unsigned short* __restrict__ p5,
                                               int n)
{
    int idx = blockIdx.x * 256 + threadIdx.x;
    if (idx >= n) return;
    int b = idx / 3600;
    int rem = idx - b * 3600;
    int i = rem / 60, j = rem - i * 60;
    const unsigned short* src =
        x + ((size_t)b * HW_ + (size_t)(i * 5) * W_ + j * 5) * 8;
    float ss[8] = {0, 0, 0, 0, 0, 0, 0, 0};
#pragma unroll
    for (int r = 0; r < 5; ++r)
#pragma unroll
        for (int c = 0; c < 5; ++c) {
            u16x8 v = *(const u16x8*)&src[((size_t)r * W_ + c) * 8];
#pragma unroll
            for (int k = 0; k < 8; ++k) ss[k] += b2f(v[k]);
        }
    uint4 st;
    st.x = packbf(ss[0] * 0.04f, ss[1] * 0.04f);
    st.y = packbf(ss[2] * 0.04f, ss[3] * 0.04f);
    st.z = packbf(ss[4] * 0.04f, ss[5] * 0.04f);
    st.w = packbf(ss[6] * 0.04f, ss[7] * 0.04f);
    *(uint4*)&p5[(size_t)idx * 8] = st;
}

template <int R, int OD>
__device__ __forceinline__ void poolr_body(const unsigned short* __restrict__ p5,
                                           unsigned short* __restrict__ po, int idx)
{
    int b = idx / (OD * OD);
    int rem = idx - b * OD * OD;
    int i = rem / OD, j = rem - i * OD;
    const unsigned short* src =
        p5 + ((size_t)b * 3600 + (size_t)(i * R) * 60 + j * R) * 8;
    float ss[8] = {0, 0, 0, 0, 0, 0, 0, 0};
    const float inv = 1.f / (R * R);
#pragma unroll
    for (int r = 0; r < R; ++r)
#pragma unroll
        for (int c = 0; c < R; ++c) {
            u16x8 v = *(const u16x8*)&src[((size_t)r * 60 + c) * 8];
#pragma unroll
            for (int k = 0; k < 8; ++k) ss[k] += b2f(v[k]);
        }
    uint4 st;
    st.x = packbf(ss[0] * inv, ss[1] * inv);
    st.y = packbf(ss[2] * inv, ss[3] * inv);
    st.z = packbf(ss[4] * inv, ss[5] * inv);
    st.w = packbf(ss[6] * inv, ss[7] * inv);
    *(uint4*)&po[(size_t)idx * 8] = st;
}

__global__ __launch_bounds__(256) void poolrs_k(const unsigned short* __restrict__ p5,
                                                unsigned short* __restrict__ p10,
                                                unsigned short* __restrict__ p15,
                                                int n10, int n15)
{
    int idx = blockIdx.x * 256 + threadIdx.x;
    if (idx < n10) {
        poolr_body<2, 30>(p5, p10, idx);
    } else {
        idx -= n10;
        if (idx < n15) poolr_body<3, 20>(p5, p15, idx);
    }
}

// ---------------------------------------------------------------------------
// BN stats over NHWC gated: RB blocks.
// ---------------------------------------------------------------------------
__global__ __launch_bounds__(256) void reduce_k(
    const unsigned short* __restrict__ gated, float2* __restrict__ partials)
{
    int bx = blockIdx.x;
    int tid = threadIdx.x;
    float s[8] = {0, 0, 0, 0, 0, 0, 0, 0};
    float s2[8] = {0, 0, 0, 0, 0, 0, 0, 0};
    const size_t N = (size_t)NBATCH * HW_;
    for (size_t i = (size_t)bx * 256 + tid; i < N; i += (size_t)RB * 256) {
        u16x8 v = *(const u16x8*)&gated[i * 8];
#pragma unroll
        for (int k = 0; k < 8; ++k) {
            float f = b2f(v[k]);
            s[k] += f;
            s2[k] += f * f;
        }
    }
#pragma unroll
    for (int off = 32; off > 0; off >>= 1) {
#pragma unroll
        for (int k = 0; k < 8; ++k) {
            s[k] += __shfl_down(s[k], off);
            s2[k] += __shfl_down(s2[k], off);
        }
    }
    __shared__ float2 red[4][8];
    int lane = tid & 63, wvi = tid >> 6;
    if (lane == 0) {
#pragma unroll
        for (int k = 0; k < 8; ++k) red[wvi][k] = make_float2(s[k], s2[k]);
    }
    __syncthreads();
    if (tid < 8) {
        float a = 0.f, b2 = 0.f;
        for (int i = 0; i < 4; ++i) { a += red[i][tid].x; b2 += red[i][tid].y; }
        partials[tid * RB + bx] = make_float2(a, b2);
    }
}

// Parallel fold: reduce RB partials, fold BN into conv11 weights.
__global__ __launch_bounds__(256) void stats_fold_k(
    const float2* __restrict__ partials, const float* __restrict__ bn_w,
    const float* __restrict__ bn_b, const float* __restrict__ w11,
    const float* __restrict__ b11, float* __restrict__ wfold)
{
    __shared__ float sc[8], tc[8];
    __shared__ float2 acc8[8];
    int tid = threadIdx.x;
    int c = tid >> 5, sl = tid & 31;
    float s = 0.f, s2 = 0.f;
    for (int i = sl; i < RB; i += 32) {
        float2 p = partials[c * RB + i];
        s += p.x;
        s2 += p.y;
    }
#pragma unroll
    for (int off = 16; off > 0; off >>= 1) {
        s += __shfl_down(s, off, 32);
        s2 += __shfl_down(s2, off, 32);
    }
    if (sl == 0) acc8[c] = make_float2(s, s2);
    __syncthreads();
    if (tid < 8) {
        double ds = acc8[tid].x, ds2 = acc8[tid].y;
        double N = (double)NBATCH * HW_;
        double mean = ds / N;
        double var = ds2 / N - mean * mean;
        float rstd = (float)(1.0 / sqrt(var + 1e-5));
        float scv = bn_w[tid] * rstd;
        sc[tid] = scv;
        tc[tid] = bn_b[tid] - (float)mean * scv;
    }
    __syncthreads();
    if (tid < 72) {
        int t = tid >> 3, ci = tid & 7;
        wfold[tid] = w11[ci * 9 + t] * sc[ci];
    }
    if (tid == 72) {
        float a = b11[0];
        for (int i = 0; i < 72; ++i) a += w11[i] * tc[i / 9];
        wfold[72] = a;
    }
}

// ---------------------------------------------------------------------------
// Final: att = sigmoid(conv 8->1 over NHWC gated), blend with im (NCHW fp32).
// ---------------------------------------------------------------------------
__global__ __launch_bounds__(256) void final_k(
    const unsigned short* __restrict__ gated, const float* __restrict__ wf,
    const float* __restrict__ im, const float* __restrict__ gamma,
    float* __restrict__ out)
{
    __shared__ __align__(16) unsigned short s_g[1156 * 8];
    __shared__ float s_w[80];

    int b = blockIdx.z;
    int x0 = blockIdx.x * 32, y0 = blockIdx.y * 32;
    int tid = threadIdx.x;
    bool interior = (x0 >= 1) && (x0 + 32 < W_) && (y0 >= 1) && (y0 + 32 < H_);

    if (tid < 73) s_w[tid] = wf[tid];

    const unsigned short* gb = gated + (size_t)b * HW_ * 8;
    if (interior) {
        const unsigned short* gb0 = gb + ((size_t)(y0 - 1) * W_ + (x0 - 1)) * 8;
        for (int e = tid; e < 1156; e += 256) {
            int y = e / 34;
            u16x8 v = *(const u16x8*)&gb0[(size_t)(e + y * 266) * 8];
            *(u16x8*)&s_g[e * 8] = v;
        }
    } else {
        for (int e = tid; e < 1156; e += 256) {
            int y = e / 34, x = e - y * 34;
            int gy = y0 + y - 1, gx = x0 + x - 1;
            u16x8 v = {0, 0, 0, 0, 0, 0, 0, 0};
            if (gy >= 0 && gy < H_ && gx >= 0 && gx < W_)
                v = *(const u16x8*)&gb[((size_t)gy * W_ + gx) * 8];
            *(u16x8*)&s_g[e * 8] = v;
        }
    }
    __syncthreads();

    int qx = (tid & 15) * 2, qy = (tid >> 4) * 2;
    float f[4];
    float gm = *gamma;
#pragma unroll
    for (int p = 0; p < 4; ++p) {
        int ly = qy + (p >> 1), lx = qx + (p & 1);
        float acc = s_w[72];
#pragma unroll
        for (int t = 0; t < 9; ++t) {
            u16x8 n = *(const u16x8*)&s_g[((ly + t / 3) * 34 + lx + t % 3) * 8];
#pragma unroll
            for (int ci = 0; ci < 8; ++ci) acc += b2f(n[ci]) * s_w[t * 8 + ci];
        }
        f[p] = (1.f - gm) + gm * sigm(acc);
    }

    int px = x0 + qx, py = y0 + qy;
    if (px < W_) {
#pragma unroll
        for (int ch = 0; ch < 3; ++ch) {
            const float* imb = im + ((size_t)b * 3 + ch) * HW_;
            float* ob = out + ((size_t)b * 3 + ch) * HW_;
#pragma unroll
            for (int pr = 0; pr < 2; ++pr) {
                if (py + pr < H_) {
                    float2 iv = *(const float2*)&imb[(size_t)(py + pr) * W_ + px];
                    float2 ov;
                    ov.x = iv.x * f[pr * 2 + 0];
                    ov.y = iv.y * f[pr * 2 + 1];
                    *(float2*)&ob[(size_t)(py + pr) * W_ + px] = ov;
                }
            }
        }
    }
}

// ---------------------------------------------------------------------------

extern "C" void kernel_launch(void* const* d_in, const int* in_sizes, int n_in,
                              void* d_out, int out_size, void* d_ws,
                              size_t ws_size, hipStream_t stream)
{
    (void)in_sizes; (void)n_in; (void)out_size;

    const float* im  = (const float*)d_in[0];
    const float* w1  = (const float*)d_in[1];
    const float* b1  = (const float*)d_in[2];
    const float* w2  = (const float*)d_in[3];
    const float* b2  = (const float*)d_in[4];
    const float* w3  = (const float*)d_in[5];
    const float* b3  = (const float*)d_in[6];
    const float* w4  = (const float*)d_in[7];
    const float* b4  = (const float*)d_in[8];
    const float* w5  = (const float*)d_in[9];
    const float* b5  = (const float*)d_in[10];
    const float* wc5 = (const float*)d_in[11];
    const float* bc5 = (const float*)d_in[12];
    const float* wc10= (const float*)d_in[13];
    const float* bc10= (const float*)d_in[14];
    const float* wc15= (const float*)d_in[15];
    const float* bc15= (const float*)d_in[16];
    const float* wg  = (const float*)d_in[17];
    const float* bg  = (const float*)d_in[18];
    const float* wm  = (const float*)d_in[19];
    const float* bm  = (const float*)d_in[20];
    const float* bnw = (const float*)d_in[21];
    const float* bnb = (const float*)d_in[22];
    const float* w11 = (const float*)d_in[23];
    const float* b11 = (const float*)d_in[24];
    const float* gam = (const float*)d_in[25];
    float* out = (float*)d_out;

    // ---- workspace plan (chunked batch; deterministic in ws_size) ----------
    const size_t GATED_B = 46080000;
    const size_t PER_IMG = 1440000 + 2880000 + 5760000 + 57600 + 14400 + 6656;
    const size_t MISC    = 262144;
    int c = 32;
    while (c > 1 && GATED_B + MISC + (size_t)c * PER_IMG + 2048 > ws_size)
        c >>= 1;

    char* p = (char*)d_ws;
    auto take = [&](size_t bytes) {
        char* r = p;
        p += (bytes + 255) & ~(size_t)255;
        return r;
    };
    unsigned short* GATED = (unsigned short*)take(GATED_B);
    unsigned short* A   = (unsigned short*)take((size_t)c * 1440000);
    unsigned short* Bb  = (unsigned short*)take((size_t)c * 2880000);
    unsigned short* C   = (unsigned short*)take((size_t)c * 5760000);
    unsigned short* P5  = (unsigned short*)take((size_t)c * 57600);
    unsigned short* P10 = (unsigned short*)take((size_t)c * 14400);
    unsigned short* P15 = (unsigned short*)take((size_t)c * 6656);
    float2* parts = (float2*)take(8 * RB * sizeof(float2));
    float*  wfold = (float*)take(512);
    unsigned short* WP = (unsigned short*)take(65536);

    unsigned short* PK2 = WP;            // conv2: 3 steps
    unsigned short* PK3 = WP + 2048;     // conv3: 5x2
    unsigned short* PK4 = WP + 8192;     // conv4: 9
    unsigned short* PK5 = WP + 13312;    // conv5: 5
    unsigned short* PKc = WP + 16384;    // convc composite: 9x2
    unsigned short* PKg = WP + 25600;    // gated: 9
    unsigned short* PK1 = WP + 30720;    // conv1: 3

    dim3 blk(256);

    pack_all_k<<<dim3(7), blk, 0, stream>>>(w1, w2, w3, w4, w5, wc5, wc10, wc15,
                                            wg, wm, WP);

    for (int b0 = 0; b0 < NBATCH; b0 += c) {
        dim3 g32(10, 10, c);   // TH=32 kernels
        dim3 g16(10, 19, c);   // TH=16 kernels
        const float* imc = im + (size_t)b0 * 3 * HW_;

        mfconv_k<8, 8, 8, 1, 3, 32><<<g32, blk, 0, stream>>>(
            (const unsigned short*)imc, PK1, b1, nullptr, A, 8, 0);
        mfconv_k<8, 8, 16, 1, 0, 32><<<g32, blk, 0, stream>>>(
            A, PK2, b2, nullptr, Bb, 16, 0);
        mfconv_k<16, 16, 32, 2, 0, 32><<<g32, blk, 0, stream>>>(
            Bb, PK3, b3, nullptr, C, 32, 0);
        mfconv_k<32, 32, 16, 1, 0, 16><<<g16, blk, 0, stream>>>(
            C, PK4, b4, nullptr, Bb, 16, 0);
        mfconv_k<16, 16, 8, 1, 0, 32><<<g32, blk, 0, stream>>>(
            Bb, PK5, b5, nullptr, A, 8, 0);

        int n5 = c * 3600, n10 = c * 900, n15 = c * 400;
        pool5_k<<<dim3((n5 + 255) / 256), blk, 0, stream>>>(A, P5, n5);
        poolrs_k<<<dim3((n10 + n15 + 255) / 256), blk, 0, stream>>>(P5, P10, P15,
                                                                    n10, n15);

        convc3_k<<<g16, blk, 0, stream>>>(A, P5, P10, P15, PKc, bc5, bc10, bc15, C);

        mfconv_k<24, 32, 16, 1, 2, 16><<<g16, blk, 0, stream>>>(
            C, PKg, bg, bm, GATED + (size_t)b0 * HW_ * 8, 8, 0);
    }

    reduce_k<<<dim3(RB), blk, 0, stream>>>(GATED, parts);
    stats_fold_k<<<dim3(1), blk, 0, stream>>>(parts, bnw, bnb, w11, b11, wfold);
    final_k<<<dim3(10, 10, NBATCH), blk, 0, stream>>>(GATED, wfold, im, gam,
                                                      out);
}